// Round 1
// baseline (10750.932 us; speedup 1.0000x reference)
//
#include <hip/hip_runtime.h>
#include <hip/hip_bf16.h>

#define DI __device__ __forceinline__

constexpr int Bc = 2, Cc = 256, Hc = 256, Wc = 256, Nc = Hc * Wc; // N=65536
constexpr float LA_EPS = 1e-6f;

// ---------------------------------------------------------------------------
// K1: Q,K = 1x1 conv of x (32 ch each), L2-normalized over channel dim per pixel
// grid: B * (N/64) = 2048 blocks, 256 threads
// ---------------------------------------------------------------------------
__global__ __launch_bounds__(256) void k1_qk(const float* __restrict__ x,
        const float* __restrict__ wq, const float* __restrict__ bq,
        const float* __restrict__ wk, const float* __restrict__ bk,
        float* __restrict__ Qo, float* __restrict__ Ko)
{
    int b = blockIdx.x >> 10;
    int n0 = (blockIdx.x & 1023) * 64;
    int t = threadIdx.x;
    int px = t & 63, g = t >> 6;
    __shared__ float xT[256][64];
    __shared__ float qkT[64][65];
    __shared__ float rn[2][64];
    const float* xb = x + (size_t)b * Cc * Nc + n0;
    for (int i = 0; i < 64; ++i) {
        int c = i * 4 + g;
        xT[c][px] = xb[(size_t)c * Nc + px];
    }
    __syncthreads();
    float outv[16];
    #pragma unroll
    for (int j = 0; j < 16; ++j) {
        int oc = j * 4 + g;
        const float* wrow;
        float acc;
        if (oc < 32) { wrow = wq + oc * 256; acc = bq[oc]; }
        else         { wrow = wk + (oc - 32) * 256; acc = bk[oc - 32]; }
        for (int c = 0; c < 256; ++c) acc += wrow[c] * xT[c][px];
        outv[j] = acc;
        qkT[oc][px] = acc;
    }
    __syncthreads();
    if (t < 128) {
        int p = t & 63, which = t >> 6; // 0=q, 1=k
        float s = 0.f;
        #pragma unroll
        for (int m = 0; m < 32; ++m) { float v = qkT[which * 32 + m][p]; s += v * v; }
        rn[which][p] = 1.0f / sqrtf(s);
    }
    __syncthreads();
    #pragma unroll
    for (int j = 0; j < 16; ++j) {
        int oc = j * 4 + g;
        if (oc < 32) Qo[((size_t)b * 32 + oc) * Nc + n0 + px] = outv[j] * rn[0][px];
        else         Ko[((size_t)b * 32 + oc - 32) * Nc + n0 + px] = outv[j] * rn[1][px];
    }
}

// ---------------------------------------------------------------------------
// K2: KX[b,m,c] = sum_n K[b,m,n]*x[b,c,n]; xsum[b,c]; Ksum[b,m]  (atomics)
// grid: 256 blocks (128 per batch), 256 threads; each block 8 chunks of 64 px
// ---------------------------------------------------------------------------
__global__ __launch_bounds__(256) void k2_kx(const float* __restrict__ x,
        const float* __restrict__ Kn, float* __restrict__ KX,
        float* __restrict__ xsum, float* __restrict__ Ksum)
{
    int b = blockIdx.x >> 7;
    int blk = blockIdx.x & 127;
    int t = threadIdx.x;
    int pxl = t & 63, g = t >> 6;
    __shared__ float xT[256][65];
    __shared__ float kT[32][64];
    float acc[32];
    #pragma unroll
    for (int m = 0; m < 32; ++m) acc[m] = 0.f;
    float xs = 0.f, ks = 0.f;
    for (int i = 0; i < 8; ++i) {
        int n0 = (blk + 128 * i) * 64;
        __syncthreads();
        for (int j = 0; j < 64; ++j) {
            int c = j * 4 + g;
            xT[c][pxl] = x[(size_t)(b * 256 + c) * Nc + n0 + pxl];
        }
        #pragma unroll
        for (int j = 0; j < 8; ++j) {
            int m = j * 4 + g;
            kT[m][pxl] = Kn[((size_t)b * 32 + m) * Nc + n0 + pxl];
        }
        __syncthreads();
        #pragma unroll 2
        for (int p = 0; p < 64; ++p) {
            float xv = xT[t][p];
            xs += xv;
            #pragma unroll
            for (int m = 0; m < 32; ++m) acc[m] += kT[m][p] * xv;
        }
        if (t < 32) {
            for (int p = 0; p < 64; ++p) ks += kT[t][p];
        }
    }
    atomicAdd(&xsum[b * 256 + t], xs);
    if (t < 32) atomicAdd(&Ksum[b * 32 + t], ks);
    #pragma unroll
    for (int m = 0; m < 32; ++m) atomicAdd(&KX[(b * 32 + m) * 256 + t], acc[m]);
}

// ---------------------------------------------------------------------------
// K3: matrix[b,m,c] = sum_c' wv[c,c']*KX[b,m,c'] + bv[c]*Ksum[b,m]
//     vsum[b,c]    = sum_c' wv[c,c']*xsum[b,c'] + bv[c]*N
// grid: 2 blocks (one per batch), 256 threads (thread = c)
// ---------------------------------------------------------------------------
__global__ __launch_bounds__(256) void k3_mat(const float* __restrict__ wv,
        const float* __restrict__ bv, const float* __restrict__ KX,
        const float* __restrict__ xsum, const float* __restrict__ Ksum,
        float* __restrict__ matrix, float* __restrict__ vsum)
{
    int b = blockIdx.x, t = threadIdx.x;
    __shared__ float sx[256];
    __shared__ float sk[32];
    __shared__ float skx[32][256];
    __shared__ float wT[256][65];
    sx[t] = xsum[b * 256 + t];
    if (t < 32) sk[t] = Ksum[b * 32 + t];
    for (int j = 0; j < 32; ++j) skx[j][t] = KX[(b * 32 + j) * 256 + t];
    float vs = bv[t] * (float)Nc;
    float mv[32];
    #pragma unroll
    for (int m = 0; m < 32; ++m) mv[m] = 0.f;
    for (int cc0 = 0; cc0 < 256; cc0 += 64) {
        __syncthreads();
        for (int i = 0; i < 64; ++i) {
            int c = i * 4 + (t >> 6);
            wT[c][t & 63] = wv[(size_t)c * 256 + cc0 + (t & 63)];
        }
        __syncthreads();
        for (int ccl = 0; ccl < 64; ++ccl) {
            float w = wT[t][ccl];
            int cc = cc0 + ccl;
            vs += w * sx[cc];
            #pragma unroll
            for (int m = 0; m < 32; ++m) mv[m] += w * skx[m][cc];
        }
    }
    vsum[b * 256 + t] = vs;
    float bvt = bv[t];
    for (int m = 0; m < 32; ++m) matrix[(b * 32 + m) * 256 + t] = mv[m] + bvt * sk[m];
}

// ---------------------------------------------------------------------------
// K4: z = x + gamma * (vsum[c] + sum_m Q[m,n]*matrix[m,c]) * tailor[n]
//     tailor[n] = 1/(N + sum_m Q[m,n]*(Ksum[m]+EPS));  z -> d_out
// grid: B*(N/64) = 2048 blocks, 256 threads
// ---------------------------------------------------------------------------
__global__ __launch_bounds__(256) void k4_z(const float* __restrict__ x,
        const float* __restrict__ Q, const float* __restrict__ matrix,
        const float* __restrict__ vsum, const float* __restrict__ Ksum,
        const float* __restrict__ gamma_p, float* __restrict__ z)
{
    int b = blockIdx.x >> 10;
    int n0 = (blockIdx.x & 1023) * 64;
    int t = threadIdx.x;
    int px = t & 63, g = t >> 6;
    __shared__ float qT[32][64];
    __shared__ float mat[32][256];
    __shared__ float vs[256];
    __shared__ float tail[64];
    __shared__ float sk[32];
    #pragma unroll
    for (int j = 0; j < 8; ++j) {
        int m = j * 4 + g;
        qT[m][px] = Q[((size_t)b * 32 + m) * Nc + n0 + px];
    }
    for (int j = 0; j < 32; ++j) {
        int idx = j * 256 + t;
        (&mat[0][0])[idx] = matrix[b * 8192 + idx];
    }
    vs[t] = vsum[b * 256 + t];
    if (t < 32) sk[t] = Ksum[b * 32 + t] + LA_EPS;
    __syncthreads();
    if (t < 64) {
        float s = 0.f;
        #pragma unroll
        for (int m = 0; m < 32; ++m) s += qT[m][t] * sk[m];
        tail[t] = 1.0f / ((float)Nc + s);
    }
    __syncthreads();
    float gamma = gamma_p[0];
    for (int l = 0; l < 64; ++l) {
        int c = l * 4 + g;
        float s = vs[c];
        #pragma unroll
        for (int m = 0; m < 32; ++m) s += qT[m][px] * mat[m][c];
        size_t idx = (size_t)(b * 256 + c) * Nc + n0 + px;
        z[idx] = x[idx] + gamma * s * tail[px];
    }
}

// ---------------------------------------------------------------------------
// K5: local = s2*(wl2@y)+b2 + s1*conv3x3(y,wl1)+b1  (scales folded into weights)
// grid: B * 8 coutTiles * 1024 spatial(8x8) = 16384 blocks, 256 threads
// thread tile: 4 cout x 2 px
// ---------------------------------------------------------------------------
__global__ __launch_bounds__(256) void k5_local(const float* __restrict__ y,
        const float* __restrict__ wl1, const float* __restrict__ s1, const float* __restrict__ b1,
        const float* __restrict__ wl2, const float* __restrict__ s2, const float* __restrict__ b2,
        float* __restrict__ L)
{
    int blk = blockIdx.x;
    int tile = blk & 1023;
    int ct = (blk >> 10) & 7;
    int b = blk >> 13;
    int ty = tile >> 5, tx = tile & 31;
    int t = threadIdx.x;
    __shared__ float yT[32][100];     // [ci][yy*10+xx], halo origin (-1,-1)
    __shared__ float w1T[32][32][9];  // scaled by s1
    __shared__ float w2T[32][32];     // scaled by s2
    int p0 = t & 31, cg = t >> 5;
    int yy0 = p0 >> 3, xx0 = p0 & 7;
    float acc[4][2];
    #pragma unroll
    for (int j = 0; j < 4; ++j) { acc[j][0] = 0.f; acc[j][1] = 0.f; }
    for (int cin0 = 0; cin0 < 256; cin0 += 32) {
        __syncthreads();
        for (int i = 0; i < 13; ++i) {
            int idx = i * 256 + t;
            if (idx < 3200) {
                int ci = idx / 100, r = idx - ci * 100;
                int yy = r / 10, xx = r - yy * 10;
                int gy = ty * 8 + yy - 1, gx = tx * 8 + xx - 1;
                float v = 0.f;
                if ((unsigned)gy < 256u && (unsigned)gx < 256u)
                    v = y[((size_t)(b * 256 + cin0 + ci) * 256 + gy) * 256 + gx];
                yT[ci][r] = v;
            }
        }
        for (int i = 0; i < 36; ++i) {
            int idx = i * 256 + t;
            int co = idx / 288, r = idx - co * 288;
            int ci = r / 9, uv = r - ci * 9;
            int gco = ct * 32 + co;
            w1T[co][ci][uv] = wl1[((size_t)gco * 256 + cin0 + ci) * 9 + uv] * s1[gco];
        }
        for (int i = 0; i < 4; ++i) {
            int idx = i * 256 + t;
            int co = idx >> 5, ci = idx & 31;
            int gco = ct * 32 + co;
            w2T[co][ci] = wl2[(size_t)gco * 256 + cin0 + ci] * s2[gco];
        }
        __syncthreads();
        for (int ci = 0; ci < 32; ++ci) {
            #pragma unroll
            for (int u = 0; u < 3; ++u)
            #pragma unroll
            for (int v = 0; v < 3; ++v) {
                float y0v = yT[ci][(yy0 + u) * 10 + xx0 + v];
                float y1v = yT[ci][(yy0 + 4 + u) * 10 + xx0 + v];
                #pragma unroll
                for (int j = 0; j < 4; ++j) {
                    float wv = w1T[cg * 4 + j][ci][u * 3 + v];
                    acc[j][0] += wv * y0v;
                    acc[j][1] += wv * y1v;
                }
            }
            float y0v = yT[ci][(yy0 + 1) * 10 + xx0 + 1];
            float y1v = yT[ci][(yy0 + 5) * 10 + xx0 + 1];
            #pragma unroll
            for (int j = 0; j < 4; ++j) {
                float wv = w2T[cg * 4 + j][ci];
                acc[j][0] += wv * y0v;
                acc[j][1] += wv * y1v;
            }
        }
    }
    #pragma unroll
    for (int j = 0; j < 4; ++j) {
        int gco = ct * 32 + cg * 4 + j;
        float bias = b1[gco] + b2[gco];
        size_t base = ((size_t)(b * 256 + gco) * 256 + ty * 8) * 256 + tx * 8;
        L[base + yy0 * 256 + xx0] = acc[j][0] + bias;
        L[base + (yy0 + 4) * 256 + xx0] = acc[j][1] + bias;
    }
}

// ---------------------------------------------------------------------------
// K6: fused qkv(1x1 conv of z) + 8x8 window attention (16 heads, d=16)
// grid: B*32*32 = 2048 blocks (one window), 256 threads
// ---------------------------------------------------------------------------
__global__ __launch_bounds__(256) void k6_attn(const float* __restrict__ z,
        const float* __restrict__ wqkv, const float* __restrict__ rel,
        float* __restrict__ A)
{
    int blk = blockIdx.x;
    int wx = blk & 31, wy = (blk >> 5) & 31, b = blk >> 10;
    int t = threadIdx.x;
    __shared__ float zW[64][257];   // [px][c]
    __shared__ float wS[48][257];   // [rr][c] rows: q(16) k(16) v(16) for head h
    __shared__ float qkvH[48][66];  // [rr][px]
    __shared__ float SL[64][65];
    __shared__ float srow[64];
    {
        int px = t & 63, cg = t >> 6;
        int gy = wy * 8 + (px >> 3), gx = wx * 8 + (px & 7);
        const float* zb = z + (size_t)b * 256 * Nc + gy * 256 + gx;
        for (int i = 0; i < 64; ++i) {
            int c = i * 4 + cg;
            zW[px][c] = zb[(size_t)c * Nc];
        }
    }
    int pp = t & 31, rowg = t >> 5;
    int jj = t & 63, ig = t >> 6;
    for (int h = 0; h < 16; ++h) {
        __syncthreads();
        for (int rr = 0; rr < 48; ++rr) {
            int wrow = (rr >> 4) * 256 + h * 16 + (rr & 15);
            wS[rr][t] = wqkv[(size_t)wrow * 256 + t];
        }
        __syncthreads();
        { // qkv: 48 rows x 64 px; thread tile 6 rows x 2 px
            float acc[6][2];
            #pragma unroll
            for (int r = 0; r < 6; ++r) { acc[r][0] = 0.f; acc[r][1] = 0.f; }
            for (int c = 0; c < 256; ++c) {
                float z0 = zW[pp][c], z1 = zW[pp + 32][c];
                #pragma unroll
                for (int r = 0; r < 6; ++r) {
                    float w = wS[rowg * 6 + r][c];
                    acc[r][0] += w * z0;
                    acc[r][1] += w * z1;
                }
            }
            #pragma unroll
            for (int r = 0; r < 6; ++r) {
                qkvH[rowg * 6 + r][pp] = acc[r][0];
                qkvH[rowg * 6 + r][pp + 32] = acc[r][1];
            }
        }
        __syncthreads();
        { // S[i][j] = 0.25*q_i.k_j + rel bias; thread: j = jj, i = ig+4l
            float accS[16];
            #pragma unroll
            for (int l = 0; l < 16; ++l) accS[l] = 0.f;
            for (int dd = 0; dd < 16; ++dd) {
                float kv = qkvH[16 + dd][jj];
                #pragma unroll
                for (int l = 0; l < 16; ++l)
                    accS[l] += qkvH[dd][ig + 4 * l] * kv;
            }
            #pragma unroll
            for (int l = 0; l < 16; ++l) {
                int i = ig + 4 * l;
                int di = (i >> 3) - (jj >> 3) + 7;
                int dj = (i & 7) - (jj & 7) + 7;
                SL[i][jj] = accS[l] * 0.25f + rel[(di * 15 + dj) * 16 + h];
            }
        }
        __syncthreads();
        if (t < 64) {
            float mx = -1e30f;
            for (int j2 = 0; j2 < 64; ++j2) mx = fmaxf(mx, SL[t][j2]);
            float s = 0.f;
            for (int j2 = 0; j2 < 64; ++j2) {
                float e = __expf(SL[t][j2] - mx);
                SL[t][j2] = e;
                s += e;
            }
            srow[t] = 1.0f / s;
        }
        __syncthreads();
        { // O[i][dd] = (sum_j e*v)/s ; thread: i = t&63, dd = (t>>6)*4 + l
            int i = t & 63, ddg = t >> 6;
            float o[4];
            #pragma unroll
            for (int l = 0; l < 4; ++l) o[l] = 0.f;
            for (int j2 = 0; j2 < 64; ++j2) {
                float a = SL[i][j2];
                #pragma unroll
                for (int l = 0; l < 4; ++l)
                    o[l] += a * qkvH[32 + ddg * 4 + l][j2];
            }
            float rs = srow[i];
            int gy = wy * 8 + (i >> 3), gx = wx * 8 + (i & 7);
            #pragma unroll
            for (int l = 0; l < 4; ++l) {
                int cch = h * 16 + ddg * 4 + l;
                A[((size_t)(b * 256 + cch) * 256 + gy) * 256 + gx] = o[l] * rs;
            }
        }
    }
}

// ---------------------------------------------------------------------------
// K7: L += avgpoolV(reflect-bottom-1, k=8, zeropad 3) + avgpoolH(reflect-right-1)
// grid: B*C*H*W/256 blocks
// ---------------------------------------------------------------------------
__global__ __launch_bounds__(256) void k7_pool(const float* __restrict__ A,
        float* __restrict__ L)
{
    size_t idx = (size_t)blockIdx.x * 256 + threadIdx.x;
    int j = (int)(idx & 255);
    int i = (int)((idx >> 8) & 255);
    size_t bc = idx >> 16;
    const float* Abc = A + (bc << 16);
    float sv = 0.f, sh = 0.f;
    #pragma unroll
    for (int u = 0; u < 8; ++u) {
        int r = i - 3 + u;
        if (r >= 0 && r <= 256) {
            int rr = (r == 256) ? 254 : r;
            sv += Abc[rr * 256 + j];
        }
        int c2 = j - 3 + u;
        if (c2 >= 0 && c2 <= 256) {
            int cc = (c2 == 256) ? 254 : c2;
            sh += Abc[i * 256 + cc];
        }
    }
    L[idx] += 0.125f * (sv + sh);
}

// ---------------------------------------------------------------------------
// K8: D = sp * dwconv8x8(pad_out(P), wdw, pad=3) + bp
//  P is conceptually 257x257 (reflect right/bottom by 1), zero outside
// grid: B*C*(16x16 tiles) = 131072 blocks, 256 threads (1 output each)
// ---------------------------------------------------------------------------
__global__ __launch_bounds__(256) void k8_dw(const float* __restrict__ P,
        const float* __restrict__ wdw, const float* __restrict__ sp,
        const float* __restrict__ bp, float* __restrict__ D)
{
    int blk = blockIdx.x;
    int tile = blk & 255;
    int c = (blk >> 8) & 255;
    int b = blk >> 16;
    int ty = tile >> 4, tx = tile & 15;
    int t = threadIdx.x;
    __shared__ float pT[23][24];
    __shared__ float wT[64];
    const float* Pc = P + ((size_t)(b * 256 + c) << 16);
    for (int i = t; i < 529; i += 256) {
        int yy = i / 23, xx = i - yy * 23;
        int gy = ty * 16 - 3 + yy, gx = tx * 16 - 3 + xx;
        float v = 0.f;
        if (gy >= 0 && gy <= 256 && gx >= 0 && gx <= 256) {
            int ry = (gy == 256) ? 254 : gy;
            int rx = (gx == 256) ? 254 : gx;
            v = Pc[ry * 256 + rx];
        }
        pT[yy][xx] = v;
    }
    if (t < 64) wT[t] = wdw[c * 64 + t];
    __syncthreads();
    int yy = t >> 4, xx = t & 15;
    float acc = 0.f;
    #pragma unroll
    for (int u = 0; u < 8; ++u)
        #pragma unroll
        for (int v = 0; v < 8; ++v)
            acc += wT[u * 8 + v] * pT[yy + u][xx + v];
    D[((size_t)(b * 256 + c) << 16) + (ty * 16 + yy) * 256 + tx * 16 + xx] =
        sp[c] * acc + bp[c];
}

// ---------------------------------------------------------------------------
// K9: out = wpw @ D  (1x1 conv, 256x256)
// grid: B * 4 coutTiles(64) * 1024 pxTiles(64) = 8192 blocks
// thread tile: 4 cout x 4 px
// ---------------------------------------------------------------------------
__global__ __launch_bounds__(256) void k9_pw(const float* __restrict__ D,
        const float* __restrict__ wpw, float* __restrict__ out)
{
    int blk = blockIdx.x;
    int pt = blk & 1023;
    int ct = (blk >> 10) & 3;
    int b = blk >> 12;
    int n0 = pt * 64;
    int t = threadIdx.x;
    __shared__ float DT[256][64];
    __shared__ float wT[64][257];
    for (int i = 0; i < 64; ++i) {
        int ci = i * 4 + (t >> 6);
        DT[ci][t & 63] = D[((size_t)(b * 256 + ci) << 16) + n0 + (t & 63)];
    }
    for (int i = 0; i < 64; ++i)
        wT[i][t] = wpw[(size_t)(ct * 64 + i) * 256 + t];
    __syncthreads();
    int cog = t >> 4, pxg = t & 15;
    float acc[4][4];
    #pragma unroll
    for (int a = 0; a < 4; ++a)
        #pragma unroll
        for (int p = 0; p < 4; ++p) acc[a][p] = 0.f;
    for (int ci = 0; ci < 256; ++ci) {
        float wv0 = wT[cog * 4 + 0][ci];
        float wv1 = wT[cog * 4 + 1][ci];
        float wv2 = wT[cog * 4 + 2][ci];
        float wv3 = wT[cog * 4 + 3][ci];
        #pragma unroll
        for (int p = 0; p < 4; ++p) {
            float dv = DT[ci][pxg * 4 + p];
            acc[0][p] += wv0 * dv;
            acc[1][p] += wv1 * dv;
            acc[2][p] += wv2 * dv;
            acc[3][p] += wv3 * dv;
        }
    }
    #pragma unroll
    for (int a = 0; a < 4; ++a) {
        int co = ct * 64 + cog * 4 + a;
        #pragma unroll
        for (int p = 0; p < 4; ++p) {
            out[((size_t)(b * 256 + co) << 16) + n0 + pxg * 4 + p] = acc[a][p];
        }
    }
}

// ---------------------------------------------------------------------------
extern "C" void kernel_launch(void* const* d_in, const int* in_sizes, int n_in,
                              void* d_out, int out_size, void* d_ws, size_t ws_size,
                              hipStream_t stream)
{
    (void)in_sizes; (void)n_in; (void)out_size; (void)ws_size;
    const float* x     = (const float*)d_in[0];
    const float* y     = (const float*)d_in[1];
    const float* gamma = (const float*)d_in[2];
    const float* la_wq = (const float*)d_in[3];
    const float* la_bq = (const float*)d_in[4];
    const float* la_wk = (const float*)d_in[5];
    const float* la_bk = (const float*)d_in[6];
    const float* la_wv = (const float*)d_in[7];
    const float* la_bv = (const float*)d_in[8];
    const float* wqkv  = (const float*)d_in[9];
    const float* wl1   = (const float*)d_in[10];
    const float* s1    = (const float*)d_in[11];
    const float* b1    = (const float*)d_in[12];
    const float* wl2   = (const float*)d_in[13];
    const float* s2    = (const float*)d_in[14];
    const float* b2    = (const float*)d_in[15];
    const float* rel   = (const float*)d_in[16];
    const float* wdw   = (const float*)d_in[17];
    const float* sp    = (const float*)d_in[18];
    const float* bp    = (const float*)d_in[19];
    const float* wpw   = (const float*)d_in[20];
    float* out = (float*)d_out;

    float* ws = (float*)d_ws;
    float* Q      = ws;                      // 4,194,304 floats
    float* Kn     = ws + 4194304;            // 4,194,304
    float* stats  = ws + 8388608;            // 40,960 region
    float* Ksum   = stats;                   // 64
    float* xsum   = stats + 64;              // 512
    float* KX     = stats + 576;             // 16,384
    float* matrix = stats + 16960;           // 16,384
    float* vsum   = stats + 33344;           // 512
    float* A      = ws + 8429568;            // 33,554,432 (attn out; later dw out)
    float* L      = A + 33554432;            // 33,554,432 (local; later local+pool)

    // zero the atomic accumulators (Ksum + xsum + KX = 16,960 floats)
    hipMemsetAsync(stats, 0, 16960 * sizeof(float), stream);

    k1_qk  <<<2048,   256, 0, stream>>>(x, la_wq, la_bq, la_wk, la_bk, Q, Kn);
    k2_kx  <<<256,    256, 0, stream>>>(x, Kn, KX, xsum, Ksum);
    k3_mat <<<2,      256, 0, stream>>>(la_wv, la_bv, KX, xsum, Ksum, matrix, vsum);
    k4_z   <<<2048,   256, 0, stream>>>(x, Q, matrix, vsum, Ksum, gamma, out); // z -> d_out
    k5_local<<<16384, 256, 0, stream>>>(y, wl1, s1, b1, wl2, s2, b2, L);
    k6_attn<<<2048,   256, 0, stream>>>(out, wqkv, rel, A);
    k7_pool<<<131072, 256, 0, stream>>>(A, L);                 // L += pooled(A)
    k8_dw  <<<131072, 256, 0, stream>>>(L, wdw, sp, bp, A);    // D aliases A
    k9_pw  <<<8192,   256, 0, stream>>>(A, wpw, out);          // final output
}

// Round 2
// 4506.196 us; speedup vs baseline: 2.3858x; 2.3858x over previous
//
#include <hip/hip_runtime.h>
#include <hip/hip_bf16.h>

#define DI __device__ __forceinline__

constexpr int Bc = 2, Cc = 256, Hc = 256, Wc = 256, Nc = Hc * Wc; // N=65536
constexpr float LA_EPS = 1e-6f;

typedef __attribute__((ext_vector_type(8))) short short8;
typedef __attribute__((ext_vector_type(4))) float floatx4;

DI ushort f2bf(float f) {
    uint u = __float_as_uint(f);
    uint r = (u + 0x7fff + ((u >> 16) & 1)) >> 16;
    return (ushort)r;
}

DI void gload16(const void* g, void* l) {
    __builtin_amdgcn_global_load_lds(
        (const __attribute__((address_space(1))) void*)g,
        (__attribute__((address_space(3))) void*)l, 16, 0, 0);
}

// ---------------------------------------------------------------------------
// K1: Q,K = 1x1 conv of x (32 ch each), L2-normalized over channel dim per pixel
// ---------------------------------------------------------------------------
__global__ __launch_bounds__(256) void k1_qk(const float* __restrict__ x,
        const float* __restrict__ wq, const float* __restrict__ bq,
        const float* __restrict__ wk, const float* __restrict__ bk,
        float* __restrict__ Qo, float* __restrict__ Ko)
{
    int b = blockIdx.x >> 10;
    int n0 = (blockIdx.x & 1023) * 64;
    int t = threadIdx.x;
    int px = t & 63, g = t >> 6;
    __shared__ float xT[256][64];
    __shared__ float qkT[64][65];
    __shared__ float rn[2][64];
    const float* xb = x + (size_t)b * Cc * Nc + n0;
    for (int i = 0; i < 64; ++i) {
        int c = i * 4 + g;
        xT[c][px] = xb[(size_t)c * Nc + px];
    }
    __syncthreads();
    float outv[16];
    #pragma unroll
    for (int j = 0; j < 16; ++j) {
        int oc = j * 4 + g;
        const float* wrow;
        float acc;
        if (oc < 32) { wrow = wq + oc * 256; acc = bq[oc]; }
        else         { wrow = wk + (oc - 32) * 256; acc = bk[oc - 32]; }
        for (int c = 0; c < 256; ++c) acc += wrow[c] * xT[c][px];
        outv[j] = acc;
        qkT[oc][px] = acc;
    }
    __syncthreads();
    if (t < 128) {
        int p = t & 63, which = t >> 6;
        float s = 0.f;
        #pragma unroll
        for (int m = 0; m < 32; ++m) { float v = qkT[which * 32 + m][p]; s += v * v; }
        rn[which][p] = 1.0f / sqrtf(s);
    }
    __syncthreads();
    #pragma unroll
    for (int j = 0; j < 16; ++j) {
        int oc = j * 4 + g;
        if (oc < 32) Qo[((size_t)b * 32 + oc) * Nc + n0 + px] = outv[j] * rn[0][px];
        else         Ko[((size_t)b * 32 + oc - 32) * Nc + n0 + px] = outv[j] * rn[1][px];
    }
}

// ---------------------------------------------------------------------------
// K2: KX[b,m,c] = sum_n K[b,m,n]*x[b,c,n]; xsum[b,c]; Ksum[b,m]  (atomics)
// ---------------------------------------------------------------------------
__global__ __launch_bounds__(256) void k2_kx(const float* __restrict__ x,
        const float* __restrict__ Kn, float* __restrict__ KX,
        float* __restrict__ xsum, float* __restrict__ Ksum)
{
    int b = blockIdx.x >> 7;
    int blk = blockIdx.x & 127;
    int t = threadIdx.x;
    int pxl = t & 63, g = t >> 6;
    __shared__ float xT[256][65];
    __shared__ float kT[32][64];
    float acc[32];
    #pragma unroll
    for (int m = 0; m < 32; ++m) acc[m] = 0.f;
    float xs = 0.f, ks = 0.f;
    for (int i = 0; i < 8; ++i) {
        int n0 = (blk + 128 * i) * 64;
        __syncthreads();
        for (int j = 0; j < 64; ++j) {
            int c = j * 4 + g;
            xT[c][pxl] = x[(size_t)(b * 256 + c) * Nc + n0 + pxl];
        }
        #pragma unroll
        for (int j = 0; j < 8; ++j) {
            int m = j * 4 + g;
            kT[m][pxl] = Kn[((size_t)b * 32 + m) * Nc + n0 + pxl];
        }
        __syncthreads();
        #pragma unroll 2
        for (int p = 0; p < 64; ++p) {
            float xv = xT[t][p];
            xs += xv;
            #pragma unroll
            for (int m = 0; m < 32; ++m) acc[m] += kT[m][p] * xv;
        }
        if (t < 32) {
            for (int p = 0; p < 64; ++p) ks += kT[t][p];
        }
    }
    atomicAdd(&xsum[b * 256 + t], xs);
    if (t < 32) atomicAdd(&Ksum[b * 32 + t], ks);
    #pragma unroll
    for (int m = 0; m < 32; ++m) atomicAdd(&KX[(b * 32 + m) * 256 + t], acc[m]);
}

// ---------------------------------------------------------------------------
// K3: matrix/vsum from KX, xsum, Ksum
// ---------------------------------------------------------------------------
__global__ __launch_bounds__(256) void k3_mat(const float* __restrict__ wv,
        const float* __restrict__ bv, const float* __restrict__ KX,
        const float* __restrict__ xsum, const float* __restrict__ Ksum,
        float* __restrict__ matrix, float* __restrict__ vsum)
{
    int b = blockIdx.x, t = threadIdx.x;
    __shared__ float sx[256];
    __shared__ float sk[32];
    __shared__ float skx[32][256];
    __shared__ float wT[256][65];
    sx[t] = xsum[b * 256 + t];
    if (t < 32) sk[t] = Ksum[b * 32 + t];
    for (int j = 0; j < 32; ++j) skx[j][t] = KX[(b * 32 + j) * 256 + t];
    float vs = bv[t] * (float)Nc;
    float mv[32];
    #pragma unroll
    for (int m = 0; m < 32; ++m) mv[m] = 0.f;
    for (int cc0 = 0; cc0 < 256; cc0 += 64) {
        __syncthreads();
        for (int i = 0; i < 64; ++i) {
            int c = i * 4 + (t >> 6);
            wT[c][t & 63] = wv[(size_t)c * 256 + cc0 + (t & 63)];
        }
        __syncthreads();
        for (int ccl = 0; ccl < 64; ++ccl) {
            float w = wT[t][ccl];
            int cc = cc0 + ccl;
            vs += w * sx[cc];
            #pragma unroll
            for (int m = 0; m < 32; ++m) mv[m] += w * skx[m][cc];
        }
    }
    vsum[b * 256 + t] = vs;
    float bvt = bv[t];
    for (int m = 0; m < 32; ++m) matrix[(b * 32 + m) * 256 + t] = mv[m] + bvt * sk[m];
}

// ---------------------------------------------------------------------------
// K4: z = x + gamma * (vsum[c] + sum_m Q[m,n]*matrix[m,c]) * tailor[n]
// ---------------------------------------------------------------------------
__global__ __launch_bounds__(256) void k4_z(const float* __restrict__ x,
        const float* __restrict__ Q, const float* __restrict__ matrix,
        const float* __restrict__ vsum, const float* __restrict__ Ksum,
        const float* __restrict__ gamma_p, float* __restrict__ z)
{
    int b = blockIdx.x >> 10;
    int n0 = (blockIdx.x & 1023) * 64;
    int t = threadIdx.x;
    int px = t & 63, g = t >> 6;
    __shared__ float qT[32][64];
    __shared__ float mat[32][256];
    __shared__ float vs[256];
    __shared__ float tail[64];
    __shared__ float sk[32];
    #pragma unroll
    for (int j = 0; j < 8; ++j) {
        int m = j * 4 + g;
        qT[m][px] = Q[((size_t)b * 32 + m) * Nc + n0 + px];
    }
    for (int j = 0; j < 32; ++j) {
        int idx = j * 256 + t;
        (&mat[0][0])[idx] = matrix[b * 8192 + idx];
    }
    vs[t] = vsum[b * 256 + t];
    if (t < 32) sk[t] = Ksum[b * 32 + t] + LA_EPS;
    __syncthreads();
    if (t < 64) {
        float s = 0.f;
        #pragma unroll
        for (int m = 0; m < 32; ++m) s += qT[m][t] * sk[m];
        tail[t] = 1.0f / ((float)Nc + s);
    }
    __syncthreads();
    float gamma = gamma_p[0];
    for (int l = 0; l < 64; ++l) {
        int c = l * 4 + g;
        float s = vs[c];
        #pragma unroll
        for (int m = 0; m < 32; ++m) s += qT[m][px] * mat[m][c];
        size_t idx = (size_t)(b * 256 + c) * Nc + n0 + px;
        z[idx] = x[idx] + gamma * s * tail[px];
    }
}

// ---------------------------------------------------------------------------
// KPREP_Y: y (NCHW f32) -> ybf (padded NHWC bf16, [b][258][258][256], origin +1)
// grid: 2*1024*8 = 16384 blocks, 256 threads; tile = 32ci x 64px
// ---------------------------------------------------------------------------
__global__ __launch_bounds__(256) void kprep_y(const float* __restrict__ y,
        ushort* __restrict__ ybf)
{
    int blk = blockIdx.x;
    int b = blk >> 13;
    int rest = blk & 8191;
    int ci0 = (rest & 7) * 32;
    int n0 = (rest >> 3) * 64;
    int row = n0 >> 8, x = n0 & 255;
    int t = threadIdx.x;
    __shared__ uint u[16][65];
    int px = t & 63, cig = t >> 6;
    const float* yb = y + (((size_t)(b * 256 + ci0 + cig * 8)) << 16) + n0 + px;
    #pragma unroll
    for (int jj = 0; jj < 4; ++jj) {
        float v0 = yb[((size_t)(jj * 2)) << 16];
        float v1 = yb[((size_t)(jj * 2 + 1)) << 16];
        u[cig * 4 + jj][px] = (uint)f2bf(v0) | ((uint)f2bf(v1) << 16);
    }
    __syncthreads();
    uint* out32 = (uint*)ybf;
    size_t pbase = (size_t)(row + 1) * 258 + (x + 1);
    int pr = t & 15, pg = t >> 4;
    #pragma unroll
    for (int g2 = 0; g2 < 4; ++g2) {
        int ppx = g2 * 16 + pg;
        size_t uidx = (((size_t)b * 258 * 258 * 256 + (pbase + ppx) * 256 + ci0) >> 1) + pr;
        out32[uidx] = u[pr][ppx];
    }
}

// ---------------------------------------------------------------------------
// KPREP_W: Wb[tap][co][ci] = bf16(wl1[co][ci][tap]*s1[co] + (tap==4)*wl2[co][ci]*s2[co])
// grid: 2304 blocks, 256 threads
// ---------------------------------------------------------------------------
__global__ __launch_bounds__(256) void kprep_w(const float* __restrict__ wl1,
        const float* __restrict__ s1, const float* __restrict__ wl2,
        const float* __restrict__ s2, ushort* __restrict__ Wb)
{
    int idx = blockIdx.x * 256 + threadIdx.x;
    int tp = idx >> 16;
    int r = idx & 65535;
    int co = r >> 8;
    float v = wl1[(size_t)r * 9 + tp] * s1[co];
    if (tp == 4) v += wl2[r] * s2[co];
    Wb[idx] = f2bf(v);
}

// ---------------------------------------------------------------------------
// K5 (MFMA): L = conv3x3(ybf, Wc) + bias   -- 1x1 branch folded into center tap
// M=co(256), N=128 px (one row segment), K=2304 (9 taps x 256 ci)
// grid: 2*256*2 = 1024 blocks, 512 threads (8 waves: 4 co-chunks x 2 px-chunks)
// ---------------------------------------------------------------------------
__global__ __launch_bounds__(512, 2) void k5_mfma(
        const ushort* __restrict__ ybf, const ushort* __restrict__ Wb,
        const float* __restrict__ b1, const float* __restrict__ b2,
        float* __restrict__ L)
{
    int blk = blockIdx.x;
    int b = blk >> 9;
    int y0 = (blk >> 1) & 255;
    int x0 = (blk & 1) << 7;
    int t = threadIdx.x;
    int lane = t & 63;
    int w = t >> 6;
    int wr = w >> 1;   // co chunk (64 co each)
    int wc = w & 1;    // px chunk (64 px each)

    __shared__ ushort sW[256 * 64];   // [co][ci] xor-swizzled, 32KB
    __shared__ ushort sY[128 * 64];   // [px][ci] xor-swizzled, 16KB

    floatx4 acc[4][4];
    #pragma unroll
    for (int m = 0; m < 4; ++m)
        #pragma unroll
        for (int n = 0; n < 4; ++n)
            acc[m][n] = {0.f, 0.f, 0.f, 0.f};

    const ushort* yb = ybf + (size_t)b * 258 * 258 * 256;
    int ldsWbase = w * 64 * 16;   // wave-uniform byte bases
    int ldsYbase = w * 64 * 16;

    for (int tp = 0; tp < 9; ++tp) {
        int dy = tp / 3 - 1, dx = tp % 3 - 1;
        const ushort* yrow = yb + ((size_t)(y0 + dy + 1) * 258 + (x0 + dx + 1)) * 256;
        const ushort* wtap = Wb + tp * 65536;
        for (int cb = 0; cb < 4; ++cb) {
            int ci0 = cb * 64;
            __syncthreads();
            // stage W: 256 rows x 8 chunks(16B) = 2048 chunks, 4 passes
            #pragma unroll
            for (int p = 0; p < 4; ++p) {
                int m = p * 512 + t;
                int row = m >> 3, ch = m & 7;
                const ushort* g = wtap + row * 256 + ci0 + ((ch ^ (row & 7)) << 3);
                gload16(g, (char*)sW + p * 512 * 16 + ldsWbase);
            }
            // stage Y: 128 rows x 8 chunks = 1024 chunks, 2 passes
            #pragma unroll
            for (int p = 0; p < 2; ++p) {
                int m = p * 512 + t;
                int pxr = m >> 3, ch = m & 7;
                const ushort* g = yrow + (size_t)pxr * 256 + ci0 + ((ch ^ (pxr & 7)) << 3);
                gload16(g, (char*)sY + p * 512 * 16 + ldsYbase);
            }
            __syncthreads();
            #pragma unroll
            for (int kk = 0; kk < 2; ++kk) {
                int chunkb = kk * 4 + (lane >> 4);
                short8 afr[4], bfr[4];
                #pragma unroll
                for (int m2 = 0; m2 < 4; ++m2) {
                    int row = wr * 64 + m2 * 16 + (lane & 15);
                    int ch = chunkb ^ (row & 7);
                    afr[m2] = *(const short8*)((const char*)sW + row * 128 + ch * 16);
                }
                #pragma unroll
                for (int n2 = 0; n2 < 4; ++n2) {
                    int row = wc * 64 + n2 * 16 + (lane & 15);
                    int ch = chunkb ^ (row & 7);
                    bfr[n2] = *(const short8*)((const char*)sY + row * 128 + ch * 16);
                }
                #pragma unroll
                for (int m2 = 0; m2 < 4; ++m2)
                    #pragma unroll
                    for (int n2 = 0; n2 < 4; ++n2)
                        acc[m2][n2] = __builtin_amdgcn_mfma_f32_16x16x32_bf16(
                            afr[m2], bfr[n2], acc[m2][n2], 0, 0, 0);
            }
        }
    }
    // epilogue: D row=co=(lane>>4)*4+r, col=px=lane&15
    int pxb = x0 + wc * 64 + (lane & 15);
    #pragma unroll
    for (int m2 = 0; m2 < 4; ++m2) {
        int cobase = wr * 64 + m2 * 16 + (lane >> 4) * 4;
        #pragma unroll
        for (int r = 0; r < 4; ++r) {
            int co = cobase + r;
            float bias = b1[co] + b2[co];
            float* dst = L + (((size_t)(b * 256 + co)) << 16) + y0 * 256 + pxb;
            #pragma unroll
            for (int n2 = 0; n2 < 4; ++n2)
                dst[n2 * 16] = acc[m2][n2][r] + bias;
        }
    }
}

// ---------------------------------------------------------------------------
// K6: fused qkv(1x1 conv of z) + 8x8 window attention (16 heads, d=16)
// ---------------------------------------------------------------------------
__global__ __launch_bounds__(256) void k6_attn(const float* __restrict__ z,
        const float* __restrict__ wqkv, const float* __restrict__ rel,
        float* __restrict__ A)
{
    int blk = blockIdx.x;
    int wx = blk & 31, wy = (blk >> 5) & 31, b = blk >> 10;
    int t = threadIdx.x;
    __shared__ float zW[64][257];
    __shared__ float wS[48][257];
    __shared__ float qkvH[48][66];
    __shared__ float SL[64][65];
    __shared__ float srow[64];
    {
        int px = t & 63, cg = t >> 6;
        int gy = wy * 8 + (px >> 3), gx = wx * 8 + (px & 7);
        const float* zb = z + (size_t)b * 256 * Nc + gy * 256 + gx;
        for (int i = 0; i < 64; ++i) {
            int c = i * 4 + cg;
            zW[px][c] = zb[(size_t)c * Nc];
        }
    }
    int pp = t & 31, rowg = t >> 5;
    int jj = t & 63, ig = t >> 6;
    for (int h = 0; h < 16; ++h) {
        __syncthreads();
        for (int rr = 0; rr < 48; ++rr) {
            int wrow = (rr >> 4) * 256 + h * 16 + (rr & 15);
            wS[rr][t] = wqkv[(size_t)wrow * 256 + t];
        }
        __syncthreads();
        {
            float acc[6][2];
            #pragma unroll
            for (int r = 0; r < 6; ++r) { acc[r][0] = 0.f; acc[r][1] = 0.f; }
            for (int c = 0; c < 256; ++c) {
                float z0 = zW[pp][c], z1 = zW[pp + 32][c];
                #pragma unroll
                for (int r = 0; r < 6; ++r) {
                    float w = wS[rowg * 6 + r][c];
                    acc[r][0] += w * z0;
                    acc[r][1] += w * z1;
                }
            }
            #pragma unroll
            for (int r = 0; r < 6; ++r) {
                qkvH[rowg * 6 + r][pp] = acc[r][0];
                qkvH[rowg * 6 + r][pp + 32] = acc[r][1];
            }
        }
        __syncthreads();
        {
            float accS[16];
            #pragma unroll
            for (int l = 0; l < 16; ++l) accS[l] = 0.f;
            for (int dd = 0; dd < 16; ++dd) {
                float kv = qkvH[16 + dd][jj];
                #pragma unroll
                for (int l = 0; l < 16; ++l)
                    accS[l] += qkvH[dd][ig + 4 * l] * kv;
            }
            #pragma unroll
            for (int l = 0; l < 16; ++l) {
                int i = ig + 4 * l;
                int di = (i >> 3) - (jj >> 3) + 7;
                int dj = (i & 7) - (jj & 7) + 7;
                SL[i][jj] = accS[l] * 0.25f + rel[(di * 15 + dj) * 16 + h];
            }
        }
        __syncthreads();
        if (t < 64) {
            float mx = -1e30f;
            for (int j2 = 0; j2 < 64; ++j2) mx = fmaxf(mx, SL[t][j2]);
            float s = 0.f;
            for (int j2 = 0; j2 < 64; ++j2) {
                float e = __expf(SL[t][j2] - mx);
                SL[t][j2] = e;
                s += e;
            }
            srow[t] = 1.0f / s;
        }
        __syncthreads();
        {
            int i = t & 63, ddg = t >> 6;
            float o[4];
            #pragma unroll
            for (int l = 0; l < 4; ++l) o[l] = 0.f;
            for (int j2 = 0; j2 < 64; ++j2) {
                float a = SL[i][j2];
                #pragma unroll
                for (int l = 0; l < 4; ++l)
                    o[l] += a * qkvH[32 + ddg * 4 + l][j2];
            }
            float rs = srow[i];
            int gy = wy * 8 + (i >> 3), gx = wx * 8 + (i & 7);
            #pragma unroll
            for (int l = 0; l < 4; ++l) {
                int cch = h * 16 + ddg * 4 + l;
                A[((size_t)(b * 256 + cch) * 256 + gy) * 256 + gx] = o[l] * rs;
            }
        }
    }
}

// ---------------------------------------------------------------------------
// K7: L += avgpools of A
// ---------------------------------------------------------------------------
__global__ __launch_bounds__(256) void k7_pool(const float* __restrict__ A,
        float* __restrict__ L)
{
    size_t idx = (size_t)blockIdx.x * 256 + threadIdx.x;
    int j = (int)(idx & 255);
    int i = (int)((idx >> 8) & 255);
    size_t bc = idx >> 16;
    const float* Abc = A + (bc << 16);
    float sv = 0.f, sh = 0.f;
    #pragma unroll
    for (int u = 0; u < 8; ++u) {
        int r = i - 3 + u;
        if (r >= 0 && r <= 256) {
            int rr = (r == 256) ? 254 : r;
            sv += Abc[rr * 256 + j];
        }
        int c2 = j - 3 + u;
        if (c2 >= 0 && c2 <= 256) {
            int cc = (c2 == 256) ? 254 : c2;
            sh += Abc[i * 256 + cc];
        }
    }
    L[idx] += 0.125f * (sv + sh);
}

// ---------------------------------------------------------------------------
// K8: D = sp * dwconv8x8(pad_out(P), wdw, pad=3) + bp
// ---------------------------------------------------------------------------
__global__ __launch_bounds__(256) void k8_dw(const float* __restrict__ P,
        const float* __restrict__ wdw, const float* __restrict__ sp,
        const float* __restrict__ bp, float* __restrict__ D)
{
    int blk = blockIdx.x;
    int tile = blk & 255;
    int c = (blk >> 8) & 255;
    int b = blk >> 16;
    int ty = tile >> 4, tx = tile & 15;
    int t = threadIdx.x;
    __shared__ float pT[23][24];
    __shared__ float wT[64];
    const float* Pc = P + ((size_t)(b * 256 + c) << 16);
    for (int i = t; i < 529; i += 256) {
        int yy = i / 23, xx = i - yy * 23;
        int gy = ty * 16 - 3 + yy, gx = tx * 16 - 3 + xx;
        float v = 0.f;
        if (gy >= 0 && gy <= 256 && gx >= 0 && gx <= 256) {
            int ry = (gy == 256) ? 254 : gy;
            int rx = (gx == 256) ? 254 : gx;
            v = Pc[ry * 256 + rx];
        }
        pT[yy][xx] = v;
    }
    if (t < 64) wT[t] = wdw[c * 64 + t];
    __syncthreads();
    int yy = t >> 4, xx = t & 15;
    float acc = 0.f;
    #pragma unroll
    for (int u = 0; u < 8; ++u)
        #pragma unroll
        for (int v = 0; v < 8; ++v)
            acc += wT[u * 8 + v] * pT[yy + u][xx + v];
    D[((size_t)(b * 256 + c) << 16) + (ty * 16 + yy) * 256 + tx * 16 + xx] =
        sp[c] * acc + bp[c];
}

// ---------------------------------------------------------------------------
// K9: out = wpw @ D  (1x1 conv, 256x256)
// ---------------------------------------------------------------------------
__global__ __launch_bounds__(256) void k9_pw(const float* __restrict__ D,
        const float* __restrict__ wpw, float* __restrict__ out)
{
    int blk = blockIdx.x;
    int pt = blk & 1023;
    int ct = (blk >> 10) & 3;
    int b = blk >> 12;
    int n0 = pt * 64;
    int t = threadIdx.x;
    __shared__ float DT[256][64];
    __shared__ float wT[64][257];
    for (int i = 0; i < 64; ++i) {
        int ci = i * 4 + (t >> 6);
        DT[ci][t & 63] = D[((size_t)(b * 256 + ci) << 16) + n0 + (t & 63)];
    }
    for (int i = 0; i < 64; ++i)
        wT[i][t] = wpw[(size_t)(ct * 64 + i) * 256 + t];
    __syncthreads();
    int cog = t >> 4, pxg = t & 15;
    float acc[4][4];
    #pragma unroll
    for (int a = 0; a < 4; ++a)
        #pragma unroll
        for (int p = 0; p < 4; ++p) acc[a][p] = 0.f;
    for (int ci = 0; ci < 256; ++ci) {
        float wv0 = wT[cog * 4 + 0][ci];
        float wv1 = wT[cog * 4 + 1][ci];
        float wv2 = wT[cog * 4 + 2][ci];
        float wv3 = wT[cog * 4 + 3][ci];
        #pragma unroll
        for (int p = 0; p < 4; ++p) {
            float dv = DT[ci][pxg * 4 + p];
            acc[0][p] += wv0 * dv;
            acc[1][p] += wv1 * dv;
            acc[2][p] += wv2 * dv;
            acc[3][p] += wv3 * dv;
        }
    }
    #pragma unroll
    for (int a = 0; a < 4; ++a) {
        int co = ct * 64 + cog * 4 + a;
        #pragma unroll
        for (int p = 0; p < 4; ++p) {
            out[((size_t)(b * 256 + co) << 16) + n0 + pxg * 4 + p] = acc[a][p];
        }
    }
}

// ---------------------------------------------------------------------------
extern "C" void kernel_launch(void* const* d_in, const int* in_sizes, int n_in,
                              void* d_out, int out_size, void* d_ws, size_t ws_size,
                              hipStream_t stream)
{
    (void)in_sizes; (void)n_in; (void)out_size; (void)ws_size;
    const float* x     = (const float*)d_in[0];
    const float* y     = (const float*)d_in[1];
    const float* gamma = (const float*)d_in[2];
    const float* la_wq = (const float*)d_in[3];
    const float* la_bq = (const float*)d_in[4];
    const float* la_wk = (const float*)d_in[5];
    const float* la_bk = (const float*)d_in[6];
    const float* la_wv = (const float*)d_in[7];
    const float* la_bv = (const float*)d_in[8];
    const float* wqkv  = (const float*)d_in[9];
    const float* wl1   = (const float*)d_in[10];
    const float* s1    = (const float*)d_in[11];
    const float* b1    = (const float*)d_in[12];
    const float* wl2   = (const float*)d_in[13];
    const float* s2    = (const float*)d_in[14];
    const float* b2    = (const float*)d_in[15];
    const float* rel   = (const float*)d_in[16];
    const float* wdw   = (const float*)d_in[17];
    const float* sp    = (const float*)d_in[18];
    const float* bp    = (const float*)d_in[19];
    const float* wpw   = (const float*)d_in[20];
    float* out = (float*)d_out;

    float* ws = (float*)d_ws;
    float* Q      = ws;                      // 4,194,304 floats
    float* Kn     = ws + 4194304;            // 4,194,304 (reused as Wb after k2)
    float* stats  = ws + 8388608;
    float* Ksum   = stats;
    float* xsum   = stats + 64;
    float* KX     = stats + 576;
    float* matrix = stats + 16960;
    float* vsum   = stats + 33344;
    float* A      = ws + 8429568;            // 33,554,432 floats (ybf alias; attn; dw out)
    float* L      = A + 33554432;            // 33,554,432 floats

    ushort* Wb  = (ushort*)Kn;               // 589,824 bf16 (1.18 MB) — after k2
    ushort* ybf = (ushort*)A;                // 34,080,768 bf16 (68.2 MB) — until k6

    hipMemsetAsync(stats, 0, 16960 * sizeof(float), stream);
    hipMemsetAsync(ybf, 0, (size_t)2 * 258 * 258 * 256 * sizeof(ushort), stream);

    kprep_y<<<16384, 256, 0, stream>>>(y, ybf);
    k1_qk  <<<2048,  256, 0, stream>>>(x, la_wq, la_bq, la_wk, la_bk, Q, Kn);
    k2_kx  <<<256,   256, 0, stream>>>(x, Kn, KX, xsum, Ksum);
    kprep_w<<<2304,  256, 0, stream>>>(wl1, s1, wl2, s2, Wb);   // Kn dead after k2
    k3_mat <<<2,     256, 0, stream>>>(la_wv, la_bv, KX, xsum, Ksum, matrix, vsum);
    k4_z   <<<2048,  256, 0, stream>>>(x, Q, matrix, vsum, Ksum, gamma, out);
    k5_mfma<<<1024,  512, 0, stream>>>(ybf, Wb, b1, b2, L);
    k6_attn<<<2048,  256, 0, stream>>>(out, wqkv, rel, A);      // overwrites ybf region
    k7_pool<<<131072,256, 0, stream>>>(A, L);
    k8_dw  <<<131072,256, 0, stream>>>(L, wdw, sp, bp, A);
    k9_pw  <<<8192,  256, 0, stream>>>(A, wpw, out);
}

// Round 3
// 2767.008 us; speedup vs baseline: 3.8854x; 1.6285x over previous
//
#include <hip/hip_runtime.h>
#include <hip/hip_bf16.h>

#define DI __device__ __forceinline__

constexpr int Bc = 2, Cc = 256, Hc = 256, Wc = 256, Nc = Hc * Wc; // N=65536
constexpr float LA_EPS = 1e-6f;

typedef __attribute__((ext_vector_type(8))) short short8;
typedef __attribute__((ext_vector_type(4))) float floatx4;
typedef __attribute__((ext_vector_type(16))) float floatx16;

DI ushort f2bf(float f) {
    uint u = __float_as_uint(f);
    uint r = (u + 0x7fff + ((u >> 16) & 1)) >> 16;
    return (ushort)r;
}

DI uint pack2(float a, float b) {
    return (uint)f2bf(a) | ((uint)f2bf(b) << 16);
}

DI void gload16(const void* g, void* l) {
    __builtin_amdgcn_global_load_lds(
        (const __attribute__((address_space(1))) void*)g,
        (__attribute__((address_space(3))) void*)l, 16, 0, 0);
}

// ---------------------------------------------------------------------------
// K1: Q,K = 1x1 conv of x (32 ch each), L2-normalized over channel dim per pixel
// ---------------------------------------------------------------------------
__global__ __launch_bounds__(256) void k1_qk(const float* __restrict__ x,
        const float* __restrict__ wq, const float* __restrict__ bq,
        const float* __restrict__ wk, const float* __restrict__ bk,
        float* __restrict__ Qo, float* __restrict__ Ko)
{
    int b = blockIdx.x >> 10;
    int n0 = (blockIdx.x & 1023) * 64;
    int t = threadIdx.x;
    int px = t & 63, g = t >> 6;
    __shared__ float xT[256][64];
    __shared__ float qkT[64][65];
    __shared__ float rn[2][64];
    const float* xb = x + (size_t)b * Cc * Nc + n0;
    for (int i = 0; i < 64; ++i) {
        int c = i * 4 + g;
        xT[c][px] = xb[(size_t)c * Nc + px];
    }
    __syncthreads();
    float outv[16];
    #pragma unroll
    for (int j = 0; j < 16; ++j) {
        int oc = j * 4 + g;
        const float* wrow;
        float acc;
        if (oc < 32) { wrow = wq + oc * 256; acc = bq[oc]; }
        else         { wrow = wk + (oc - 32) * 256; acc = bk[oc - 32]; }
        for (int c = 0; c < 256; ++c) acc += wrow[c] * xT[c][px];
        outv[j] = acc;
        qkT[oc][px] = acc;
    }
    __syncthreads();
    if (t < 128) {
        int p = t & 63, which = t >> 6;
        float s = 0.f;
        #pragma unroll
        for (int m = 0; m < 32; ++m) { float v = qkT[which * 32 + m][p]; s += v * v; }
        rn[which][p] = 1.0f / sqrtf(s);
    }
    __syncthreads();
    #pragma unroll
    for (int j = 0; j < 16; ++j) {
        int oc = j * 4 + g;
        if (oc < 32) Qo[((size_t)b * 32 + oc) * Nc + n0 + px] = outv[j] * rn[0][px];
        else         Ko[((size_t)b * 32 + oc - 32) * Nc + n0 + px] = outv[j] * rn[1][px];
    }
}

// ---------------------------------------------------------------------------
// K2: KX[b,m,c] = sum_n K[b,m,n]*x[b,c,n]; xsum[b,c]; Ksum[b,m]  (atomics)
// ---------------------------------------------------------------------------
__global__ __launch_bounds__(256) void k2_kx(const float* __restrict__ x,
        const float* __restrict__ Kn, float* __restrict__ KX,
        float* __restrict__ xsum, float* __restrict__ Ksum)
{
    int b = blockIdx.x >> 7;
    int blk = blockIdx.x & 127;
    int t = threadIdx.x;
    int pxl = t & 63, g = t >> 6;
    __shared__ float xT[256][65];
    __shared__ float kT[32][64];
    float acc[32];
    #pragma unroll
    for (int m = 0; m < 32; ++m) acc[m] = 0.f;
    float xs = 0.f, ks = 0.f;
    for (int i = 0; i < 8; ++i) {
        int n0 = (blk + 128 * i) * 64;
        __syncthreads();
        for (int j = 0; j < 64; ++j) {
            int c = j * 4 + g;
            xT[c][pxl] = x[(size_t)(b * 256 + c) * Nc + n0 + pxl];
        }
        #pragma unroll
        for (int j = 0; j < 8; ++j) {
            int m = j * 4 + g;
            kT[m][pxl] = Kn[((size_t)b * 32 + m) * Nc + n0 + pxl];
        }
        __syncthreads();
        #pragma unroll 2
        for (int p = 0; p < 64; ++p) {
            float xv = xT[t][p];
            xs += xv;
            #pragma unroll
            for (int m = 0; m < 32; ++m) acc[m] += kT[m][p] * xv;
        }
        if (t < 32) {
            for (int p = 0; p < 64; ++p) ks += kT[t][p];
        }
    }
    atomicAdd(&xsum[b * 256 + t], xs);
    if (t < 32) atomicAdd(&Ksum[b * 32 + t], ks);
    #pragma unroll
    for (int m = 0; m < 32; ++m) atomicAdd(&KX[(b * 32 + m) * 256 + t], acc[m]);
}

// ---------------------------------------------------------------------------
// K3: matrix/vsum from KX, xsum, Ksum
// ---------------------------------------------------------------------------
__global__ __launch_bounds__(256) void k3_mat(const float* __restrict__ wv,
        const float* __restrict__ bv, const float* __restrict__ KX,
        const float* __restrict__ xsum, const float* __restrict__ Ksum,
        float* __restrict__ matrix, float* __restrict__ vsum)
{
    int b = blockIdx.x, t = threadIdx.x;
    __shared__ float sx[256];
    __shared__ float sk[32];
    __shared__ float skx[32][256];
    __shared__ float wT[256][65];
    sx[t] = xsum[b * 256 + t];
    if (t < 32) sk[t] = Ksum[b * 32 + t];
    for (int j = 0; j < 32; ++j) skx[j][t] = KX[(b * 32 + j) * 256 + t];
    float vs = bv[t] * (float)Nc;
    float mv[32];
    #pragma unroll
    for (int m = 0; m < 32; ++m) mv[m] = 0.f;
    for (int cc0 = 0; cc0 < 256; cc0 += 64) {
        __syncthreads();
        for (int i = 0; i < 64; ++i) {
            int c = i * 4 + (t >> 6);
            wT[c][t & 63] = wv[(size_t)c * 256 + cc0 + (t & 63)];
        }
        __syncthreads();
        for (int ccl = 0; ccl < 64; ++ccl) {
            float w = wT[t][ccl];
            int cc = cc0 + ccl;
            vs += w * sx[cc];
            #pragma unroll
            for (int m = 0; m < 32; ++m) mv[m] += w * skx[m][cc];
        }
    }
    vsum[b * 256 + t] = vs;
    float bvt = bv[t];
    for (int m = 0; m < 32; ++m) matrix[(b * 32 + m) * 256 + t] = mv[m] + bvt * sk[m];
}

// ---------------------------------------------------------------------------
// K4: z = x + gamma * (vsum[c] + sum_m Q[m,n]*matrix[m,c]) * tailor[n]
// ---------------------------------------------------------------------------
__global__ __launch_bounds__(256) void k4_z(const float* __restrict__ x,
        const float* __restrict__ Q, const float* __restrict__ matrix,
        const float* __restrict__ vsum, const float* __restrict__ Ksum,
        const float* __restrict__ gamma_p, float* __restrict__ z)
{
    int b = blockIdx.x >> 10;
    int n0 = (blockIdx.x & 1023) * 64;
    int t = threadIdx.x;
    int px = t & 63, g = t >> 6;
    __shared__ float qT[32][64];
    __shared__ float mat[32][256];
    __shared__ float vs[256];
    __shared__ float tail[64];
    __shared__ float sk[32];
    #pragma unroll
    for (int j = 0; j < 8; ++j) {
        int m = j * 4 + g;
        qT[m][px] = Q[((size_t)b * 32 + m) * Nc + n0 + px];
    }
    for (int j = 0; j < 32; ++j) {
        int idx = j * 256 + t;
        (&mat[0][0])[idx] = matrix[b * 8192 + idx];
    }
    vs[t] = vsum[b * 256 + t];
    if (t < 32) sk[t] = Ksum[b * 32 + t] + LA_EPS;
    __syncthreads();
    if (t < 64) {
        float s = 0.f;
        #pragma unroll
        for (int m = 0; m < 32; ++m) s += qT[m][t] * sk[m];
        tail[t] = 1.0f / ((float)Nc + s);
    }
    __syncthreads();
    float gamma = gamma_p[0];
    for (int l = 0; l < 64; ++l) {
        int c = l * 4 + g;
        float s = vs[c];
        #pragma unroll
        for (int m = 0; m < 32; ++m) s += qT[m][px] * mat[m][c];
        size_t idx = (size_t)(b * 256 + c) * Nc + n0 + px;
        z[idx] = x[idx] + gamma * s * tail[px];
    }
}

// ---------------------------------------------------------------------------
// KPREP_Y: y (NCHW f32) -> ybf (padded NHWC bf16, [b][258][258][256], origin +1)
// ---------------------------------------------------------------------------
__global__ __launch_bounds__(256) void kprep_y(const float* __restrict__ y,
        ushort* __restrict__ ybf)
{
    int blk = blockIdx.x;
    int b = blk >> 13;
    int rest = blk & 8191;
    int ci0 = (rest & 7) * 32;
    int n0 = (rest >> 3) * 64;
    int row = n0 >> 8, x = n0 & 255;
    int t = threadIdx.x;
    __shared__ uint u[16][65];
    int px = t & 63, cig = t >> 6;
    const float* yb = y + (((size_t)(b * 256 + ci0 + cig * 8)) << 16) + n0 + px;
    #pragma unroll
    for (int jj = 0; jj < 4; ++jj) {
        float v0 = yb[((size_t)(jj * 2)) << 16];
        float v1 = yb[((size_t)(jj * 2 + 1)) << 16];
        u[cig * 4 + jj][px] = (uint)f2bf(v0) | ((uint)f2bf(v1) << 16);
    }
    __syncthreads();
    uint* out32 = (uint*)ybf;
    size_t pbase = (size_t)(row + 1) * 258 + (x + 1);
    int pr = t & 15, pg = t >> 4;
    #pragma unroll
    for (int g2 = 0; g2 < 4; ++g2) {
        int ppx = g2 * 16 + pg;
        size_t uidx = (((size_t)b * 258 * 258 * 256 + (pbase + ppx) * 256 + ci0) >> 1) + pr;
        out32[uidx] = u[pr][ppx];
    }
}

// ---------------------------------------------------------------------------
// KPREP_W: Wb[tap][co][ci] = bf16(wl1[co][ci][tap]*s1[co] + (tap==4)*wl2[co][ci]*s2[co])
// ---------------------------------------------------------------------------
__global__ __launch_bounds__(256) void kprep_w(const float* __restrict__ wl1,
        const float* __restrict__ s1, const float* __restrict__ wl2,
        const float* __restrict__ s2, ushort* __restrict__ Wb)
{
    int idx = blockIdx.x * 256 + threadIdx.x;
    int tp = idx >> 16;
    int r = idx & 65535;
    int co = r >> 8;
    float v = wl1[(size_t)r * 9 + tp] * s1[co];
    if (tp == 4) v += wl2[r] * s2[co];
    Wb[idx] = f2bf(v);
}

// ---------------------------------------------------------------------------
// KPREP_QW: Wqb = bf16(wqkv), q rows (0..255) pre-scaled by 0.25 (= d^-0.5)
// ---------------------------------------------------------------------------
__global__ __launch_bounds__(256) void kprep_qw(const float* __restrict__ wqkv,
        ushort* __restrict__ Wqb)
{
    int idx = blockIdx.x * 256 + threadIdx.x;   // 768*256 = 196608
    float v = wqkv[idx];
    if (idx < 65536) v *= 0.25f;
    Wqb[idx] = f2bf(v);
}

// ---------------------------------------------------------------------------
// K5 (MFMA): L = conv3x3(ybf, Wc) + bias   -- 1x1 branch folded into center tap
// ---------------------------------------------------------------------------
__global__ __launch_bounds__(512, 2) void k5_mfma(
        const ushort* __restrict__ ybf, const ushort* __restrict__ Wb,
        const float* __restrict__ b1, const float* __restrict__ b2,
        float* __restrict__ L)
{
    int blk = blockIdx.x;
    int b = blk >> 9;
    int y0 = (blk >> 1) & 255;
    int x0 = (blk & 1) << 7;
    int t = threadIdx.x;
    int lane = t & 63;
    int w = t >> 6;
    int wr = w >> 1;
    int wc = w & 1;

    __shared__ ushort sW[256 * 64];
    __shared__ ushort sY[128 * 64];

    floatx4 acc[4][4];
    #pragma unroll
    for (int m = 0; m < 4; ++m)
        #pragma unroll
        for (int n = 0; n < 4; ++n)
            acc[m][n] = {0.f, 0.f, 0.f, 0.f};

    const ushort* yb = ybf + (size_t)b * 258 * 258 * 256;
    int ldsWbase = w * 64 * 16;
    int ldsYbase = w * 64 * 16;

    for (int tp = 0; tp < 9; ++tp) {
        int dy = tp / 3 - 1, dx = tp % 3 - 1;
        const ushort* yrow = yb + ((size_t)(y0 + dy + 1) * 258 + (x0 + dx + 1)) * 256;
        const ushort* wtap = Wb + tp * 65536;
        for (int cb = 0; cb < 4; ++cb) {
            int ci0 = cb * 64;
            __syncthreads();
            #pragma unroll
            for (int p = 0; p < 4; ++p) {
                int m = p * 512 + t;
                int row = m >> 3, ch = m & 7;
                const ushort* g = wtap + row * 256 + ci0 + ((ch ^ (row & 7)) << 3);
                gload16(g, (char*)sW + p * 512 * 16 + ldsWbase);
            }
            #pragma unroll
            for (int p = 0; p < 2; ++p) {
                int m = p * 512 + t;
                int pxr = m >> 3, ch = m & 7;
                const ushort* g = yrow + (size_t)pxr * 256 + ci0 + ((ch ^ (pxr & 7)) << 3);
                gload16(g, (char*)sY + p * 512 * 16 + ldsYbase);
            }
            __syncthreads();
            #pragma unroll
            for (int kk = 0; kk < 2; ++kk) {
                int chunkb = kk * 4 + (lane >> 4);
                short8 afr[4], bfr[4];
                #pragma unroll
                for (int m2 = 0; m2 < 4; ++m2) {
                    int row = wr * 64 + m2 * 16 + (lane & 15);
                    int ch = chunkb ^ (row & 7);
                    afr[m2] = *(const short8*)((const char*)sW + row * 128 + ch * 16);
                }
                #pragma unroll
                for (int n2 = 0; n2 < 4; ++n2) {
                    int row = wc * 64 + n2 * 16 + (lane & 15);
                    int ch = chunkb ^ (row & 7);
                    bfr[n2] = *(const short8*)((const char*)sY + row * 128 + ch * 16);
                }
                #pragma unroll
                for (int m2 = 0; m2 < 4; ++m2)
                    #pragma unroll
                    for (int n2 = 0; n2 < 4; ++n2)
                        acc[m2][n2] = __builtin_amdgcn_mfma_f32_16x16x32_bf16(
                            afr[m2], bfr[n2], acc[m2][n2], 0, 0, 0);
            }
        }
    }
    int pxb = x0 + wc * 64 + (lane & 15);
    #pragma unroll
    for (int m2 = 0; m2 < 4; ++m2) {
        int cobase = wr * 64 + m2 * 16 + (lane >> 4) * 4;
        #pragma unroll
        for (int r = 0; r < 4; ++r) {
            int co = cobase + r;
            float bias = b1[co] + b2[co];
            float* dst = L + (((size_t)(b * 256 + co)) << 16) + y0 * 256 + pxb;
            #pragma unroll
            for (int n2 = 0; n2 < 4; ++n2)
                dst[n2 * 16] = acc[m2][n2][r] + bias;
        }
    }
}

// ---------------------------------------------------------------------------
// K6 (MFMA, fused): qkv projection + 8x8 window attention, one block per window
// 512 threads = 8 waves; wave w handles heads 2w, 2w+1 independently.
// ---------------------------------------------------------------------------
__global__ __launch_bounds__(512, 2) void k6_mfma(const float* __restrict__ z,
        const ushort* __restrict__ Wqb, const float* __restrict__ rel,
        float* __restrict__ A)
{
    int blk = blockIdx.x;
    int wx = blk & 31, wy = (blk >> 5) & 31, b = blk >> 10;
    int t = threadIdx.x;
    int lane = t & 63;
    int w = t >> 6;

    __shared__ ushort zT[64 * 256];      // [px][ci] bf16, xor-swizzled (32 KB)
    __shared__ float srel[3600];         // rel bias table (14.4 KB)
    __shared__ ushort wbuf[8][4096];     // per-wave: qT[0,1024) kT[1024,2048) vD[2048,4096)

    char* zTc = (char*)zT;

    // ---- stage z window (f32 -> bf16, swizzled) + rel table ----
    #pragma unroll
    for (int i = 0; i < 16; ++i) {
        int idx = i * 512 + t;
        int cp = idx >> 6;          // ci pair 0..127
        int px = idx & 63;
        int gy = wy * 8 + (px >> 3), gx = wx * 8 + (px & 7);
        const float* zp = z + ((size_t)(b * 256 + cp * 2) << 16) + gy * 256 + gx;
        uint pv = pack2(zp[0], zp[1ull << 16]);
        *(uint*)(zTc + px * 512 + (((cp >> 2) ^ (px & 7)) << 4) + (cp & 3) * 4) = pv;
    }
    for (int i = t; i < 3600; i += 512) srel[i] = rel[i];
    __syncthreads();

    char* qTb = (char*)&wbuf[w][0];
    char* kTb = (char*)&wbuf[w][1024];
    char* vDb = (char*)&wbuf[w][2048];

    int l15 = lane & 15, l4 = lane >> 4;
    int l31 = lane & 31, l5 = lane >> 5;
    bool hilane = (l5 != 0);

    for (int hrep = 0; hrep < 2; ++hrep) {
        int h = w * 2 + hrep;

        // ---- q-GEMM: D[d][px] = 0.25*Wq_h @ z ----
        floatx4 qacc[4] = {};
        #pragma unroll
        for (int ks = 0; ks < 8; ++ks) {
            short8 aw = *(const short8*)(Wqb + ((h * 16 + l15) << 8) + ks * 32 + (l4 << 3));
            #pragma unroll
            for (int n = 0; n < 4; ++n) {
                int px = n * 16 + l15;
                short8 bz = *(const short8*)(zTc + px * 512 + (((ks * 4 + l4) ^ (px & 7)) << 4));
                qacc[n] = __builtin_amdgcn_mfma_f32_16x16x32_bf16(aw, bz, qacc[n], 0, 0, 0);
            }
        }
        #pragma unroll
        for (int n = 0; n < 4; ++n) {   // qT[px][d] (row 32B)
            int px = n * 16 + l15;
            uint2 wv = { pack2(qacc[n][0], qacc[n][1]), pack2(qacc[n][2], qacc[n][3]) };
            *(uint2*)(qTb + px * 32 + (l4 << 3)) = wv;
        }

        // ---- kT-GEMM: D[px][d] = z^T @ Wk_h^T ----
        floatx4 kacc[4] = {};
        #pragma unroll
        for (int ks = 0; ks < 8; ++ks) {
            short8 bw = *(const short8*)(Wqb + ((256 + h * 16 + l15) << 8) + ks * 32 + (l4 << 3));
            #pragma unroll
            for (int m = 0; m < 4; ++m) {
                int px = m * 16 + l15;
                short8 az = *(const short8*)(zTc + px * 512 + (((ks * 4 + l4) ^ (px & 7)) << 4));
                kacc[m] = __builtin_amdgcn_mfma_f32_16x16x32_bf16(az, bw, kacc[m], 0, 0, 0);
            }
        }
        #pragma unroll
        for (int m = 0; m < 4; ++m) {   // kT[px][d], d = l15
            #pragma unroll
            for (int r = 0; r < 4; ++r) {
                int px = m * 16 + l4 * 4 + r;
                *(ushort*)(kTb + px * 32 + l15 * 2) = f2bf(kacc[m][r]);
            }
        }

        // ---- v-GEMM: vD[d][px] = Wv_h @ z  (rows 16..31 garbage-padded) ----
        floatx4 vacc[4] = {};
        #pragma unroll
        for (int ks = 0; ks < 8; ++ks) {
            short8 aw = *(const short8*)(Wqb + ((512 + h * 16 + l15) << 8) + ks * 32 + (l4 << 3));
            #pragma unroll
            for (int n = 0; n < 4; ++n) {
                int px = n * 16 + l15;
                short8 bz = *(const short8*)(zTc + px * 512 + (((ks * 4 + l4) ^ (px & 7)) << 4));
                vacc[n] = __builtin_amdgcn_mfma_f32_16x16x32_bf16(aw, bz, vacc[n], 0, 0, 0);
            }
        }
        #pragma unroll
        for (int n = 0; n < 4; ++n) {   // vD[d][px] swizzled rows of 128B
            int px = n * 16 + l15;
            #pragma unroll
            for (int r = 0; r < 4; ++r) {
                int d = l4 * 4 + r;
                *(ushort*)(vDb + d * 128 + ((((px >> 3) ^ (d & 7)) << 4) + (px & 7) * 2)) = f2bf(vacc[n][r]);
            }
        }

        // ---- S^T: st[jt][it], 32x32x16 MFMAs (K = d = 16) ----
        floatx16 st[2][2];
        short8 bq[2];
        #pragma unroll
        for (int it = 0; it < 2; ++it)
            bq[it] = *(const short8*)(qTb + (it * 32 + l31) * 32 + (l5 << 4));
        #pragma unroll
        for (int jt = 0; jt < 2; ++jt) {
            short8 ak = *(const short8*)(kTb + (jt * 32 + l31) * 32 + (l5 << 4));
            #pragma unroll
            for (int it = 0; it < 2; ++it) {
                floatx16 zc = {};
                st[jt][it] = __builtin_amdgcn_mfma_f32_32x32x16_bf16(ak, bq[it], zc, 0, 0, 0);
            }
        }

        // ---- bias + softmax (over j) ----
        // lane holds col i = it*32 + l31; rows j = jt*32 + (r&3)+8*(r>>2)+4*l5
        float rinv[2];
        #pragma unroll
        for (int it = 0; it < 2; ++it) {
            int i = it * 32 + l31;
            int Ai = (i >> 3) * 15 + (i & 7) + 112;
            float mx = -1e30f;
            #pragma unroll
            for (int jt = 0; jt < 2; ++jt)
                #pragma unroll
                for (int r = 0; r < 16; ++r) {
                    int j = jt * 32 + (r & 3) + 8 * (r >> 2) + 4 * l5;
                    int Bjr = (j >> 3) * 15 + (j & 7);
                    float s = st[jt][it][r] + srel[(Ai - Bjr) * 16 + h];
                    st[jt][it][r] = s;
                    mx = fmaxf(mx, s);
                }
            mx = fmaxf(mx, __shfl_xor(mx, 32));
            float sum = 0.f;
            #pragma unroll
            for (int jt = 0; jt < 2; ++jt)
                #pragma unroll
                for (int r = 0; r < 16; ++r) {
                    float e = __expf(st[jt][it][r] - mx);
                    st[jt][it][r] = e;
                    sum += e;
                }
            sum += __shfl_xor(sum, 32);
            rinv[it] = 1.0f / sum;
        }

        // ---- PV: O^T[d][i] via 32x32x16, P fragments built in-register ----
        int i_out = l31;
        #pragma unroll
        for (int it = 0; it < 2; ++it) {
            floatx16 ot = {};
            #pragma unroll
            for (int jc = 0; jc < 4; ++jc) {
                int jt = jc >> 1, rb = (jc & 1) * 8;
                uint u0 = pack2(st[jt][it][rb + 0], st[jt][it][rb + 1]);
                uint u1 = pack2(st[jt][it][rb + 2], st[jt][it][rb + 3]);
                uint u2 = pack2(st[jt][it][rb + 4], st[jt][it][rb + 5]);
                uint u3 = pack2(st[jt][it][rb + 6], st[jt][it][rb + 7]);
                uint s0 = __shfl_xor(u0, 32);
                uint s1 = __shfl_xor(u1, 32);
                uint s2 = __shfl_xor(u2, 32);
                uint s3 = __shfl_xor(u3, 32);
                union { short8 v; uint u[4]; } bf;
                bf.u[0] = hilane ? s2 : u0;
                bf.u[1] = hilane ? s3 : u1;
                bf.u[2] = hilane ? u2 : s0;
                bf.u[3] = hilane ? u3 : s1;
                short8 av = *(const short8*)(vDb + l31 * 128 + (((jc * 2 + l5) ^ (l31 & 7)) << 4));
                ot = __builtin_amdgcn_mfma_f32_32x32x16_bf16(av, bf.v, ot, 0, 0, 0);
            }
            float rs = rinv[it];
            int i = it * 32 + i_out;
            int gy = wy * 8 + (i >> 3), gx = wx * 8 + (i & 7);
            float* Ab = A + (((size_t)(b * 256 + h * 16)) << 16) + gy * 256 + gx;
            #pragma unroll
            for (int r = 0; r < 8; ++r) {
                int d = (r & 3) + 8 * (r >> 2) + 4 * l5;
                Ab[(size_t)d << 16] = ot[r] * rs;
            }
        }
    }
}

// ---------------------------------------------------------------------------
// K7: L += avgpools of A
// ---------------------------------------------------------------------------
__global__ __launch_bounds__(256) void k7_pool(const float* __restrict__ A,
        float* __restrict__ L)
{
    size_t idx = (size_t)blockIdx.x * 256 + threadIdx.x;
    int j = (int)(idx & 255);
    int i = (int)((idx >> 8) & 255);
    size_t bc = idx >> 16;
    const float* Abc = A + (bc << 16);
    float sv = 0.f, sh = 0.f;
    #pragma unroll
    for (int u = 0; u < 8; ++u) {
        int r = i - 3 + u;
        if (r >= 0 && r <= 256) {
            int rr = (r == 256) ? 254 : r;
            sv += Abc[rr * 256 + j];
        }
        int c2 = j - 3 + u;
        if (c2 >= 0 && c2 <= 256) {
            int cc = (c2 == 256) ? 254 : c2;
            sh += Abc[i * 256 + cc];
        }
    }
    L[idx] += 0.125f * (sv + sh);
}

// ---------------------------------------------------------------------------
// K8: D = sp * dwconv8x8(pad_out(P), wdw, pad=3) + bp
// ---------------------------------------------------------------------------
__global__ __launch_bounds__(256) void k8_dw(const float* __restrict__ P,
        const float* __restrict__ wdw, const float* __restrict__ sp,
        const float* __restrict__ bp, float* __restrict__ D)
{
    int blk = blockIdx.x;
    int tile = blk & 255;
    int c = (blk >> 8) & 255;
    int b = blk >> 16;
    int ty = tile >> 4, tx = tile & 15;
    int t = threadIdx.x;
    __shared__ float pT[23][24];
    __shared__ float wT[64];
    const float* Pc = P + ((size_t)(b * 256 + c) << 16);
    for (int i = t; i < 529; i += 256) {
        int yy = i / 23, xx = i - yy * 23;
        int gy = ty * 16 - 3 + yy, gx = tx * 16 - 3 + xx;
        float v = 0.f;
        if (gy >= 0 && gy <= 256 && gx >= 0 && gx <= 256) {
            int ry = (gy == 256) ? 254 : gy;
            int rx = (gx == 256) ? 254 : gx;
            v = Pc[ry * 256 + rx];
        }
        pT[yy][xx] = v;
    }
    if (t < 64) wT[t] = wdw[c * 64 + t];
    __syncthreads();
    int yy = t >> 4, xx = t & 15;
    float acc = 0.f;
    #pragma unroll
    for (int u = 0; u < 8; ++u)
        #pragma unroll
        for (int v = 0; v < 8; ++v)
            acc += wT[u * 8 + v] * pT[yy + u][xx + v];
    D[((size_t)(b * 256 + c) << 16) + (ty * 16 + yy) * 256 + tx * 16 + xx] =
        sp[c] * acc + bp[c];
}

// ---------------------------------------------------------------------------
// K9: out = wpw @ D  (1x1 conv, 256x256)
// ---------------------------------------------------------------------------
__global__ __launch_bounds__(256) void k9_pw(const float* __restrict__ D,
        const float* __restrict__ wpw, float* __restrict__ out)
{
    int blk = blockIdx.x;
    int pt = blk & 1023;
    int ct = (blk >> 10) & 3;
    int b = blk >> 12;
    int n0 = pt * 64;
    int t = threadIdx.x;
    __shared__ float DT[256][64];
    __shared__ float wT[64][257];
    for (int i = 0; i < 64; ++i) {
        int ci = i * 4 + (t >> 6);
        DT[ci][t & 63] = D[((size_t)(b * 256 + ci) << 16) + n0 + (t & 63)];
    }
    for (int i = 0; i < 64; ++i)
        wT[i][t] = wpw[(size_t)(ct * 64 + i) * 256 + t];
    __syncthreads();
    int cog = t >> 4, pxg = t & 15;
    float acc[4][4];
    #pragma unroll
    for (int a = 0; a < 4; ++a)
        #pragma unroll
        for (int p = 0; p < 4; ++p) acc[a][p] = 0.f;
    for (int ci = 0; ci < 256; ++ci) {
        float wv0 = wT[cog * 4 + 0][ci];
        float wv1 = wT[cog * 4 + 1][ci];
        float wv2 = wT[cog * 4 + 2][ci];
        float wv3 = wT[cog * 4 + 3][ci];
        #pragma unroll
        for (int p = 0; p < 4; ++p) {
            float dv = DT[ci][pxg * 4 + p];
            acc[0][p] += wv0 * dv;
            acc[1][p] += wv1 * dv;
            acc[2][p] += wv2 * dv;
            acc[3][p] += wv3 * dv;
        }
    }
    #pragma unroll
    for (int a = 0; a < 4; ++a) {
        int co = ct * 64 + cog * 4 + a;
        #pragma unroll
        for (int p = 0; p < 4; ++p) {
            out[((size_t)(b * 256 + co) << 16) + n0 + pxg * 4 + p] = acc[a][p];
        }
    }
}

// ---------------------------------------------------------------------------
extern "C" void kernel_launch(void* const* d_in, const int* in_sizes, int n_in,
                              void* d_out, int out_size, void* d_ws, size_t ws_size,
                              hipStream_t stream)
{
    (void)in_sizes; (void)n_in; (void)out_size; (void)ws_size;
    const float* x     = (const float*)d_in[0];
    const float* y     = (const float*)d_in[1];
    const float* gamma = (const float*)d_in[2];
    const float* la_wq = (const float*)d_in[3];
    const float* la_bq = (const float*)d_in[4];
    const float* la_wk = (const float*)d_in[5];
    const float* la_bk = (const float*)d_in[6];
    const float* la_wv = (const float*)d_in[7];
    const float* la_bv = (const float*)d_in[8];
    const float* wqkv  = (const float*)d_in[9];
    const float* wl1   = (const float*)d_in[10];
    const float* s1    = (const float*)d_in[11];
    const float* b1    = (const float*)d_in[12];
    const float* wl2   = (const float*)d_in[13];
    const float* s2    = (const float*)d_in[14];
    const float* b2    = (const float*)d_in[15];
    const float* rel   = (const float*)d_in[16];
    const float* wdw   = (const float*)d_in[17];
    const float* sp    = (const float*)d_in[18];
    const float* bp    = (const float*)d_in[19];
    const float* wpw   = (const float*)d_in[20];
    float* out = (float*)d_out;

    float* ws = (float*)d_ws;
    float* Q      = ws;                      // 4,194,304 floats
    float* Kn     = ws + 4194304;            // 4,194,304 (Wb + Wqb after k2)
    float* stats  = ws + 8388608;
    float* Ksum   = stats;
    float* xsum   = stats + 64;
    float* KX     = stats + 576;
    float* matrix = stats + 16960;
    float* vsum   = stats + 33344;
    float* A      = ws + 8429568;            // 33,554,432 (ybf alias; attn out; dw out)
    float* L      = A + 33554432;            // 33,554,432

    ushort* Wb  = (ushort*)Kn;               // conv weights, 589,824 bf16
    ushort* Wqb = (ushort*)Kn + 600064;      // qkv weights, 196,608 bf16
    ushort* ybf = (ushort*)A;                // padded NHWC y, bf16 — until k6

    hipMemsetAsync(stats, 0, 16960 * sizeof(float), stream);
    hipMemsetAsync(ybf, 0, (size_t)2 * 258 * 258 * 256 * sizeof(ushort), stream);

    kprep_y<<<16384, 256, 0, stream>>>(y, ybf);
    k1_qk  <<<2048,  256, 0, stream>>>(x, la_wq, la_bq, la_wk, la_bk, Q, Kn);
    k2_kx  <<<256,   256, 0, stream>>>(x, Kn, KX, xsum, Ksum);
    kprep_w<<<2304,  256, 0, stream>>>(wl1, s1, wl2, s2, Wb);   // Kn dead after k2
    kprep_qw<<<768,  256, 0, stream>>>(wqkv, Wqb);
    k3_mat <<<2,     256, 0, stream>>>(la_wv, la_bv, KX, xsum, Ksum, matrix, vsum);
    k4_z   <<<2048,  256, 0, stream>>>(x, Q, matrix, vsum, Ksum, gamma, out);
    k5_mfma<<<1024,  512, 0, stream>>>(ybf, Wb, b1, b2, L);
    k6_mfma<<<2048,  512, 0, stream>>>(out, Wqb, rel, A);       // overwrites ybf region
    k7_pool<<<131072,256, 0, stream>>>(A, L);
    k8_dw  <<<131072,256, 0, stream>>>(L, wdw, sp, bp, A);
    k9_pw  <<<8192,  256, 0, stream>>>(A, wpw, out);
}

// Round 4
// 2346.776 us; speedup vs baseline: 4.5812x; 1.1791x over previous
//
#include <hip/hip_runtime.h>
#include <hip/hip_bf16.h>

#define DI __device__ __forceinline__

constexpr int Bc = 2, Cc = 256, Hc = 256, Wc = 256, Nc = Hc * Wc; // N=65536
constexpr float LA_EPS = 1e-6f;

typedef __attribute__((ext_vector_type(8))) short short8;
typedef __attribute__((ext_vector_type(4))) float floatx4;
typedef __attribute__((ext_vector_type(16))) float floatx16;

DI ushort f2bf(float f) {
    uint u = __float_as_uint(f);
    uint r = (u + 0x7fff + ((u >> 16) & 1)) >> 16;
    return (ushort)r;
}

DI uint pack2(float a, float b) {
    return (uint)f2bf(a) | ((uint)f2bf(b) << 16);
}

DI void gload16(const void* g, void* l) {
    __builtin_amdgcn_global_load_lds(
        (const __attribute__((address_space(1))) void*)g,
        (__attribute__((address_space(3))) void*)l, 16, 0, 0);
}

// ---------------------------------------------------------------------------
// K1: Q,K = 1x1 conv of x (32 ch each), L2-normalized over channel dim per pixel
// c-outer / j-inner: 256 LDS reads/thread (was 4096), weights via uniform s-loads
// ---------------------------------------------------------------------------
__global__ __launch_bounds__(256) void k1_qk(const float* __restrict__ x,
        const float* __restrict__ wq, const float* __restrict__ bq,
        const float* __restrict__ wk, const float* __restrict__ bk,
        float* __restrict__ Qo, float* __restrict__ Ko)
{
    int b = blockIdx.x >> 10;
    int n0 = (blockIdx.x & 1023) * 64;
    int t = threadIdx.x;
    int px = t & 63, g = t >> 6;
    __shared__ float xT[256][64];
    __shared__ float qkT[64][65];
    __shared__ float rn[2][64];
    const float* xb = x + (size_t)b * Cc * Nc + n0;
    for (int i = 0; i < 64; ++i) {
        int c = i * 4 + g;
        xT[c][px] = xb[(size_t)c * Nc + px];
    }
    __syncthreads();
    float accv[16];
    const float* wr_[16];
    #pragma unroll
    for (int j = 0; j < 16; ++j) {
        int oc = j * 4 + g;
        if (oc < 32) { wr_[j] = wq + oc * 256; accv[j] = bq[oc]; }
        else         { wr_[j] = wk + (oc - 32) * 256; accv[j] = bk[oc - 32]; }
    }
    for (int c = 0; c < 256; ++c) {
        float xv = xT[c][px];
        #pragma unroll
        for (int j = 0; j < 16; ++j) accv[j] += wr_[j][c] * xv;
    }
    #pragma unroll
    for (int j = 0; j < 16; ++j) qkT[j * 4 + g][px] = accv[j];
    __syncthreads();
    if (t < 128) {
        int p = t & 63, which = t >> 6;
        float s = 0.f;
        #pragma unroll
        for (int m = 0; m < 32; ++m) { float v = qkT[which * 32 + m][p]; s += v * v; }
        rn[which][p] = 1.0f / sqrtf(s);
    }
    __syncthreads();
    #pragma unroll
    for (int j = 0; j < 16; ++j) {
        int oc = j * 4 + g;
        if (oc < 32) Qo[((size_t)b * 32 + oc) * Nc + n0 + px] = accv[j] * rn[0][px];
        else         Ko[((size_t)b * 32 + oc - 32) * Nc + n0 + px] = accv[j] * rn[1][px];
    }
}

// ---------------------------------------------------------------------------
// K2: KX[b,m,c] = sum_n K[b,m,n]*x[b,c,n]; xsum[b,c]; Ksum[b,m]  (atomics)
// ---------------------------------------------------------------------------
__global__ __launch_bounds__(256) void k2_kx(const float* __restrict__ x,
        const float* __restrict__ Kn, float* __restrict__ KX,
        float* __restrict__ xsum, float* __restrict__ Ksum)
{
    int b = blockIdx.x >> 7;
    int blk = blockIdx.x & 127;
    int t = threadIdx.x;
    int pxl = t & 63, g = t >> 6;
    __shared__ float xT[256][65];
    __shared__ float kT[32][64];
    float acc[32];
    #pragma unroll
    for (int m = 0; m < 32; ++m) acc[m] = 0.f;
    float xs = 0.f, ks = 0.f;
    for (int i = 0; i < 8; ++i) {
        int n0 = (blk + 128 * i) * 64;
        __syncthreads();
        for (int j = 0; j < 64; ++j) {
            int c = j * 4 + g;
            xT[c][pxl] = x[(size_t)(b * 256 + c) * Nc + n0 + pxl];
        }
        #pragma unroll
        for (int j = 0; j < 8; ++j) {
            int m = j * 4 + g;
            kT[m][pxl] = Kn[((size_t)b * 32 + m) * Nc + n0 + pxl];
        }
        __syncthreads();
        #pragma unroll 2
        for (int p = 0; p < 64; ++p) {
            float xv = xT[t][p];
            xs += xv;
            #pragma unroll
            for (int m = 0; m < 32; ++m) acc[m] += kT[m][p] * xv;
        }
        if (t < 32) {
            for (int p = 0; p < 64; ++p) ks += kT[t][p];
        }
    }
    atomicAdd(&xsum[b * 256 + t], xs);
    if (t < 32) atomicAdd(&Ksum[b * 32 + t], ks);
    #pragma unroll
    for (int m = 0; m < 32; ++m) atomicAdd(&KX[(b * 32 + m) * 256 + t], acc[m]);
}

// ---------------------------------------------------------------------------
// K3: matrix/vsum from KX, xsum, Ksum
// ---------------------------------------------------------------------------
__global__ __launch_bounds__(256) void k3_mat(const float* __restrict__ wv,
        const float* __restrict__ bv, const float* __restrict__ KX,
        const float* __restrict__ xsum, const float* __restrict__ Ksum,
        float* __restrict__ matrix, float* __restrict__ vsum)
{
    int b = blockIdx.x, t = threadIdx.x;
    __shared__ float sx[256];
    __shared__ float sk[32];
    __shared__ float skx[32][256];
    __shared__ float wT[256][65];
    sx[t] = xsum[b * 256 + t];
    if (t < 32) sk[t] = Ksum[b * 32 + t];
    for (int j = 0; j < 32; ++j) skx[j][t] = KX[(b * 32 + j) * 256 + t];
    float vs = bv[t] * (float)Nc;
    float mv[32];
    #pragma unroll
    for (int m = 0; m < 32; ++m) mv[m] = 0.f;
    for (int cc0 = 0; cc0 < 256; cc0 += 64) {
        __syncthreads();
        for (int i = 0; i < 64; ++i) {
            int c = i * 4 + (t >> 6);
            wT[c][t & 63] = wv[(size_t)c * 256 + cc0 + (t & 63)];
        }
        __syncthreads();
        for (int ccl = 0; ccl < 64; ++ccl) {
            float w = wT[t][ccl];
            int cc = cc0 + ccl;
            vs += w * sx[cc];
            #pragma unroll
            for (int m = 0; m < 32; ++m) mv[m] += w * skx[m][cc];
        }
    }
    vsum[b * 256 + t] = vs;
    float bvt = bv[t];
    for (int m = 0; m < 32; ++m) matrix[(b * 32 + m) * 256 + t] = mv[m] + bvt * sk[m];
}

// ---------------------------------------------------------------------------
// K4: z = x + gamma * (vsum[c] + sum_m Q[m,n]*matrix[m,c]) * tailor[n]
// ---------------------------------------------------------------------------
__global__ __launch_bounds__(256) void k4_z(const float* __restrict__ x,
        const float* __restrict__ Q, const float* __restrict__ matrix,
        const float* __restrict__ vsum, const float* __restrict__ Ksum,
        const float* __restrict__ gamma_p, float* __restrict__ z)
{
    int b = blockIdx.x >> 10;
    int n0 = (blockIdx.x & 1023) * 64;
    int t = threadIdx.x;
    int px = t & 63, g = t >> 6;
    __shared__ float qT[32][64];
    __shared__ float mat[32][256];
    __shared__ float vs[256];
    __shared__ float tail[64];
    __shared__ float sk[32];
    #pragma unroll
    for (int j = 0; j < 8; ++j) {
        int m = j * 4 + g;
        qT[m][px] = Q[((size_t)b * 32 + m) * Nc + n0 + px];
    }
    for (int j = 0; j < 32; ++j) {
        int idx = j * 256 + t;
        (&mat[0][0])[idx] = matrix[b * 8192 + idx];
    }
    vs[t] = vsum[b * 256 + t];
    if (t < 32) sk[t] = Ksum[b * 32 + t] + LA_EPS;
    __syncthreads();
    if (t < 64) {
        float s = 0.f;
        #pragma unroll
        for (int m = 0; m < 32; ++m) s += qT[m][t] * sk[m];
        tail[t] = 1.0f / ((float)Nc + s);
    }
    __syncthreads();
    float gamma = gamma_p[0];
    for (int l = 0; l < 64; ++l) {
        int c = l * 4 + g;
        float s = vs[c];
        #pragma unroll
        for (int m = 0; m < 32; ++m) s += qT[m][px] * mat[m][c];
        size_t idx = (size_t)(b * 256 + c) * Nc + n0 + px;
        z[idx] = x[idx] + gamma * s * tail[px];
    }
}

// ---------------------------------------------------------------------------
// KPREP_Y: y (NCHW f32) -> ybf (padded NHWC bf16, [b][258][258][256], origin +1)
// ---------------------------------------------------------------------------
__global__ __launch_bounds__(256) void kprep_y(const float* __restrict__ y,
        ushort* __restrict__ ybf)
{
    int blk = blockIdx.x;
    int b = blk >> 13;
    int rest = blk & 8191;
    int ci0 = (rest & 7) * 32;
    int n0 = (rest >> 3) * 64;
    int row = n0 >> 8, x = n0 & 255;
    int t = threadIdx.x;
    __shared__ uint u[16][65];
    int px = t & 63, cig = t >> 6;
    const float* yb = y + (((size_t)(b * 256 + ci0 + cig * 8)) << 16) + n0 + px;
    #pragma unroll
    for (int jj = 0; jj < 4; ++jj) {
        float v0 = yb[((size_t)(jj * 2)) << 16];
        float v1 = yb[((size_t)(jj * 2 + 1)) << 16];
        u[cig * 4 + jj][px] = (uint)f2bf(v0) | ((uint)f2bf(v1) << 16);
    }
    __syncthreads();
    uint* out32 = (uint*)ybf;
    size_t pbase = (size_t)(row + 1) * 258 + (x + 1);
    int pr = t & 15, pg = t >> 4;
    #pragma unroll
    for (int g2 = 0; g2 < 4; ++g2) {
        int ppx = g2 * 16 + pg;
        size_t uidx = (((size_t)b * 258 * 258 * 256 + (pbase + ppx) * 256 + ci0) >> 1) + pr;
        out32[uidx] = u[pr][ppx];
    }
}

// ---------------------------------------------------------------------------
// KPREP_W: Wb[tap][co][ci] = bf16(wl1[co][ci][tap]*s1[co] + (tap==4)*wl2[co][ci]*s2[co])
// ---------------------------------------------------------------------------
__global__ __launch_bounds__(256) void kprep_w(const float* __restrict__ wl1,
        const float* __restrict__ s1, const float* __restrict__ wl2,
        const float* __restrict__ s2, ushort* __restrict__ Wb)
{
    int idx = blockIdx.x * 256 + threadIdx.x;
    int tp = idx >> 16;
    int r = idx & 65535;
    int co = r >> 8;
    float v = wl1[(size_t)r * 9 + tp] * s1[co];
    if (tp == 4) v += wl2[r] * s2[co];
    Wb[idx] = f2bf(v);
}

// ---------------------------------------------------------------------------
// KPREP_QW: Wqb = bf16(wqkv), q rows (0..255) pre-scaled by 0.25 (= d^-0.5)
// ---------------------------------------------------------------------------
__global__ __launch_bounds__(256) void kprep_qw(const float* __restrict__ wqkv,
        ushort* __restrict__ Wqb)
{
    int idx = blockIdx.x * 256 + threadIdx.x;   // 768*256 = 196608
    float v = wqkv[idx];
    if (idx < 65536) v *= 0.25f;
    Wqb[idx] = f2bf(v);
}

// ---------------------------------------------------------------------------
// KPREP_PW: Wpwb = bf16(wpw)
// ---------------------------------------------------------------------------
__global__ __launch_bounds__(256) void kprep_pw(const float* __restrict__ wpw,
        ushort* __restrict__ Wpwb)
{
    int idx = blockIdx.x * 256 + threadIdx.x;   // 65536
    Wpwb[idx] = f2bf(wpw[idx]);
}

// ---------------------------------------------------------------------------
// K5 (MFMA): L = conv3x3(ybf, Wc) + bias   -- 1x1 branch folded into center tap
// ---------------------------------------------------------------------------
__global__ __launch_bounds__(512, 2) void k5_mfma(
        const ushort* __restrict__ ybf, const ushort* __restrict__ Wb,
        const float* __restrict__ b1, const float* __restrict__ b2,
        float* __restrict__ L)
{
    int blk = blockIdx.x;
    int b = blk >> 9;
    int y0 = (blk >> 1) & 255;
    int x0 = (blk & 1) << 7;
    int t = threadIdx.x;
    int lane = t & 63;
    int w = t >> 6;
    int wr = w >> 1;
    int wc = w & 1;

    __shared__ ushort sW[256 * 64];
    __shared__ ushort sY[128 * 64];

    floatx4 acc[4][4];
    #pragma unroll
    for (int m = 0; m < 4; ++m)
        #pragma unroll
        for (int n = 0; n < 4; ++n)
            acc[m][n] = {0.f, 0.f, 0.f, 0.f};

    const ushort* yb = ybf + (size_t)b * 258 * 258 * 256;
    int ldsWbase = w * 64 * 16;
    int ldsYbase = w * 64 * 16;

    for (int tp = 0; tp < 9; ++tp) {
        int dy = tp / 3 - 1, dx = tp % 3 - 1;
        const ushort* yrow = yb + ((size_t)(y0 + dy + 1) * 258 + (x0 + dx + 1)) * 256;
        const ushort* wtap = Wb + tp * 65536;
        for (int cb = 0; cb < 4; ++cb) {
            int ci0 = cb * 64;
            __syncthreads();
            #pragma unroll
            for (int p = 0; p < 4; ++p) {
                int m = p * 512 + t;
                int row = m >> 3, ch = m & 7;
                const ushort* g = wtap + row * 256 + ci0 + ((ch ^ (row & 7)) << 3);
                gload16(g, (char*)sW + p * 512 * 16 + ldsWbase);
            }
            #pragma unroll
            for (int p = 0; p < 2; ++p) {
                int m = p * 512 + t;
                int pxr = m >> 3, ch = m & 7;
                const ushort* g = yrow + (size_t)pxr * 256 + ci0 + ((ch ^ (pxr & 7)) << 3);
                gload16(g, (char*)sY + p * 512 * 16 + ldsYbase);
            }
            __syncthreads();
            #pragma unroll
            for (int kk = 0; kk < 2; ++kk) {
                int chunkb = kk * 4 + (lane >> 4);
                short8 afr[4], bfr[4];
                #pragma unroll
                for (int m2 = 0; m2 < 4; ++m2) {
                    int row = wr * 64 + m2 * 16 + (lane & 15);
                    int ch = chunkb ^ (row & 7);
                    afr[m2] = *(const short8*)((const char*)sW + row * 128 + ch * 16);
                }
                #pragma unroll
                for (int n2 = 0; n2 < 4; ++n2) {
                    int row = wc * 64 + n2 * 16 + (lane & 15);
                    int ch = chunkb ^ (row & 7);
                    bfr[n2] = *(const short8*)((const char*)sY + row * 128 + ch * 16);
                }
                #pragma unroll
                for (int m2 = 0; m2 < 4; ++m2)
                    #pragma unroll
                    for (int n2 = 0; n2 < 4; ++n2)
                        acc[m2][n2] = __builtin_amdgcn_mfma_f32_16x16x32_bf16(
                            afr[m2], bfr[n2], acc[m2][n2], 0, 0, 0);
            }
        }
    }
    int pxb = x0 + wc * 64 + (lane & 15);
    #pragma unroll
    for (int m2 = 0; m2 < 4; ++m2) {
        int cobase = wr * 64 + m2 * 16 + (lane >> 4) * 4;
        #pragma unroll
        for (int r = 0; r < 4; ++r) {
            int co = cobase + r;
            float bias = b1[co] + b2[co];
            float* dst = L + (((size_t)(b * 256 + co)) << 16) + y0 * 256 + pxb;
            #pragma unroll
            for (int n2 = 0; n2 < 4; ++n2)
                dst[n2 * 16] = acc[m2][n2][r] + bias;
        }
    }
}

// ---------------------------------------------------------------------------
// K6 (MFMA, fused): qkv + window attention, TWO adjacent windows per block.
// 512 threads = 8 waves; waves 0-3 -> window 0, waves 4-7 -> window 1;
// each wave handles 4 heads. L2-coalesces the 32B NCHW half-lines.
// ---------------------------------------------------------------------------
__global__ __launch_bounds__(512, 2) void k6_mfma(const float* __restrict__ z,
        const ushort* __restrict__ Wqb, const float* __restrict__ rel,
        float* __restrict__ A)
{
    int blk = blockIdx.x;
    int wxp = blk & 15, wy = (blk >> 4) & 31, b = blk >> 9;
    int t = threadIdx.x;
    int lane = t & 63;
    int w = t >> 6;
    int win = w >> 2;
    int wq4 = w & 3;

    __shared__ ushort zT[128 * 256];     // [pxg][ci] bf16, xor-swizzled (64 KB)
    __shared__ float srel[3600];         // rel bias table (14.4 KB)
    __shared__ ushort wbuf[8][4096];     // per-wave: qT / kT / vD

    char* zTc = (char*)zT;

    // ---- stage both z windows (f32 -> bf16, swizzled) + rel table ----
    #pragma unroll
    for (int i = 0; i < 32; ++i) {
        int idx = i * 512 + t;
        int cp = idx >> 7;          // ci pair 0..127
        int pxg = idx & 127;
        int px = pxg & 63;
        int gy = wy * 8 + (px >> 3);
        int gx = (wxp * 2 + (pxg >> 6)) * 8 + (px & 7);
        const float* zp = z + ((size_t)(b * 256 + cp * 2) << 16) + gy * 256 + gx;
        uint pv = pack2(zp[0], zp[1ull << 16]);
        *(uint*)(zTc + pxg * 512 + (((cp >> 2) ^ (pxg & 7)) << 4) + (cp & 3) * 4) = pv;
    }
    for (int i = t; i < 3600; i += 512) srel[i] = rel[i];
    __syncthreads();

    char* qTb = (char*)&wbuf[w][0];
    char* kTb = (char*)&wbuf[w][1024];
    char* vDb = (char*)&wbuf[w][2048];

    int l15 = lane & 15, l4 = lane >> 4;
    int l31 = lane & 31, l5 = lane >> 5;
    bool hilane = (l5 != 0);
    int pxbase = win * 64;

    for (int hrep = 0; hrep < 4; ++hrep) {
        int h = wq4 * 4 + hrep;

        // ---- q-GEMM: D[d][px] = 0.25*Wq_h @ z ----
        floatx4 qacc[4] = {};
        #pragma unroll
        for (int ks = 0; ks < 8; ++ks) {
            short8 aw = *(const short8*)(Wqb + ((h * 16 + l15) << 8) + ks * 32 + (l4 << 3));
            #pragma unroll
            for (int n = 0; n < 4; ++n) {
                int px = n * 16 + l15;
                short8 bz = *(const short8*)(zTc + (pxbase + px) * 512 + (((ks * 4 + l4) ^ (px & 7)) << 4));
                qacc[n] = __builtin_amdgcn_mfma_f32_16x16x32_bf16(aw, bz, qacc[n], 0, 0, 0);
            }
        }
        #pragma unroll
        for (int n = 0; n < 4; ++n) {   // qT[px][d] (row 32B)
            int px = n * 16 + l15;
            uint2 wv = { pack2(qacc[n][0], qacc[n][1]), pack2(qacc[n][2], qacc[n][3]) };
            *(uint2*)(qTb + px * 32 + (l4 << 3)) = wv;
        }

        // ---- kT-GEMM: D[px][d] = z^T @ Wk_h^T ----
        floatx4 kacc[4] = {};
        #pragma unroll
        for (int ks = 0; ks < 8; ++ks) {
            short8 bw = *(const short8*)(Wqb + ((256 + h * 16 + l15) << 8) + ks * 32 + (l4 << 3));
            #pragma unroll
            for (int m = 0; m < 4; ++m) {
                int px = m * 16 + l15;
                short8 az = *(const short8*)(zTc + (pxbase + px) * 512 + (((ks * 4 + l4) ^ (px & 7)) << 4));
                kacc[m] = __builtin_amdgcn_mfma_f32_16x16x32_bf16(az, bw, kacc[m], 0, 0, 0);
            }
        }
        #pragma unroll
        for (int m = 0; m < 4; ++m) {
            #pragma unroll
            for (int r = 0; r < 4; ++r) {
                int px = m * 16 + l4 * 4 + r;
                *(ushort*)(kTb + px * 32 + l15 * 2) = f2bf(kacc[m][r]);
            }
        }

        // ---- v-GEMM: vD[d][px] = Wv_h @ z ----
        floatx4 vacc[4] = {};
        #pragma unroll
        for (int ks = 0; ks < 8; ++ks) {
            short8 aw = *(const short8*)(Wqb + ((512 + h * 16 + l15) << 8) + ks * 32 + (l4 << 3));
            #pragma unroll
            for (int n = 0; n < 4; ++n) {
                int px = n * 16 + l15;
                short8 bz = *(const short8*)(zTc + (pxbase + px) * 512 + (((ks * 4 + l4) ^ (px & 7)) << 4));
                vacc[n] = __builtin_amdgcn_mfma_f32_16x16x32_bf16(aw, bz, vacc[n], 0, 0, 0);
            }
        }
        #pragma unroll
        for (int n = 0; n < 4; ++n) {   // vD[d][px] swizzled rows of 128B
            int px = n * 16 + l15;
            #pragma unroll
            for (int r = 0; r < 4; ++r) {
                int d = l4 * 4 + r;
                *(ushort*)(vDb + d * 128 + ((((px >> 3) ^ (d & 7)) << 4) + (px & 7) * 2)) = f2bf(vacc[n][r]);
            }
        }

        // ---- S^T via 32x32x16 MFMAs (K = d = 16) ----
        floatx16 st[2][2];
        short8 bq[2];
        #pragma unroll
        for (int it = 0; it < 2; ++it)
            bq[it] = *(const short8*)(qTb + (it * 32 + l31) * 32 + (l5 << 4));
        #pragma unroll
        for (int jt = 0; jt < 2; ++jt) {
            short8 ak = *(const short8*)(kTb + (jt * 32 + l31) * 32 + (l5 << 4));
            #pragma unroll
            for (int it = 0; it < 2; ++it) {
                floatx16 zc = {};
                st[jt][it] = __builtin_amdgcn_mfma_f32_32x32x16_bf16(ak, bq[it], zc, 0, 0, 0);
            }
        }

        // ---- bias + softmax (over j) ----
        float rinv[2];
        #pragma unroll
        for (int it = 0; it < 2; ++it) {
            int i = it * 32 + l31;
            int Ai = (i >> 3) * 15 + (i & 7) + 112;
            float mx = -1e30f;
            #pragma unroll
            for (int jt = 0; jt < 2; ++jt)
                #pragma unroll
                for (int r = 0; r < 16; ++r) {
                    int j = jt * 32 + (r & 3) + 8 * (r >> 2) + 4 * l5;
                    int Bjr = (j >> 3) * 15 + (j & 7);
                    float s = st[jt][it][r] + srel[(Ai - Bjr) * 16 + h];
                    st[jt][it][r] = s;
                    mx = fmaxf(mx, s);
                }
            mx = fmaxf(mx, __shfl_xor(mx, 32));
            float sum = 0.f;
            #pragma unroll
            for (int jt = 0; jt < 2; ++jt)
                #pragma unroll
                for (int r = 0; r < 16; ++r) {
                    float e = __expf(st[jt][it][r] - mx);
                    st[jt][it][r] = e;
                    sum += e;
                }
            sum += __shfl_xor(sum, 32);
            rinv[it] = 1.0f / sum;
        }

        // ---- PV: O^T[d][i] via 32x32x16, P fragments built in-register ----
        #pragma unroll
        for (int it = 0; it < 2; ++it) {
            floatx16 ot = {};
            #pragma unroll
            for (int jc = 0; jc < 4; ++jc) {
                int jt = jc >> 1, rb = (jc & 1) * 8;
                uint u0 = pack2(st[jt][it][rb + 0], st[jt][it][rb + 1]);
                uint u1 = pack2(st[jt][it][rb + 2], st[jt][it][rb + 3]);
                uint u2 = pack2(st[jt][it][rb + 4], st[jt][it][rb + 5]);
                uint u3 = pack2(st[jt][it][rb + 6], st[jt][it][rb + 7]);
                uint s0 = __shfl_xor(u0, 32);
                uint s1 = __shfl_xor(u1, 32);
                uint s2 = __shfl_xor(u2, 32);
                uint s3 = __shfl_xor(u3, 32);
                union { short8 v; uint u[4]; } bf;
                bf.u[0] = hilane ? s2 : u0;
                bf.u[1] = hilane ? s3 : u1;
                bf.u[2] = hilane ? u2 : s0;
                bf.u[3] = hilane ? u3 : s1;
                short8 av = *(const short8*)(vDb + l31 * 128 + (((jc * 2 + l5) ^ (l31 & 7)) << 4));
                ot = __builtin_amdgcn_mfma_f32_32x32x16_bf16(av, bf.v, ot, 0, 0, 0);
            }
            float rs = rinv[it];
            int i = it * 32 + l31;
            int gy = wy * 8 + (i >> 3);
            int gx = (wxp * 2 + win) * 8 + (i & 7);
            float* Ab = A + (((size_t)(b * 256 + h * 16)) << 16) + gy * 256 + gx;
            #pragma unroll
            for (int r = 0; r < 8; ++r) {
                int d = (r & 3) + 8 * (r >> 2) + 4 * l5;
                Ab[(size_t)d << 16] = ot[r] * rs;
            }
        }
    }
}

// ---------------------------------------------------------------------------
// K7: L += avgpools of A
// ---------------------------------------------------------------------------
__global__ __launch_bounds__(256) void k7_pool(const float* __restrict__ A,
        float* __restrict__ L)
{
    size_t idx = (size_t)blockIdx.x * 256 + threadIdx.x;
    int j = (int)(idx & 255);
    int i = (int)((idx >> 8) & 255);
    size_t bc = idx >> 16;
    const float* Abc = A + (bc << 16);
    float sv = 0.f, sh = 0.f;
    #pragma unroll
    for (int u = 0; u < 8; ++u) {
        int r = i - 3 + u;
        if (r >= 0 && r <= 256) {
            int rr = (r == 256) ? 254 : r;
            sv += Abc[rr * 256 + j];
        }
        int c2 = j - 3 + u;
        if (c2 >= 0 && c2 <= 256) {
            int cc = (c2 == 256) ? 254 : c2;
            sh += Abc[i * 256 + cc];
        }
    }
    L[idx] += 0.125f * (sv + sh);
}

// ---------------------------------------------------------------------------
// K8: D(bf16) = sp * dwconv8x8(pad_out(P), wdw, pad=3) + bp
// ---------------------------------------------------------------------------
__global__ __launch_bounds__(256) void k8_dw(const float* __restrict__ P,
        const float* __restrict__ wdw, const float* __restrict__ sp,
        const float* __restrict__ bp, ushort* __restrict__ D)
{
    int blk = blockIdx.x;
    int tile = blk & 255;
    int c = (blk >> 8) & 255;
    int b = blk >> 16;
    int ty = tile >> 4, tx = tile & 15;
    int t = threadIdx.x;
    __shared__ float pT[23][24];
    __shared__ float wT[64];
    const float* Pc = P + ((size_t)(b * 256 + c) << 16);
    for (int i = t; i < 529; i += 256) {
        int yy = i / 23, xx = i - yy * 23;
        int gy = ty * 16 - 3 + yy, gx = tx * 16 - 3 + xx;
        float v = 0.f;
        if (gy >= 0 && gy <= 256 && gx >= 0 && gx <= 256) {
            int ry = (gy == 256) ? 254 : gy;
            int rx = (gx == 256) ? 254 : gx;
            v = Pc[ry * 256 + rx];
        }
        pT[yy][xx] = v;
    }
    if (t < 64) wT[t] = wdw[c * 64 + t];
    __syncthreads();
    int yy = t >> 4, xx = t & 15;
    float acc = 0.f;
    #pragma unroll
    for (int u = 0; u < 8; ++u)
        #pragma unroll
        for (int v = 0; v < 8; ++v)
            acc += wT[u * 8 + v] * pT[yy + u][xx + v];
    D[((size_t)(b * 256 + c) << 16) + (ty * 16 + yy) * 256 + tx * 16 + xx] =
        f2bf(sp[c] * acc + bp[c]);
}

// ---------------------------------------------------------------------------
// K9 (MFMA): out[co][px] = sum_ci Wpw[co][ci] * D[ci][px]
// M=256 co, N=128 px, K=256 ci. 8 waves (4 co-chunks x 2 px-chunks).
// W staged via swizzled global_load_lds; D reg-transpose-staged.
// ---------------------------------------------------------------------------
__global__ __launch_bounds__(512, 2) void k9_mfma(
        const ushort* __restrict__ D, const ushort* __restrict__ Wpwb,
        float* __restrict__ out)
{
    int blk = blockIdx.x;
    int b = blk >> 9;
    int px0 = (blk & 511) << 7;
    int t = threadIdx.x;
    int lane = t & 63;
    int w = t >> 6;
    int wr = w >> 1, wc = w & 1;

    __shared__ ushort sW[256 * 64];   // [co][ci] swizzled, 32KB
    __shared__ ushort sD[128 * 64];   // [px][ci] swizzled, 16KB

    floatx4 acc[4][4];
    #pragma unroll
    for (int m = 0; m < 4; ++m)
        #pragma unroll
        for (int n = 0; n < 4; ++n)
            acc[m][n] = {0.f, 0.f, 0.f, 0.f};

    int ldsWbase = w * 64 * 16;

    for (int cb = 0; cb < 4; ++cb) {
        int ci0 = cb * 64;
        __syncthreads();
        #pragma unroll
        for (int p = 0; p < 4; ++p) {
            int m = p * 512 + t;
            int row = m >> 3, ch = m & 7;
            const ushort* g = Wpwb + row * 256 + ci0 + ((ch ^ (row & 7)) << 3);
            gload16(g, (char*)sW + p * 512 * 16 + ldsWbase);
        }
        // reg-transpose stage of D: 16B (8 px) loads, b16 scatter to [px][ci]
        #pragma unroll
        for (int p = 0; p < 2; ++p) {
            int m = p * 512 + t;
            int ci = m & 63, pxb = (m >> 6) * 8;
            short8 v = *(const short8*)(D + ((size_t)(b * 256 + ci0 + ci) << 16) + px0 + pxb);
            #pragma unroll
            for (int k2 = 0; k2 < 8; ++k2) {
                int px = pxb + k2;
                *(ushort*)((char*)sD + px * 128 + (((ci >> 3) ^ (px & 7)) << 4) + (ci & 7) * 2) =
                    (ushort)v[k2];
            }
        }
        __syncthreads();
        #pragma unroll
        for (int kk = 0; kk < 2; ++kk) {
            int chunkb = kk * 4 + (lane >> 4);
            short8 afr[4], bfr[4];
            #pragma unroll
            for (int m2 = 0; m2 < 4; ++m2) {
                int row = wr * 64 + m2 * 16 + (lane & 15);
                int ch = chunkb ^ (row & 7);
                afr[m2] = *(const short8*)((const char*)sW + row * 128 + ch * 16);
            }
            #pragma unroll
            for (int n2 = 0; n2 < 4; ++n2) {
                int row = wc * 64 + n2 * 16 + (lane & 15);
                int ch = chunkb ^ (row & 7);
                bfr[n2] = *(const short8*)((const char*)sD + row * 128 + ch * 16);
            }
            #pragma unroll
            for (int m2 = 0; m2 < 4; ++m2)
                #pragma unroll
                for (int n2 = 0; n2 < 4; ++n2)
                    acc[m2][n2] = __builtin_amdgcn_mfma_f32_16x16x32_bf16(
                        afr[m2], bfr[n2], acc[m2][n2], 0, 0, 0);
        }
    }
    int pxb = px0 + wc * 64 + (lane & 15);
    #pragma unroll
    for (int m2 = 0; m2 < 4; ++m2) {
        int cobase = wr * 64 + m2 * 16 + (lane >> 4) * 4;
        #pragma unroll
        for (int r = 0; r < 4; ++r) {
            int co = cobase + r;
            float* dst = out + (((size_t)(b * 256 + co)) << 16) + pxb;
            #pragma unroll
            for (int n2 = 0; n2 < 4; ++n2)
                dst[n2 * 16] = acc[m2][n2][r];
        }
    }
}

// ---------------------------------------------------------------------------
extern "C" void kernel_launch(void* const* d_in, const int* in_sizes, int n_in,
                              void* d_out, int out_size, void* d_ws, size_t ws_size,
                              hipStream_t stream)
{
    (void)in_sizes; (void)n_in; (void)out_size; (void)ws_size;
    const float* x     = (const float*)d_in[0];
    const float* y     = (const float*)d_in[1];
    const float* gamma = (const float*)d_in[2];
    const float* la_wq = (const float*)d_in[3];
    const float* la_bq = (const float*)d_in[4];
    const float* la_wk = (const float*)d_in[5];
    const float* la_bk = (const float*)d_in[6];
    const float* la_wv = (const float*)d_in[7];
    const float* la_bv = (const float*)d_in[8];
    const float* wqkv  = (const float*)d_in[9];
    const float* wl1   = (const float*)d_in[10];
    const float* s1    = (const float*)d_in[11];
    const float* b1    = (const float*)d_in[12];
    const float* wl2   = (const float*)d_in[13];
    const float* s2    = (const float*)d_in[14];
    const float* b2    = (const float*)d_in[15];
    const float* rel   = (const float*)d_in[16];
    const float* wdw   = (const float*)d_in[17];
    const float* sp    = (const float*)d_in[18];
    const float* bp    = (const float*)d_in[19];
    const float* wpw   = (const float*)d_in[20];
    float* out = (float*)d_out;

    float* ws = (float*)d_ws;
    float* Q      = ws;                      // 4,194,304 floats
    float* Kn     = ws + 4194304;            // 4,194,304 (W-preps after k2)
    float* stats  = ws + 8388608;
    float* Ksum   = stats;
    float* xsum   = stats + 64;
    float* KX     = stats + 576;
    float* matrix = stats + 16960;
    float* vsum   = stats + 33344;
    float* A      = ws + 8429568;            // 33,554,432 (ybf alias; attn out; Dbf)
    float* L      = A + 33554432;            // 33,554,432

    ushort* Wb   = (ushort*)Kn;              // conv weights, 589,824 bf16
    ushort* Wqb  = (ushort*)Kn + 600064;     // qkv weights, 196,608 bf16
    ushort* Wpwb = (ushort*)Kn + 798720;     // pw weights, 65,536 bf16
    ushort* ybf  = (ushort*)A;               // padded NHWC y, bf16 — until k6
    ushort* Dbf  = (ushort*)A;               // bf16 dwconv out — after k8

    hipMemsetAsync(stats, 0, 16960 * sizeof(float), stream);
    hipMemsetAsync(ybf, 0, (size_t)2 * 258 * 258 * 256 * sizeof(ushort), stream);

    kprep_y<<<16384, 256, 0, stream>>>(y, ybf);
    k1_qk  <<<2048,  256, 0, stream>>>(x, la_wq, la_bq, la_wk, la_bk, Q, Kn);
    k2_kx  <<<256,   256, 0, stream>>>(x, Kn, KX, xsum, Ksum);
    kprep_w<<<2304,  256, 0, stream>>>(wl1, s1, wl2, s2, Wb);   // Kn dead after k2
    kprep_qw<<<768,  256, 0, stream>>>(wqkv, Wqb);
    kprep_pw<<<256,  256, 0, stream>>>(wpw, Wpwb);
    k3_mat <<<2,     256, 0, stream>>>(la_wv, la_bv, KX, xsum, Ksum, matrix, vsum);
    k4_z   <<<2048,  256, 0, stream>>>(x, Q, matrix, vsum, Ksum, gamma, out);
    k5_mfma<<<1024,  512, 0, stream>>>(ybf, Wb, b1, b2, L);
    k6_mfma<<<1024,  512, 0, stream>>>(out, Wqb, rel, A);       // overwrites ybf region
    k7_pool<<<131072,256, 0, stream>>>(A, L);
    k8_dw  <<<131072,256, 0, stream>>>(L, wdw, sp, bp, Dbf);
    k9_mfma<<<1024,  512, 0, stream>>>(Dbf, Wpwb, out);
}

// Round 5
// 1883.842 us; speedup vs baseline: 5.7069x; 1.2457x over previous
//
#include <hip/hip_runtime.h>
#include <hip/hip_bf16.h>

#define DI __device__ __forceinline__

constexpr int Bc = 2, Cc = 256, Hc = 256, Wc = 256, Nc = Hc * Wc; // N=65536
constexpr float LA_EPS = 1e-6f;

typedef __attribute__((ext_vector_type(8))) short short8;
typedef __attribute__((ext_vector_type(4))) float floatx4;
typedef __attribute__((ext_vector_type(16))) float floatx16;

DI ushort f2bf(float f) {
    uint u = __float_as_uint(f);
    uint r = (u + 0x7fff + ((u >> 16) & 1)) >> 16;
    return (ushort)r;
}

DI uint pack2(float a, float b) {
    return (uint)f2bf(a) | ((uint)f2bf(b) << 16);
}

DI void gload16(const void* g, void* l) {
    __builtin_amdgcn_global_load_lds(
        (const __attribute__((address_space(1))) void*)g,
        (__attribute__((address_space(3))) void*)l, 16, 0, 0);
}

// ---------------------------------------------------------------------------
// KPREP_X: x (NCHW f32) -> xbf (NHWC bf16, [b][px][ci])
// ---------------------------------------------------------------------------
__global__ __launch_bounds__(256) void kprep_x(const float* __restrict__ x,
        ushort* __restrict__ xbf)
{
    int blk = blockIdx.x;
    int b = blk >> 13;
    int rest = blk & 8191;
    int ci0 = (rest & 7) * 32;
    int n0 = (rest >> 3) * 64;
    int t = threadIdx.x;
    __shared__ uint u[16][65];
    int px = t & 63, cig = t >> 6;
    const float* yb = x + (((size_t)(b * 256 + ci0 + cig * 8)) << 16) + n0 + px;
    #pragma unroll
    for (int jj = 0; jj < 4; ++jj) {
        float v0 = yb[((size_t)(jj * 2)) << 16];
        float v1 = yb[((size_t)(jj * 2 + 1)) << 16];
        u[cig * 4 + jj][px] = pack2(v0, v1);
    }
    __syncthreads();
    uint* out32 = (uint*)xbf;
    int pr = t & 15, pg = t >> 4;
    #pragma unroll
    for (int g2 = 0; g2 < 4; ++g2) {
        int ppx = g2 * 16 + pg;
        size_t uidx = (((size_t)(b * 65536 + n0 + ppx) * 256 + ci0) >> 1) + pr;
        out32[uidx] = u[pr][ppx];
    }
}

// ---------------------------------------------------------------------------
// KPREP_QK: Wqkb[64][256] = bf16( rows 0-31: wq, rows 32-63: wk )
// ---------------------------------------------------------------------------
__global__ __launch_bounds__(256) void kprep_qk(const float* __restrict__ wq,
        const float* __restrict__ wk, ushort* __restrict__ Wqkb)
{
    int idx = blockIdx.x * 256 + threadIdx.x;   // 16384
    int oc = idx >> 8, ci = idx & 255;
    float v = (oc < 32) ? wq[oc * 256 + ci] : wk[(oc - 32) * 256 + ci];
    Wqkb[idx] = f2bf(v);
}

// ---------------------------------------------------------------------------
// K1 (MFMA): Q,K = 1x1 conv (32 ch each) + per-pixel channel L2-norm.
// M=64 (q 0-31 | k 32-63), N=128 px, K=256. 8 waves = 2 (q/k) x 4 (px 32).
// Each wave owns ALL 32 rows of its type -> norm reduces via shfl only.
// ---------------------------------------------------------------------------
__global__ __launch_bounds__(512, 1) void k1_mfma(
        const ushort* __restrict__ xbf, const ushort* __restrict__ Wqkb,
        const float* __restrict__ bq, const float* __restrict__ bk,
        float* __restrict__ Qo, float* __restrict__ Ko)
{
    int blk = blockIdx.x;
    int b = blk >> 9;
    int px0 = (blk & 511) << 7;
    int t = threadIdx.x;
    int lane = t & 63, w = t >> 6;
    int wr = w >> 2;       // 0: q rows, 1: k rows
    int wc = w & 3;        // px quarter (32 px)

    __shared__ ushort sW[64 * 256];    // 32KB [oc][ci] swizzled
    __shared__ ushort sX[128 * 256];   // 64KB [px][ci] swizzled

    #pragma unroll
    for (int p = 0; p < 4; ++p) {
        int m = p * 512 + t;
        int row = m >> 5, ch = m & 31;
        const ushort* g = Wqkb + row * 256 + ((ch ^ (row & 7)) << 3);
        gload16(g, (char*)sW + p * 8192 + w * 1024);
    }
    const ushort* xb = xbf + (size_t)(b * 65536 + px0) * 256;
    #pragma unroll
    for (int p = 0; p < 8; ++p) {
        int m = p * 512 + t;
        int row = m >> 5, ch = m & 31;
        const ushort* g = xb + row * 256 + ((ch ^ (row & 7)) << 3);
        gload16(g, (char*)sX + p * 8192 + w * 1024);
    }
    __syncthreads();

    int l15 = lane & 15, l4 = lane >> 4;
    floatx4 acc[2][2];
    #pragma unroll
    for (int m2 = 0; m2 < 2; ++m2)
        #pragma unroll
        for (int n2 = 0; n2 < 2; ++n2)
            acc[m2][n2] = {0.f, 0.f, 0.f, 0.f};

    #pragma unroll
    for (int ks = 0; ks < 8; ++ks) {
        int cidx = ks * 4 + l4;
        short8 af[2];
        #pragma unroll
        for (int m2 = 0; m2 < 2; ++m2) {
            int row = wr * 32 + m2 * 16 + l15;
            af[m2] = *(const short8*)((const char*)sW + row * 512 + ((cidx ^ (row & 7)) << 4));
        }
        #pragma unroll
        for (int n2 = 0; n2 < 2; ++n2) {
            int row = wc * 32 + n2 * 16 + l15;
            short8 bf_ = *(const short8*)((const char*)sX + row * 512 + ((cidx ^ (row & 7)) << 4));
            #pragma unroll
            for (int m2 = 0; m2 < 2; ++m2)
                acc[m2][n2] = __builtin_amdgcn_mfma_f32_16x16x32_bf16(af[m2], bf_, acc[m2][n2], 0, 0, 0);
        }
    }

    const float* bias = wr ? bk : bq;
    float* outp = wr ? Ko : Qo;
    float bb[2][4];
    #pragma unroll
    for (int m2 = 0; m2 < 2; ++m2)
        #pragma unroll
        for (int r = 0; r < 4; ++r)
            bb[m2][r] = bias[m2 * 16 + l4 * 4 + r];

    #pragma unroll
    for (int n2 = 0; n2 < 2; ++n2) {
        float v[2][4];
        float s = 0.f;
        #pragma unroll
        for (int m2 = 0; m2 < 2; ++m2)
            #pragma unroll
            for (int r = 0; r < 4; ++r) {
                float vv = acc[m2][n2][r] + bb[m2][r];
                v[m2][r] = vv;
                s += vv * vv;
            }
        s += __shfl_xor(s, 16);
        s += __shfl_xor(s, 32);
        float rn = rsqrtf(s);
        int px = px0 + wc * 32 + n2 * 16 + l15;
        #pragma unroll
        for (int m2 = 0; m2 < 2; ++m2)
            #pragma unroll
            for (int r = 0; r < 4; ++r) {
                int oc = m2 * 16 + l4 * 4 + r;
                outp[((size_t)(b * 32 + oc) << 16) + px] = v[m2][r] * rn;
            }
    }
}

// ---------------------------------------------------------------------------
// K2: partial KX/xsum/Ksum per block (atomic-free). 1024 blocks, 128 px each.
// ---------------------------------------------------------------------------
__global__ __launch_bounds__(256) void k2_kx(const float* __restrict__ x,
        const float* __restrict__ Kn, float* __restrict__ KXp,
        float* __restrict__ xsp, float* __restrict__ ksp)
{
    int blk = blockIdx.x;
    int b = blk >> 9;
    int blkl = blk & 511;
    int t = threadIdx.x;
    int pxl = t & 63, g = t >> 6;
    __shared__ float xT[256][65];
    __shared__ float kT[32][64];
    float acc[32];
    #pragma unroll
    for (int m = 0; m < 32; ++m) acc[m] = 0.f;
    float xs = 0.f, ks = 0.f;
    for (int i = 0; i < 2; ++i) {
        int n0 = (blkl * 2 + i) * 64;
        __syncthreads();
        for (int j = 0; j < 64; ++j) {
            int c = j * 4 + g;
            xT[c][pxl] = x[(size_t)(b * 256 + c) * Nc + n0 + pxl];
        }
        #pragma unroll
        for (int j = 0; j < 8; ++j) {
            int m = j * 4 + g;
            kT[m][pxl] = Kn[((size_t)b * 32 + m) * Nc + n0 + pxl];
        }
        __syncthreads();
        for (int p4 = 0; p4 < 16; ++p4) {
            float x0 = xT[t][p4 * 4 + 0];
            float x1 = xT[t][p4 * 4 + 1];
            float x2 = xT[t][p4 * 4 + 2];
            float x3 = xT[t][p4 * 4 + 3];
            xs += x0 + x1 + x2 + x3;
            #pragma unroll
            for (int m = 0; m < 32; ++m) {
                floatx4 kv = *(const floatx4*)&kT[m][p4 * 4];
                acc[m] += kv[0] * x0 + kv[1] * x1 + kv[2] * x2 + kv[3] * x3;
            }
        }
        if (t < 32) {
            for (int p = 0; p < 64; ++p) ks += kT[t][p];
        }
    }
    xsp[blk * 256 + t] = xs;
    if (t < 32) ksp[blk * 32 + t] = ks;
    #pragma unroll
    for (int m = 0; m < 32; ++m) KXp[(size_t)blk * 8192 + m * 256 + t] = acc[m];
}

// ---------------------------------------------------------------------------
// K2R: reduce partials -> KX, xsum, Ksum
// ---------------------------------------------------------------------------
__global__ __launch_bounds__(256) void k2r(const float* __restrict__ KXp,
        const float* __restrict__ xsp, const float* __restrict__ ksp,
        float* __restrict__ KX, float* __restrict__ xsum, float* __restrict__ Ksum)
{
    int blk = blockIdx.x, t = threadIdx.x;
    if (blk < 64) {
        int gidx = blk * 256 + t;
        int b = gidx >> 13, idx = gidx & 8191;
        float s = 0.f;
        for (int ch = 0; ch < 512; ++ch)
            s += KXp[(size_t)((b << 9) + ch) * 8192 + idx];
        KX[gidx] = s;
    } else if (blk < 66) {
        int b = blk - 64;
        float s = 0.f;
        for (int ch = 0; ch < 512; ++ch)
            s += xsp[((b << 9) + ch) * 256 + t];
        xsum[b * 256 + t] = s;
    } else {
        int b = blk - 66;
        if (t < 32) {
            float s = 0.f;
            for (int ch = 0; ch < 512; ++ch)
                s += ksp[((b << 9) + ch) * 32 + t];
            Ksum[b * 32 + t] = s;
        }
    }
}

// ---------------------------------------------------------------------------
// K3: matrix/vsum from KX, xsum, Ksum
// ---------------------------------------------------------------------------
__global__ __launch_bounds__(256) void k3_mat(const float* __restrict__ wv,
        const float* __restrict__ bv, const float* __restrict__ KX,
        const float* __restrict__ xsum, const float* __restrict__ Ksum,
        float* __restrict__ matrix, float* __restrict__ vsum)
{
    int b = blockIdx.x, t = threadIdx.x;
    __shared__ float sx[256];
    __shared__ float sk[32];
    __shared__ float skx[32][256];
    __shared__ float wT[256][65];
    sx[t] = xsum[b * 256 + t];
    if (t < 32) sk[t] = Ksum[b * 32 + t];
    for (int j = 0; j < 32; ++j) skx[j][t] = KX[(b * 32 + j) * 256 + t];
    float vs = bv[t] * (float)Nc;
    float mv[32];
    #pragma unroll
    for (int m = 0; m < 32; ++m) mv[m] = 0.f;
    for (int cc0 = 0; cc0 < 256; cc0 += 64) {
        __syncthreads();
        for (int i = 0; i < 64; ++i) {
            int c = i * 4 + (t >> 6);
            wT[c][t & 63] = wv[(size_t)c * 256 + cc0 + (t & 63)];
        }
        __syncthreads();
        for (int ccl = 0; ccl < 64; ++ccl) {
            float w = wT[t][ccl];
            int cc = cc0 + ccl;
            vs += w * sx[cc];
            #pragma unroll
            for (int m = 0; m < 32; ++m) mv[m] += w * skx[m][cc];
        }
    }
    vsum[b * 256 + t] = vs;
    float bvt = bv[t];
    for (int m = 0; m < 32; ++m) matrix[(b * 32 + m) * 256 + t] = mv[m] + bvt * sk[m];
}

// ---------------------------------------------------------------------------
// K4: z = x + gamma * (vsum[c] + sum_m Q[m,n]*matrix[m,c]) * tailor[n]
// ---------------------------------------------------------------------------
__global__ __launch_bounds__(256) void k4_z(const float* __restrict__ x,
        const float* __restrict__ Q, const float* __restrict__ matrix,
        const float* __restrict__ vsum, const float* __restrict__ Ksum,
        const float* __restrict__ gamma_p, float* __restrict__ z)
{
    int b = blockIdx.x >> 10;
    int n0 = (blockIdx.x & 1023) * 64;
    int t = threadIdx.x;
    int px = t & 63, g = t >> 6;
    __shared__ float qT[32][64];
    __shared__ float mat[32][256];
    __shared__ float vs[256];
    __shared__ float tail[64];
    __shared__ float sk[32];
    #pragma unroll
    for (int j = 0; j < 8; ++j) {
        int m = j * 4 + g;
        qT[m][px] = Q[((size_t)b * 32 + m) * Nc + n0 + px];
    }
    for (int j = 0; j < 32; ++j) {
        int idx = j * 256 + t;
        (&mat[0][0])[idx] = matrix[b * 8192 + idx];
    }
    vs[t] = vsum[b * 256 + t];
    if (t < 32) sk[t] = Ksum[b * 32 + t] + LA_EPS;
    __syncthreads();
    if (t < 64) {
        float s = 0.f;
        #pragma unroll
        for (int m = 0; m < 32; ++m) s += qT[m][t] * sk[m];
        tail[t] = 1.0f / ((float)Nc + s);
    }
    __syncthreads();
    float gamma = gamma_p[0];
    for (int l = 0; l < 64; ++l) {
        int c = l * 4 + g;
        float s = vs[c];
        #pragma unroll
        for (int m = 0; m < 32; ++m) s += qT[m][px] * mat[m][c];
        size_t idx = (size_t)(b * 256 + c) * Nc + n0 + px;
        z[idx] = x[idx] + gamma * s * tail[px];
    }
}

// ---------------------------------------------------------------------------
// KPREP_Y: y (NCHW f32) -> ybf (padded NHWC bf16, [b][258][258][256], origin +1)
// ---------------------------------------------------------------------------
__global__ __launch_bounds__(256) void kprep_y(const float* __restrict__ y,
        ushort* __restrict__ ybf)
{
    int blk = blockIdx.x;
    int b = blk >> 13;
    int rest = blk & 8191;
    int ci0 = (rest & 7) * 32;
    int n0 = (rest >> 3) * 64;
    int row = n0 >> 8, x = n0 & 255;
    int t = threadIdx.x;
    __shared__ uint u[16][65];
    int px = t & 63, cig = t >> 6;
    const float* yb = y + (((size_t)(b * 256 + ci0 + cig * 8)) << 16) + n0 + px;
    #pragma unroll
    for (int jj = 0; jj < 4; ++jj) {
        float v0 = yb[((size_t)(jj * 2)) << 16];
        float v1 = yb[((size_t)(jj * 2 + 1)) << 16];
        u[cig * 4 + jj][px] = pack2(v0, v1);
    }
    __syncthreads();
    uint* out32 = (uint*)ybf;
    size_t pbase = (size_t)(row + 1) * 258 + (x + 1);
    int pr = t & 15, pg = t >> 4;
    #pragma unroll
    for (int g2 = 0; g2 < 4; ++g2) {
        int ppx = g2 * 16 + pg;
        size_t uidx = (((size_t)b * 258 * 258 * 256 + (pbase + ppx) * 256 + ci0) >> 1) + pr;
        out32[uidx] = u[pr][ppx];
    }
}

// ---------------------------------------------------------------------------
// KPREP_W: Wb[tap][co][ci] = bf16(wl1[co][ci][tap]*s1[co] + (tap==4)*wl2[co][ci]*s2[co])
// ---------------------------------------------------------------------------
__global__ __launch_bounds__(256) void kprep_w(const float* __restrict__ wl1,
        const float* __restrict__ s1, const float* __restrict__ wl2,
        const float* __restrict__ s2, ushort* __restrict__ Wb)
{
    int idx = blockIdx.x * 256 + threadIdx.x;
    int tp = idx >> 16;
    int r = idx & 65535;
    int co = r >> 8;
    float v = wl1[(size_t)r * 9 + tp] * s1[co];
    if (tp == 4) v += wl2[r] * s2[co];
    Wb[idx] = f2bf(v);
}

// ---------------------------------------------------------------------------
// KPREP_QW: Wqb = bf16(wqkv), q rows (0..255) pre-scaled by 0.25 (= d^-0.5)
// ---------------------------------------------------------------------------
__global__ __launch_bounds__(256) void kprep_qw(const float* __restrict__ wqkv,
        ushort* __restrict__ Wqb)
{
    int idx = blockIdx.x * 256 + threadIdx.x;   // 768*256 = 196608
    float v = wqkv[idx];
    if (idx < 65536) v *= 0.25f;
    Wqb[idx] = f2bf(v);
}

// ---------------------------------------------------------------------------
// KPREP_PW: Wpwb = bf16(wpw)
// ---------------------------------------------------------------------------
__global__ __launch_bounds__(256) void kprep_pw(const float* __restrict__ wpw,
        ushort* __restrict__ Wpwb)
{
    int idx = blockIdx.x * 256 + threadIdx.x;   // 65536
    Wpwb[idx] = f2bf(wpw[idx]);
}

// ---------------------------------------------------------------------------
// K5 (MFMA): L = conv3x3(ybf, Wc) + bias   -- 1x1 branch folded into center tap
// inner loop reordered (single live bfr) to stay under the 128-VGPR cap
// ---------------------------------------------------------------------------
__global__ __launch_bounds__(512, 2) void k5_mfma(
        const ushort* __restrict__ ybf, const ushort* __restrict__ Wb,
        const float* __restrict__ b1, const float* __restrict__ b2,
        float* __restrict__ L)
{
    int blk = blockIdx.x;
    int b = blk >> 9;
    int y0 = (blk >> 1) & 255;
    int x0 = (blk & 1) << 7;
    int t = threadIdx.x;
    int lane = t & 63;
    int w = t >> 6;
    int wr = w >> 1;
    int wc = w & 1;

    __shared__ ushort sW[256 * 64];
    __shared__ ushort sY[128 * 64];

    floatx4 acc[4][4];
    #pragma unroll
    for (int m = 0; m < 4; ++m)
        #pragma unroll
        for (int n = 0; n < 4; ++n)
            acc[m][n] = {0.f, 0.f, 0.f, 0.f};

    const ushort* yb = ybf + (size_t)b * 258 * 258 * 256;
    int ldsWbase = w * 64 * 16;
    int ldsYbase = w * 64 * 16;

    for (int tp = 0; tp < 9; ++tp) {
        int dy = tp / 3 - 1, dx = tp % 3 - 1;
        const ushort* yrow = yb + ((size_t)(y0 + dy + 1) * 258 + (x0 + dx + 1)) * 256;
        const ushort* wtap = Wb + tp * 65536;
        for (int cb = 0; cb < 4; ++cb) {
            int ci0 = cb * 64;
            __syncthreads();
            #pragma unroll
            for (int p = 0; p < 4; ++p) {
                int m = p * 512 + t;
                int row = m >> 3, ch = m & 7;
                const ushort* g = wtap + row * 256 + ci0 + ((ch ^ (row & 7)) << 3);
                gload16(g, (char*)sW + p * 512 * 16 + ldsWbase);
            }
            #pragma unroll
            for (int p = 0; p < 2; ++p) {
                int m = p * 512 + t;
                int pxr = m >> 3, ch = m & 7;
                const ushort* g = yrow + (size_t)pxr * 256 + ci0 + ((ch ^ (pxr & 7)) << 3);
                gload16(g, (char*)sY + p * 512 * 16 + ldsYbase);
            }
            __syncthreads();
            #pragma unroll
            for (int kk = 0; kk < 2; ++kk) {
                int chunkb = kk * 4 + (lane >> 4);
                short8 afr[4];
                #pragma unroll
                for (int m2 = 0; m2 < 4; ++m2) {
                    int row = wr * 64 + m2 * 16 + (lane & 15);
                    int ch = chunkb ^ (row & 7);
                    afr[m2] = *(const short8*)((const char*)sW + row * 128 + ch * 16);
                }
                #pragma unroll
                for (int n2 = 0; n2 < 4; ++n2) {
                    int row = wc * 64 + n2 * 16 + (lane & 15);
                    int ch = chunkb ^ (row & 7);
                    short8 bfr = *(const short8*)((const char*)sY + row * 128 + ch * 16);
                    #pragma unroll
                    for (int m2 = 0; m2 < 4; ++m2)
                        acc[m2][n2] = __builtin_amdgcn_mfma_f32_16x16x32_bf16(
                            afr[m2], bfr, acc[m2][n2], 0, 0, 0);
                }
            }
        }
    }
    int pxb = x0 + wc * 64 + (lane & 15);
    #pragma unroll
    for (int m2 = 0; m2 < 4; ++m2) {
        int cobase = wr * 64 + m2 * 16 + (lane >> 4) * 4;
        #pragma unroll
        for (int r = 0; r < 4; ++r) {
            int co = cobase + r;
            float bias = b1[co] + b2[co];
            float* dst = L + (((size_t)(b * 256 + co)) << 16) + y0 * 256 + pxb;
            #pragma unroll
            for (int n2 = 0; n2 < 4; ++n2)
                dst[n2 * 16] = acc[m2][n2][r] + bias;
        }
    }
}

// ---------------------------------------------------------------------------
// K6 (MFMA, fused): qkv + window attention, TWO adjacent windows per block.
// (512,1): LDS already limits to 1 block/CU; per-it S/softmax/PV cuts VGPRs.
// ---------------------------------------------------------------------------
__global__ __launch_bounds__(512, 1) void k6_mfma(const float* __restrict__ z,
        const ushort* __restrict__ Wqb, const float* __restrict__ rel,
        float* __restrict__ A)
{
    int blk = blockIdx.x;
    int wxp = blk & 15, wy = (blk >> 4) & 31, b = blk >> 9;
    int t = threadIdx.x;
    int lane = t & 63;
    int w = t >> 6;
    int win = w >> 2;
    int wq4 = w & 3;

    __shared__ ushort zT[128 * 256];     // [pxg][ci] bf16, xor-swizzled (64 KB)
    __shared__ float srel[3600];         // rel bias table (14.4 KB)
    __shared__ ushort wbuf[8][4096];     // per-wave: qT / kT / vD

    char* zTc = (char*)zT;

    #pragma unroll
    for (int i = 0; i < 32; ++i) {
        int idx = i * 512 + t;
        int cp = idx >> 7;          // ci pair 0..127
        int pxg = idx & 127;
        int px = pxg & 63;
        int gy = wy * 8 + (px >> 3);
        int gx = (wxp * 2 + (pxg >> 6)) * 8 + (px & 7);
        const float* zp = z + ((size_t)(b * 256 + cp * 2) << 16) + gy * 256 + gx;
        uint pv = pack2(zp[0], zp[1ull << 16]);
        *(uint*)(zTc + pxg * 512 + (((cp >> 2) ^ (pxg & 7)) << 4) + (cp & 3) * 4) = pv;
    }
    for (int i = t; i < 3600; i += 512) srel[i] = rel[i];
    __syncthreads();

    char* qTb = (char*)&wbuf[w][0];
    char* kTb = (char*)&wbuf[w][1024];
    char* vDb = (char*)&wbuf[w][2048];

    int l15 = lane & 15, l4 = lane >> 4;
    int l31 = lane & 31, l5 = lane >> 5;
    bool hilane = (l5 != 0);
    int pxbase = win * 64;

    for (int hrep = 0; hrep < 4; ++hrep) {
        int h = wq4 * 4 + hrep;

        // ---- q-GEMM ----
        floatx4 qacc[4] = {};
        #pragma unroll
        for (int ks = 0; ks < 8; ++ks) {
            short8 aw = *(const short8*)(Wqb + ((h * 16 + l15) << 8) + ks * 32 + (l4 << 3));
            #pragma unroll
            for (int n = 0; n < 4; ++n) {
                int px = n * 16 + l15;
                short8 bz = *(const short8*)(zTc + (pxbase + px) * 512 + (((ks * 4 + l4) ^ (px & 7)) << 4));
                qacc[n] = __builtin_amdgcn_mfma_f32_16x16x32_bf16(aw, bz, qacc[n], 0, 0, 0);
            }
        }
        #pragma unroll
        for (int n = 0; n < 4; ++n) {
            int px = n * 16 + l15;
            uint2 wv = { pack2(qacc[n][0], qacc[n][1]), pack2(qacc[n][2], qacc[n][3]) };
            *(uint2*)(qTb + px * 32 + (l4 << 3)) = wv;
        }

        // ---- kT-GEMM ----
        floatx4 kacc[4] = {};
        #pragma unroll
        for (int ks = 0; ks < 8; ++ks) {
            short8 bw = *(const short8*)(Wqb + ((256 + h * 16 + l15) << 8) + ks * 32 + (l4 << 3));
            #pragma unroll
            for (int m = 0; m < 4; ++m) {
                int px = m * 16 + l15;
                short8 az = *(const short8*)(zTc + (pxbase + px) * 512 + (((ks * 4 + l4) ^ (px & 7)) << 4));
                kacc[m] = __builtin_amdgcn_mfma_f32_16x16x32_bf16(az, bw, kacc[m], 0, 0, 0);
            }
        }
        #pragma unroll
        for (int m = 0; m < 4; ++m) {
            #pragma unroll
            for (int r = 0; r < 4; ++r) {
                int px = m * 16 + l4 * 4 + r;
                *(ushort*)(kTb + px * 32 + l15 * 2) = f2bf(kacc[m][r]);
            }
        }

        // ---- v-GEMM ----
        floatx4 vacc[4] = {};
        #pragma unroll
        for (int ks = 0; ks < 8; ++ks) {
            short8 aw = *(const short8*)(Wqb + ((512 + h * 16 + l15) << 8) + ks * 32 + (l4 << 3));
            #pragma unroll
            for (int n = 0; n < 4; ++n) {
                int px = n * 16 + l15;
                short8 bz = *(const short8*)(zTc + (pxbase + px) * 512 + (((ks * 4 + l4) ^ (px & 7)) << 4));
                vacc[n] = __builtin_amdgcn_mfma_f32_16x16x32_bf16(aw, bz, vacc[n], 0, 0, 0);
            }
        }
        #pragma unroll
        for (int n = 0; n < 4; ++n) {
            int px = n * 16 + l15;
            #pragma unroll
            for (int r = 0; r < 4; ++r) {
                int d = l4 * 4 + r;
                *(ushort*)(vDb + d * 128 + ((((px >> 3) ^ (d & 7)) << 4) + (px & 7) * 2)) = f2bf(vacc[n][r]);
            }
        }

        // ---- per-it: S^T, softmax, PV (halves live S registers) ----
        #pragma unroll
        for (int it = 0; it < 2; ++it) {
            short8 bq_ = *(const short8*)(qTb + (it * 32 + l31) * 32 + (l5 << 4));
            floatx16 st[2];
            #pragma unroll
            for (int jt = 0; jt < 2; ++jt) {
                short8 ak = *(const short8*)(kTb + (jt * 32 + l31) * 32 + (l5 << 4));
                floatx16 zc = {};
                st[jt] = __builtin_amdgcn_mfma_f32_32x32x16_bf16(ak, bq_, zc, 0, 0, 0);
            }
            int i = it * 32 + l31;
            int Ai = (i >> 3) * 15 + (i & 7) + 112;
            float mx = -1e30f;
            #pragma unroll
            for (int jt = 0; jt < 2; ++jt)
                #pragma unroll
                for (int r = 0; r < 16; ++r) {
                    int j = jt * 32 + (r & 3) + 8 * (r >> 2) + 4 * l5;
                    int Bjr = (j >> 3) * 15 + (j & 7);
                    float s = st[jt][r] + srel[(Ai - Bjr) * 16 + h];
                    st[jt][r] = s;
                    mx = fmaxf(mx, s);
                }
            mx = fmaxf(mx, __shfl_xor(mx, 32));
            float sum = 0.f;
            #pragma unroll
            for (int jt = 0; jt < 2; ++jt)
                #pragma unroll
                for (int r = 0; r < 16; ++r) {
                    float e = __expf(st[jt][r] - mx);
                    st[jt][r] = e;
                    sum += e;
                }
            sum += __shfl_xor(sum, 32);
            float rinv = 1.0f / sum;

            floatx16 ot = {};
            #pragma unroll
            for (int jc = 0; jc < 4; ++jc) {
                int jt = jc >> 1, rb = (jc & 1) * 8;
                uint u0 = pack2(st[jt][rb + 0], st[jt][rb + 1]);
                uint u1 = pack2(st[jt][rb + 2], st[jt][rb + 3]);
                uint u2 = pack2(st[jt][rb + 4], st[jt][rb + 5]);
                uint u3 = pack2(st[jt][rb + 6], st[jt][rb + 7]);
                uint s0 = __shfl_xor(u0, 32);
                uint s1 = __shfl_xor(u1, 32);
                uint s2 = __shfl_xor(u2, 32);
                uint s3 = __shfl_xor(u3, 32);
                union { short8 v; uint u[4]; } bf;
                bf.u[0] = hilane ? s2 : u0;
                bf.u[1] = hilane ? s3 : u1;
                bf.u[2] = hilane ? u2 : s0;
                bf.u[3] = hilane ? u3 : s1;
                short8 av = *(const short8*)(vDb + l31 * 128 + (((jc * 2 + l5) ^ (l31 & 7)) << 4));
                ot = __builtin_amdgcn_mfma_f32_32x32x16_bf16(av, bf.v, ot, 0, 0, 0);
            }
            int gy = wy * 8 + (i >> 3);
            int gx = (wxp * 2 + win) * 8 + (i & 7);
            float* Ab = A + (((size_t)(b * 256 + h * 16)) << 16) + gy * 256 + gx;
            #pragma unroll
            for (int r = 0; r < 8; ++r) {
                int d = (r & 3) + 8 * (r >> 2) + 4 * l5;
                Ab[(size_t)d << 16] = ot[r] * rinv;
            }
        }
    }
}

// ---------------------------------------------------------------------------
// K7: L += avgpools of A
// ---------------------------------------------------------------------------
__global__ __launch_bounds__(256) void k7_pool(const float* __restrict__ A,
        float* __restrict__ L)
{
    size_t idx = (size_t)blockIdx.x * 256 + threadIdx.x;
    int j = (int)(idx & 255);
    int i = (int)((idx >> 8) & 255);
    size_t bc = idx >> 16;
    const float* Abc = A + (bc << 16);
    float sv = 0.f, sh = 0.f;
    #pragma unroll
    for (int u = 0; u < 8; ++u) {
        int r = i - 3 + u;
        if (r >= 0 && r <= 256) {
            int rr = (r == 256) ? 254 : r;
            sv += Abc[rr * 256 + j];
        }
        int c2 = j - 3 + u;
        if (c2 >= 0 && c2 <= 256) {
            int cc = (c2 == 256) ? 254 : c2;
            sh += Abc[i * 256 + cc];
        }
    }
    L[idx] += 0.125f * (sv + sh);
}

// ---------------------------------------------------------------------------
// K8: D(bf16) = sp * dwconv8x8(pad_out(P), wdw, pad=3) + bp
// ---------------------------------------------------------------------------
__global__ __launch_bounds__(256) void k8_dw(const float* __restrict__ P,
        const float* __restrict__ wdw, const float* __restrict__ sp,
        const float* __restrict__ bp, ushort* __restrict__ D)
{
    int blk = blockIdx.x;
    int tile = blk & 255;
    int c = (blk >> 8) & 255;
    int b = blk >> 16;
    int ty = tile >> 4, tx = tile & 15;
    int t = threadIdx.x;
    __shared__ float pT[23][24];
    __shared__ float wT[64];
    const float* Pc = P + ((size_t)(b * 256 + c) << 16);
    for (int i = t; i < 529; i += 256) {
        int yy = i / 23, xx = i - yy * 23;
        int gy = ty * 16 - 3 + yy, gx = tx * 16 - 3 + xx;
        float v = 0.f;
        if (gy >= 0 && gy <= 256 && gx >= 0 && gx <= 256) {
            int ry = (gy == 256) ? 254 : gy;
            int rx = (gx == 256) ? 254 : gx;
            v = Pc[ry * 256 + rx];
        }
        pT[yy][xx] = v;
    }
    if (t < 64) wT[t] = wdw[c * 64 + t];
    __syncthreads();
    int yy = t >> 4, xx = t & 15;
    float acc = 0.f;
    #pragma unroll
    for (int u = 0; u < 8; ++u)
        #pragma unroll
        for (int v = 0; v < 8; ++v)
            acc += wT[u * 8 + v] * pT[yy + u][xx + v];
    D[((size_t)(b * 256 + c) << 16) + (ty * 16 + yy) * 256 + tx * 16 + xx] =
        f2bf(sp[c] * acc + bp[c]);
}

// ---------------------------------------------------------------------------
// K9 (MFMA): out[co][px] = sum_ci Wpw[co][ci] * D[ci][px]
// ---------------------------------------------------------------------------
__global__ __launch_bounds__(512, 2) void k9_mfma(
        const ushort* __restrict__ D, const ushort* __restrict__ Wpwb,
        float* __restrict__ out)
{
    int blk = blockIdx.x;
    int b = blk >> 9;
    int px0 = (blk & 511) << 7;
    int t = threadIdx.x;
    int lane = t & 63;
    int w = t >> 6;
    int wr = w >> 1, wc = w & 1;

    __shared__ ushort sW[256 * 64];   // [co][ci] swizzled, 32KB
    __shared__ ushort sD[128 * 64];   // [px][ci] swizzled, 16KB

    floatx4 acc[4][4];
    #pragma unroll
    for (int m = 0; m < 4; ++m)
        #pragma unroll
        for (int n = 0; n < 4; ++n)
            acc[m][n] = {0.f, 0.f, 0.f, 0.f};

    int ldsWbase = w * 64 * 16;

    for (int cb = 0; cb < 4; ++cb) {
        int ci0 = cb * 64;
        __syncthreads();
        #pragma unroll
        for (int p = 0; p < 4; ++p) {
            int m = p * 512 + t;
            int row = m >> 3, ch = m & 7;
            const ushort* g = Wpwb + row * 256 + ci0 + ((ch ^ (row & 7)) << 3);
            gload16(g, (char*)sW + p * 512 * 16 + ldsWbase);
        }
        #pragma unroll
        for (int p = 0; p < 2; ++p) {
            int m = p * 512 + t;
            int ci = m & 63, pxb = (m >> 6) * 8;
            short8 v = *(const short8*)(D + ((size_t)(b * 256 + ci0 + ci) << 16) + px0 + pxb);
            #pragma unroll
            for (int k2 = 0; k2 < 8; ++k2) {
                int px = pxb + k2;
                *(ushort*)((char*)sD + px * 128 + (((ci >> 3) ^ (px & 7)) << 4) + (ci & 7) * 2) =
                    (ushort)v[k2];
            }
        }
        __syncthreads();
        #pragma unroll
        for (int kk = 0; kk < 2; ++kk) {
            int chunkb = kk * 4 + (lane >> 4);
            short8 afr[4];
            #pragma unroll
            for (int m2 = 0; m2 < 4; ++m2) {
                int row = wr * 64 + m2 * 16 + (lane & 15);
                int ch = chunkb ^ (row & 7);
                afr[m2] = *(const short8*)((const char*)sW + row * 128 + ch * 16);
            }
            #pragma unroll
            for (int n2 = 0; n2 < 4; ++n2) {
                int row = wc * 64 + n2 * 16 + (lane & 15);
                int ch = chunkb ^ (row & 7);
                short8 bfr = *(const short8*)((const char*)sD + row * 128 + ch * 16);
                #pragma unroll
                for (int m2 = 0; m2 < 4; ++m2)
                    acc[m2][n2] = __builtin_amdgcn_mfma_f32_16x16x32_bf16(
                        afr[m2], bfr, acc[m2][n2], 0, 0, 0);
            }
        }
    }
    int pxb = px0 + wc * 64 + (lane & 15);
    #pragma unroll
    for (int m2 = 0; m2 < 4; ++m2) {
        int cobase = wr * 64 + m2 * 16 + (lane >> 4) * 4;
        #pragma unroll
        for (int r = 0; r < 4; ++r) {
            int co = cobase + r;
            float* dst = out + (((size_t)(b * 256 + co)) << 16) + pxb;
            #pragma unroll
            for (int n2 = 0; n2 < 4; ++n2)
                dst[n2 * 16] = acc[m2][n2][r];
        }
    }
}

// ---------------------------------------------------------------------------
extern "C" void kernel_launch(void* const* d_in, const int* in_sizes, int n_in,
                              void* d_out, int out_size, void* d_ws, size_t ws_size,
                              hipStream_t stream)
{
    (void)in_sizes; (void)n_in; (void)out_size; (void)ws_size;
    const float* x     = (const float*)d_in[0];
    const float* y     = (const float*)d_in[1];
    const float* gamma = (const float*)d_in[2];
    const float* la_wq = (const float*)d_in[3];
    const float* la_bq = (const float*)d_in[4];
    const float* la_wk = (const float*)d_in[5];
    const float* la_bk = (const float*)d_in[6];
    const float* la_wv = (const float*)d_in[7];
    const float* la_bv = (const float*)d_in[8];
    const float* wqkv  = (const float*)d_in[9];
    const float* wl1   = (const float*)d_in[10];
    const float* s1    = (const float*)d_in[11];
    const float* b1    = (const float*)d_in[12];
    const float* wl2   = (const float*)d_in[13];
    const float* s2    = (const float*)d_in[14];
    const float* b2    = (const float*)d_in[15];
    const float* rel   = (const float*)d_in[16];
    const float* wdw   = (const float*)d_in[17];
    const float* sp    = (const float*)d_in[18];
    const float* bp    = (const float*)d_in[19];
    const float* wpw   = (const float*)d_in[20];
    float* out = (float*)d_out;

    float* ws = (float*)d_ws;
    float* Q      = ws;                      // 4,194,304 floats (Qo)
    float* Kn     = ws + 4194304;            // 4,194,304 (W-preps alias after k2)
    float* stats  = ws + 8388608;            // 40,960 floats
    float* Ksum   = stats;                   // 64
    float* xsum   = stats + 64;              // 512
    float* KX     = stats + 576;             // 16,384
    float* matrix = stats + 16960;           // 16,384
    float* vsum   = stats + 33344;           // 512
    float* A      = ws + 8429568;            // 33,554,432 (ybf alias; attn out; Dbf)
    float* L      = A + 33554432;            // 33,554,432

    // L-region phase-1 aliases (all dead before k5 writes L):
    float* KXp   = L;                        // 1024 x 8192 = 8,388,608
    float* xsp   = L + 8388608;              // 1024 x 256  = 262,144
    float* ksp   = L + 8650752;              // 1024 x 32   = 32,768
    ushort* xbf  = (ushort*)(L + 8683520);   // 33,554,432 ushorts (x NHWC bf16)
    ushort* Wqkb = (ushort*)(L + 25460736);  // 16,384 ushorts

    ushort* Wb   = (ushort*)Kn;              // conv weights, 589,824 bf16
    ushort* Wqb  = (ushort*)Kn + 600064;     // qkv weights, 196,608 bf16
    ushort* Wpwb = (ushort*)Kn + 798720;     // pw weights, 65,536 bf16
    ushort* ybf  = (ushort*)A;               // padded NHWC y, bf16 — until k6
    ushort* Dbf  = (ushort*)A;               // bf16 dwconv out — after k8

    hipMemsetAsync(ybf, 0, (size_t)2 * 258 * 258 * 256 * sizeof(ushort), stream);

    kprep_y <<<16384, 256, 0, stream>>>(y, ybf);
    kprep_x <<<16384, 256, 0, stream>>>(x, xbf);
    kprep_qk<<<64,    256, 0, stream>>>(la_wq, la_wk, Wqkb);
    k1_mfma <<<1024,  512, 0, stream>>>(xbf, Wqkb, la_bq, la_bk, Q, Kn);
    k2_kx   <<<1024,  256, 0, stream>>>(x, Kn, KXp, xsp, ksp);
    kprep_w <<<2304,  256, 0, stream>>>(wl1, s1, wl2, s2, Wb);  // Kn dead after k2
    kprep_qw<<<768,   256, 0, stream>>>(wqkv, Wqb);
    kprep_pw<<<256,   256, 0, stream>>>(wpw, Wpwb);
    k2r     <<<68,    256, 0, stream>>>(KXp, xsp, ksp, KX, xsum, Ksum);
    k3_mat  <<<2,     256, 0, stream>>>(la_wv, la_bv, KX, xsum, Ksum, matrix, vsum);
    k4_z    <<<2048,  256, 0, stream>>>(x, Q, matrix, vsum, Ksum, gamma, out);
    k5_mfma <<<1024,  512, 0, stream>>>(ybf, Wb, b1, b2, L);    // overwrites xbf etc
    k6_mfma <<<1024,  512, 0, stream>>>(out, Wqb, rel, A);      // overwrites ybf
    k7_pool <<<131072,256, 0, stream>>>(A, L);
    k8_dw   <<<131072,256, 0, stream>>>(L, wdw, sp, bp, Dbf);
    k9_mfma <<<1024,  512, 0, stream>>>(Dbf, Wpwb, out);
}

// Round 6
// 1526.966 us; speedup vs baseline: 7.0407x; 1.2337x over previous
//
#include <hip/hip_runtime.h>
#include <hip/hip_bf16.h>

#define DI __device__ __forceinline__

constexpr int Bc = 2, Cc = 256, Hc = 256, Wc = 256, Nc = Hc * Wc; // N=65536
constexpr float LA_EPS = 1e-6f;

typedef __attribute__((ext_vector_type(8))) short short8;
typedef __attribute__((ext_vector_type(4))) float floatx4;
typedef __attribute__((ext_vector_type(16))) float floatx16;

DI ushort f2bf(float f) {
    uint u = __float_as_uint(f);
    uint r = (u + 0x7fff + ((u >> 16) & 1)) >> 16;
    return (ushort)r;
}

DI uint pack2(float a, float b) {
    return (uint)f2bf(a) | ((uint)f2bf(b) << 16);
}

DI void gload16(const void* g, void* l) {
    __builtin_amdgcn_global_load_lds(
        (const __attribute__((address_space(1))) void*)g,
        (__attribute__((address_space(3))) void*)l, 16, 0, 0);
}

// ---------------------------------------------------------------------------
// KPREP_X: NCHW f32 -> NHWC bf16 ([b][px][ci]); also reused for z transpose
// ---------------------------------------------------------------------------
__global__ __launch_bounds__(256) void kprep_x(const float* __restrict__ x,
        ushort* __restrict__ xbf)
{
    int blk = blockIdx.x;
    int b = blk >> 13;
    int rest = blk & 8191;
    int ci0 = (rest & 7) * 32;
    int n0 = (rest >> 3) * 64;
    int t = threadIdx.x;
    __shared__ uint u[16][65];
    int px = t & 63, cig = t >> 6;
    const float* yb = x + (((size_t)(b * 256 + ci0 + cig * 8)) << 16) + n0 + px;
    #pragma unroll
    for (int jj = 0; jj < 4; ++jj) {
        float v0 = yb[((size_t)(jj * 2)) << 16];
        float v1 = yb[((size_t)(jj * 2 + 1)) << 16];
        u[cig * 4 + jj][px] = pack2(v0, v1);
    }
    __syncthreads();
    uint* out32 = (uint*)xbf;
    int pr = t & 15, pg = t >> 4;
    #pragma unroll
    for (int g2 = 0; g2 < 4; ++g2) {
        int ppx = g2 * 16 + pg;
        size_t uidx = (((size_t)(b * 65536 + n0 + ppx) * 256 + ci0) >> 1) + pr;
        out32[uidx] = u[pr][ppx];
    }
}

// ---------------------------------------------------------------------------
// KPREP_QK: Wqkb[64][256] = bf16( rows 0-31: wq, rows 32-63: wk )
// ---------------------------------------------------------------------------
__global__ __launch_bounds__(256) void kprep_qk(const float* __restrict__ wq,
        const float* __restrict__ wk, ushort* __restrict__ Wqkb)
{
    int idx = blockIdx.x * 256 + threadIdx.x;   // 16384
    int oc = idx >> 8, ci = idx & 255;
    float v = (oc < 32) ? wq[oc * 256 + ci] : wk[(oc - 32) * 256 + ci];
    Wqkb[idx] = f2bf(v);
}

// ---------------------------------------------------------------------------
// K1 (MFMA): Q,K = 1x1 conv (32 ch each) + per-pixel channel L2-norm.
// ---------------------------------------------------------------------------
__global__ __launch_bounds__(512, 1) void k1_mfma(
        const ushort* __restrict__ xbf, const ushort* __restrict__ Wqkb,
        const float* __restrict__ bq, const float* __restrict__ bk,
        float* __restrict__ Qo, float* __restrict__ Ko)
{
    int blk = blockIdx.x;
    int b = blk >> 9;
    int px0 = (blk & 511) << 7;
    int t = threadIdx.x;
    int lane = t & 63, w = t >> 6;
    int wr = w >> 2;       // 0: q rows, 1: k rows
    int wc = w & 3;        // px quarter (32 px)

    __shared__ ushort sW[64 * 256];    // 32KB [oc][ci] swizzled
    __shared__ ushort sX[128 * 256];   // 64KB [px][ci] swizzled

    #pragma unroll
    for (int p = 0; p < 4; ++p) {
        int m = p * 512 + t;
        int row = m >> 5, ch = m & 31;
        const ushort* g = Wqkb + row * 256 + ((ch ^ (row & 7)) << 3);
        gload16(g, (char*)sW + p * 8192 + w * 1024);
    }
    const ushort* xb = xbf + (size_t)(b * 65536 + px0) * 256;
    #pragma unroll
    for (int p = 0; p < 8; ++p) {
        int m = p * 512 + t;
        int row = m >> 5, ch = m & 31;
        const ushort* g = xb + row * 256 + ((ch ^ (row & 7)) << 3);
        gload16(g, (char*)sX + p * 8192 + w * 1024);
    }
    __syncthreads();

    int l15 = lane & 15, l4 = lane >> 4;
    floatx4 acc[2][2];
    #pragma unroll
    for (int m2 = 0; m2 < 2; ++m2)
        #pragma unroll
        for (int n2 = 0; n2 < 2; ++n2)
            acc[m2][n2] = {0.f, 0.f, 0.f, 0.f};

    #pragma unroll
    for (int ks = 0; ks < 8; ++ks) {
        int cidx = ks * 4 + l4;
        short8 af[2];
        #pragma unroll
        for (int m2 = 0; m2 < 2; ++m2) {
            int row = wr * 32 + m2 * 16 + l15;
            af[m2] = *(const short8*)((const char*)sW + row * 512 + ((cidx ^ (row & 7)) << 4));
        }
        #pragma unroll
        for (int n2 = 0; n2 < 2; ++n2) {
            int row = wc * 32 + n2 * 16 + l15;
            short8 bf_ = *(const short8*)((const char*)sX + row * 512 + ((cidx ^ (row & 7)) << 4));
            #pragma unroll
            for (int m2 = 0; m2 < 2; ++m2)
                acc[m2][n2] = __builtin_amdgcn_mfma_f32_16x16x32_bf16(af[m2], bf_, acc[m2][n2], 0, 0, 0);
        }
    }

    const float* bias = wr ? bk : bq;
    float* outp = wr ? Ko : Qo;
    float bb[2][4];
    #pragma unroll
    for (int m2 = 0; m2 < 2; ++m2)
        #pragma unroll
        for (int r = 0; r < 4; ++r)
            bb[m2][r] = bias[m2 * 16 + l4 * 4 + r];

    #pragma unroll
    for (int n2 = 0; n2 < 2; ++n2) {
        float v[2][4];
        float s = 0.f;
        #pragma unroll
        for (int m2 = 0; m2 < 2; ++m2)
            #pragma unroll
            for (int r = 0; r < 4; ++r) {
                float vv = acc[m2][n2][r] + bb[m2][r];
                v[m2][r] = vv;
                s += vv * vv;
            }
        s += __shfl_xor(s, 16);
        s += __shfl_xor(s, 32);
        float rn = rsqrtf(s);
        int px = px0 + wc * 32 + n2 * 16 + l15;
        #pragma unroll
        for (int m2 = 0; m2 < 2; ++m2)
            #pragma unroll
            for (int r = 0; r < 4; ++r) {
                int oc = m2 * 16 + l4 * 4 + r;
                outp[((size_t)(b * 32 + oc) << 16) + px] = v[m2][r] * rn;
            }
    }
}

// ---------------------------------------------------------------------------
// K2: partial KX/xsum/Ksum per block (atomic-free). 1024 blocks, 128 px each.
// ---------------------------------------------------------------------------
__global__ __launch_bounds__(256) void k2_kx(const float* __restrict__ x,
        const float* __restrict__ Kn, float* __restrict__ KXp,
        float* __restrict__ xsp, float* __restrict__ ksp)
{
    int blk = blockIdx.x;
    int b = blk >> 9;
    int blkl = blk & 511;
    int t = threadIdx.x;
    int pxl = t & 63, g = t >> 6;
    __shared__ float xT[256][65];
    __shared__ float kT[32][64];
    float acc[32];
    #pragma unroll
    for (int m = 0; m < 32; ++m) acc[m] = 0.f;
    float xs = 0.f, ks = 0.f;
    for (int i = 0; i < 2; ++i) {
        int n0 = (blkl * 2 + i) * 64;
        __syncthreads();
        for (int j = 0; j < 64; ++j) {
            int c = j * 4 + g;
            xT[c][pxl] = x[(size_t)(b * 256 + c) * Nc + n0 + pxl];
        }
        #pragma unroll
        for (int j = 0; j < 8; ++j) {
            int m = j * 4 + g;
            kT[m][pxl] = Kn[((size_t)b * 32 + m) * Nc + n0 + pxl];
        }
        __syncthreads();
        for (int p4 = 0; p4 < 16; ++p4) {
            float x0 = xT[t][p4 * 4 + 0];
            float x1 = xT[t][p4 * 4 + 1];
            float x2 = xT[t][p4 * 4 + 2];
            float x3 = xT[t][p4 * 4 + 3];
            xs += x0 + x1 + x2 + x3;
            #pragma unroll
            for (int m = 0; m < 32; ++m) {
                floatx4 kv = *(const floatx4*)&kT[m][p4 * 4];
                acc[m] += kv[0] * x0 + kv[1] * x1 + kv[2] * x2 + kv[3] * x3;
            }
        }
        if (t < 32) {
            for (int p = 0; p < 64; ++p) ks += kT[t][p];
        }
    }
    xsp[blk * 256 + t] = xs;
    if (t < 32) ksp[blk * 32 + t] = ks;
    #pragma unroll
    for (int m = 0; m < 32; ++m) KXp[(size_t)blk * 8192 + m * 256 + t] = acc[m];
}

// ---------------------------------------------------------------------------
// K2R: reduce partials -> KX, xsum, Ksum
// ---------------------------------------------------------------------------
__global__ __launch_bounds__(256) void k2r(const float* __restrict__ KXp,
        const float* __restrict__ xsp, const float* __restrict__ ksp,
        float* __restrict__ KX, float* __restrict__ xsum, float* __restrict__ Ksum)
{
    int blk = blockIdx.x, t = threadIdx.x;
    if (blk < 64) {
        int gidx = blk * 256 + t;
        int b = gidx >> 13, idx = gidx & 8191;
        float s = 0.f;
        for (int ch = 0; ch < 512; ++ch)
            s += KXp[(size_t)((b << 9) + ch) * 8192 + idx];
        KX[gidx] = s;
    } else if (blk < 66) {
        int b = blk - 64;
        float s = 0.f;
        for (int ch = 0; ch < 512; ++ch)
            s += xsp[((b << 9) + ch) * 256 + t];
        xsum[b * 256 + t] = s;
    } else {
        int b = blk - 66;
        if (t < 32) {
            float s = 0.f;
            for (int ch = 0; ch < 512; ++ch)
                s += ksp[((b << 9) + ch) * 32 + t];
            Ksum[b * 32 + t] = s;
        }
    }
}

// ---------------------------------------------------------------------------
// K3: matrix/vsum from KX, xsum, Ksum
// ---------------------------------------------------------------------------
__global__ __launch_bounds__(256) void k3_mat(const float* __restrict__ wv,
        const float* __restrict__ bv, const float* __restrict__ KX,
        const float* __restrict__ xsum, const float* __restrict__ Ksum,
        float* __restrict__ matrix, float* __restrict__ vsum)
{
    int b = blockIdx.x, t = threadIdx.x;
    __shared__ float sx[256];
    __shared__ float sk[32];
    __shared__ float skx[32][256];
    __shared__ float wT[256][65];
    sx[t] = xsum[b * 256 + t];
    if (t < 32) sk[t] = Ksum[b * 32 + t];
    for (int j = 0; j < 32; ++j) skx[j][t] = KX[(b * 32 + j) * 256 + t];
    float vs = bv[t] * (float)Nc;
    float mv[32];
    #pragma unroll
    for (int m = 0; m < 32; ++m) mv[m] = 0.f;
    for (int cc0 = 0; cc0 < 256; cc0 += 64) {
        __syncthreads();
        for (int i = 0; i < 64; ++i) {
            int c = i * 4 + (t >> 6);
            wT[c][t & 63] = wv[(size_t)c * 256 + cc0 + (t & 63)];
        }
        __syncthreads();
        for (int ccl = 0; ccl < 64; ++ccl) {
            float w = wT[t][ccl];
            int cc = cc0 + ccl;
            vs += w * sx[cc];
            #pragma unroll
            for (int m = 0; m < 32; ++m) mv[m] += w * skx[m][cc];
        }
    }
    vsum[b * 256 + t] = vs;
    float bvt = bv[t];
    for (int m = 0; m < 32; ++m) matrix[(b * 32 + m) * 256 + t] = mv[m] + bvt * sk[m];
}

// ---------------------------------------------------------------------------
// K4: z = x + gamma * (vsum[c] + sum_m Q[m,n]*matrix[m,c]) * tailor[n]
// writes z (f32 NCHW) into scratch; kprep_x pass converts to bf16 NHWC
// ---------------------------------------------------------------------------
__global__ __launch_bounds__(256) void k4_z(const float* __restrict__ x,
        const float* __restrict__ Q, const float* __restrict__ matrix,
        const float* __restrict__ vsum, const float* __restrict__ Ksum,
        const float* __restrict__ gamma_p, float* __restrict__ z)
{
    int b = blockIdx.x >> 10;
    int n0 = (blockIdx.x & 1023) * 64;
    int t = threadIdx.x;
    int px = t & 63, g = t >> 6;
    __shared__ float qT[32][64];
    __shared__ float mat[32][256];
    __shared__ float vs[256];
    __shared__ float tail[64];
    __shared__ float sk[32];
    #pragma unroll
    for (int j = 0; j < 8; ++j) {
        int m = j * 4 + g;
        qT[m][px] = Q[((size_t)b * 32 + m) * Nc + n0 + px];
    }
    for (int j = 0; j < 32; ++j) {
        int idx = j * 256 + t;
        (&mat[0][0])[idx] = matrix[b * 8192 + idx];
    }
    vs[t] = vsum[b * 256 + t];
    if (t < 32) sk[t] = Ksum[b * 32 + t] + LA_EPS;
    __syncthreads();
    if (t < 64) {
        float s = 0.f;
        #pragma unroll
        for (int m = 0; m < 32; ++m) s += qT[m][t] * sk[m];
        tail[t] = 1.0f / ((float)Nc + s);
    }
    __syncthreads();
    float gamma = gamma_p[0];
    for (int l = 0; l < 64; ++l) {
        int c = l * 4 + g;
        float s = vs[c];
        #pragma unroll
        for (int m = 0; m < 32; ++m) s += qT[m][px] * mat[m][c];
        size_t idx = (size_t)(b * 256 + c) * Nc + n0 + px;
        z[idx] = x[idx] + gamma * s * tail[px];
    }
}

// ---------------------------------------------------------------------------
// KPREP_Y: y (NCHW f32) -> ybf (padded NHWC bf16, [b][258][258][256], origin +1)
// ---------------------------------------------------------------------------
__global__ __launch_bounds__(256) void kprep_y(const float* __restrict__ y,
        ushort* __restrict__ ybf)
{
    int blk = blockIdx.x;
    int b = blk >> 13;
    int rest = blk & 8191;
    int ci0 = (rest & 7) * 32;
    int n0 = (rest >> 3) * 64;
    int row = n0 >> 8, x = n0 & 255;
    int t = threadIdx.x;
    __shared__ uint u[16][65];
    int px = t & 63, cig = t >> 6;
    const float* yb = y + (((size_t)(b * 256 + ci0 + cig * 8)) << 16) + n0 + px;
    #pragma unroll
    for (int jj = 0; jj < 4; ++jj) {
        float v0 = yb[((size_t)(jj * 2)) << 16];
        float v1 = yb[((size_t)(jj * 2 + 1)) << 16];
        u[cig * 4 + jj][px] = pack2(v0, v1);
    }
    __syncthreads();
    uint* out32 = (uint*)ybf;
    size_t pbase = (size_t)(row + 1) * 258 + (x + 1);
    int pr = t & 15, pg = t >> 4;
    #pragma unroll
    for (int g2 = 0; g2 < 4; ++g2) {
        int ppx = g2 * 16 + pg;
        size_t uidx = (((size_t)b * 258 * 258 * 256 + (pbase + ppx) * 256 + ci0) >> 1) + pr;
        out32[uidx] = u[pr][ppx];
    }
}

// ---------------------------------------------------------------------------
// KPREP_W: Wb[tap][co][ci] = bf16(wl1[co][ci][tap]*s1[co] + (tap==4)*wl2[co][ci]*s2[co])
// ---------------------------------------------------------------------------
__global__ __launch_bounds__(256) void kprep_w(const float* __restrict__ wl1,
        const float* __restrict__ s1, const float* __restrict__ wl2,
        const float* __restrict__ s2, ushort* __restrict__ Wb)
{
    int idx = blockIdx.x * 256 + threadIdx.x;
    int tp = idx >> 16;
    int r = idx & 65535;
    int co = r >> 8;
    float v = wl1[(size_t)r * 9 + tp] * s1[co];
    if (tp == 4) v += wl2[r] * s2[co];
    Wb[idx] = f2bf(v);
}

// ---------------------------------------------------------------------------
// KPREP_QW: Wqb = bf16(wqkv), q rows (0..255) pre-scaled by 0.25 (= d^-0.5)
// ---------------------------------------------------------------------------
__global__ __launch_bounds__(256) void kprep_qw(const float* __restrict__ wqkv,
        ushort* __restrict__ Wqb)
{
    int idx = blockIdx.x * 256 + threadIdx.x;   // 768*256 = 196608
    float v = wqkv[idx];
    if (idx < 65536) v *= 0.25f;
    Wqb[idx] = f2bf(v);
}

// ---------------------------------------------------------------------------
// KPREP_PW: Wpwb = bf16(wpw)
// ---------------------------------------------------------------------------
__global__ __launch_bounds__(256) void kprep_pw(const float* __restrict__ wpw,
        ushort* __restrict__ Wpwb)
{
    int idx = blockIdx.x * 256 + threadIdx.x;   // 65536
    Wpwb[idx] = f2bf(wpw[idx]);
}

// ---------------------------------------------------------------------------
// K5 (MFMA): L = conv3x3(ybf, Wc) + bias   -- 1x1 branch folded into center tap
// ---------------------------------------------------------------------------
__global__ __launch_bounds__(512, 2) void k5_mfma(
        const ushort* __restrict__ ybf, const ushort* __restrict__ Wb,
        const float* __restrict__ b1, const float* __restrict__ b2,
        float* __restrict__ L)
{
    int blk = blockIdx.x;
    int b = blk >> 9;
    int y0 = (blk >> 1) & 255;
    int x0 = (blk & 1) << 7;
    int t = threadIdx.x;
    int lane = t & 63;
    int w = t >> 6;
    int wr = w >> 1;
    int wc = w & 1;

    __shared__ ushort sW[256 * 64];
    __shared__ ushort sY[128 * 64];

    floatx4 acc[4][4];
    #pragma unroll
    for (int m = 0; m < 4; ++m)
        #pragma unroll
        for (int n = 0; n < 4; ++n)
            acc[m][n] = {0.f, 0.f, 0.f, 0.f};

    const ushort* yb = ybf + (size_t)b * 258 * 258 * 256;
    int ldsWbase = w * 64 * 16;
    int ldsYbase = w * 64 * 16;

    for (int tp = 0; tp < 9; ++tp) {
        int dy = tp / 3 - 1, dx = tp % 3 - 1;
        const ushort* yrow = yb + ((size_t)(y0 + dy + 1) * 258 + (x0 + dx + 1)) * 256;
        const ushort* wtap = Wb + tp * 65536;
        for (int cb = 0; cb < 4; ++cb) {
            int ci0 = cb * 64;
            __syncthreads();
            #pragma unroll
            for (int p = 0; p < 4; ++p) {
                int m = p * 512 + t;
                int row = m >> 3, ch = m & 7;
                const ushort* g = wtap + row * 256 + ci0 + ((ch ^ (row & 7)) << 3);
                gload16(g, (char*)sW + p * 512 * 16 + ldsWbase);
            }
            #pragma unroll
            for (int p = 0; p < 2; ++p) {
                int m = p * 512 + t;
                int pxr = m >> 3, ch = m & 7;
                const ushort* g = yrow + (size_t)pxr * 256 + ci0 + ((ch ^ (pxr & 7)) << 3);
                gload16(g, (char*)sY + p * 512 * 16 + ldsYbase);
            }
            __syncthreads();
            #pragma unroll
            for (int kk = 0; kk < 2; ++kk) {
                int chunkb = kk * 4 + (lane >> 4);
                short8 afr[4];
                #pragma unroll
                for (int m2 = 0; m2 < 4; ++m2) {
                    int row = wr * 64 + m2 * 16 + (lane & 15);
                    int ch = chunkb ^ (row & 7);
                    afr[m2] = *(const short8*)((const char*)sW + row * 128 + ch * 16);
                }
                #pragma unroll
                for (int n2 = 0; n2 < 4; ++n2) {
                    int row = wc * 64 + n2 * 16 + (lane & 15);
                    int ch = chunkb ^ (row & 7);
                    short8 bfr = *(const short8*)((const char*)sY + row * 128 + ch * 16);
                    #pragma unroll
                    for (int m2 = 0; m2 < 4; ++m2)
                        acc[m2][n2] = __builtin_amdgcn_mfma_f32_16x16x32_bf16(
                            afr[m2], bfr, acc[m2][n2], 0, 0, 0);
                }
            }
        }
    }
    int pxb = x0 + wc * 64 + (lane & 15);
    #pragma unroll
    for (int m2 = 0; m2 < 4; ++m2) {
        int cobase = wr * 64 + m2 * 16 + (lane >> 4) * 4;
        #pragma unroll
        for (int r = 0; r < 4; ++r) {
            int co = cobase + r;
            float bias = b1[co] + b2[co];
            float* dst = L + (((size_t)(b * 256 + co)) << 16) + y0 * 256 + pxb;
            #pragma unroll
            for (int n2 = 0; n2 < 4; ++n2)
                dst[n2 * 16] = acc[m2][n2][r] + bias;
        }
    }
}

// ---------------------------------------------------------------------------
// K6 (MFMA, fused): qkv + window attention, TWO adjacent windows per block.
// z is read as bf16 NHWC via global_load_lds with pre-swizzled source.
// ---------------------------------------------------------------------------
__global__ __launch_bounds__(512, 1) void k6_mfma(const ushort* __restrict__ zbf,
        const ushort* __restrict__ Wqb, const float* __restrict__ rel,
        float* __restrict__ A)
{
    int blk = blockIdx.x;
    int wxp = blk & 15, wy = (blk >> 4) & 31, b = blk >> 9;
    int t = threadIdx.x;
    int lane = t & 63;
    int w = t >> 6;
    int win = w >> 2;
    int wq4 = w & 3;

    __shared__ ushort zT[128 * 256];     // [pxg][ci] bf16, xor-swizzled (64 KB)
    __shared__ float srel[3600];         // rel bias table (14.4 KB)
    __shared__ ushort wbuf[8][4096];     // per-wave: qT / kT / vD

    char* zTc = (char*)zT;

    // ---- stage both z windows via global_load_lds (source pre-swizzled) ----
    {
        const ushort* zb = zbf + (((size_t)b) << 16) * 256;
        int j = lane & 31;
        int ph = lane >> 5;
        #pragma unroll
        for (int p = 0; p < 8; ++p) {
            int pxg = (p * 8 + w) * 2 + ph;
            int px = pxg & 63;
            int win2 = pxg >> 6;
            int gy = wy * 8 + (px >> 3);
            int gx = (wxp * 2 + win2) * 8 + (px & 7);
            const ushort* g = zb + (((size_t)(gy * 256 + gx)) << 8) + ((j ^ (pxg & 7)) << 3);
            gload16(g, zTc + (p * 8 + w) * 1024);
        }
    }
    for (int i = t; i < 3600; i += 512) srel[i] = rel[i];
    __syncthreads();

    char* qTb = (char*)&wbuf[w][0];
    char* kTb = (char*)&wbuf[w][1024];
    char* vDb = (char*)&wbuf[w][2048];

    int l15 = lane & 15, l4 = lane >> 4;
    int l31 = lane & 31, l5 = lane >> 5;
    bool hilane = (l5 != 0);
    int pxbase = win * 64;

    for (int hrep = 0; hrep < 4; ++hrep) {
        int h = wq4 * 4 + hrep;

        // ---- q-GEMM ----
        floatx4 qacc[4] = {};
        #pragma unroll
        for (int ks = 0; ks < 8; ++ks) {
            short8 aw = *(const short8*)(Wqb + ((h * 16 + l15) << 8) + ks * 32 + (l4 << 3));
            #pragma unroll
            for (int n = 0; n < 4; ++n) {
                int px = n * 16 + l15;
                short8 bz = *(const short8*)(zTc + (pxbase + px) * 512 + (((ks * 4 + l4) ^ (px & 7)) << 4));
                qacc[n] = __builtin_amdgcn_mfma_f32_16x16x32_bf16(aw, bz, qacc[n], 0, 0, 0);
            }
        }
        #pragma unroll
        for (int n = 0; n < 4; ++n) {
            int px = n * 16 + l15;
            uint2 wv = { pack2(qacc[n][0], qacc[n][1]), pack2(qacc[n][2], qacc[n][3]) };
            *(uint2*)(qTb + px * 32 + (l4 << 3)) = wv;
        }

        // ---- kT-GEMM ----
        floatx4 kacc[4] = {};
        #pragma unroll
        for (int ks = 0; ks < 8; ++ks) {
            short8 bw = *(const short8*)(Wqb + ((256 + h * 16 + l15) << 8) + ks * 32 + (l4 << 3));
            #pragma unroll
            for (int m = 0; m < 4; ++m) {
                int px = m * 16 + l15;
                short8 az = *(const short8*)(zTc + (pxbase + px) * 512 + (((ks * 4 + l4) ^ (px & 7)) << 4));
                kacc[m] = __builtin_amdgcn_mfma_f32_16x16x32_bf16(az, bw, kacc[m], 0, 0, 0);
            }
        }
        #pragma unroll
        for (int m = 0; m < 4; ++m) {
            #pragma unroll
            for (int r = 0; r < 4; ++r) {
                int px = m * 16 + l4 * 4 + r;
                *(ushort*)(kTb + px * 32 + l15 * 2) = f2bf(kacc[m][r]);
            }
        }

        // ---- v-GEMM ----
        floatx4 vacc[4] = {};
        #pragma unroll
        for (int ks = 0; ks < 8; ++ks) {
            short8 aw = *(const short8*)(Wqb + ((512 + h * 16 + l15) << 8) + ks * 32 + (l4 << 3));
            #pragma unroll
            for (int n = 0; n < 4; ++n) {
                int px = n * 16 + l15;
                short8 bz = *(const short8*)(zTc + (pxbase + px) * 512 + (((ks * 4 + l4) ^ (px & 7)) << 4));
                vacc[n] = __builtin_amdgcn_mfma_f32_16x16x32_bf16(aw, bz, vacc[n], 0, 0, 0);
            }
        }
        #pragma unroll
        for (int n = 0; n < 4; ++n) {
            int px = n * 16 + l15;
            #pragma unroll
            for (int r = 0; r < 4; ++r) {
                int d = l4 * 4 + r;
                *(ushort*)(vDb + d * 128 + ((((px >> 3) ^ (d & 7)) << 4) + (px & 7) * 2)) = f2bf(vacc[n][r]);
            }
        }

        // ---- per-it: S^T, softmax, PV ----
        #pragma unroll
        for (int it = 0; it < 2; ++it) {
            short8 bq_ = *(const short8*)(qTb + (it * 32 + l31) * 32 + (l5 << 4));
            floatx16 st[2];
            #pragma unroll
            for (int jt = 0; jt < 2; ++jt) {
                short8 ak = *(const short8*)(kTb + (jt * 32 + l31) * 32 + (l5 << 4));
                floatx16 zc = {};
                st[jt] = __builtin_amdgcn_mfma_f32_32x32x16_bf16(ak, bq_, zc, 0, 0, 0);
            }
            int i = it * 32 + l31;
            int Ai = (i >> 3) * 15 + (i & 7) + 112;
            float mx = -1e30f;
            #pragma unroll
            for (int jt = 0; jt < 2; ++jt)
                #pragma unroll
                for (int r = 0; r < 16; ++r) {
                    int j = jt * 32 + (r & 3) + 8 * (r >> 2) + 4 * l5;
                    int Bjr = (j >> 3) * 15 + (j & 7);
                    float s = st[jt][r] + srel[(Ai - Bjr) * 16 + h];
                    st[jt][r] = s;
                    mx = fmaxf(mx, s);
                }
            mx = fmaxf(mx, __shfl_xor(mx, 32));
            float sum = 0.f;
            #pragma unroll
            for (int jt = 0; jt < 2; ++jt)
                #pragma unroll
                for (int r = 0; r < 16; ++r) {
                    float e = __expf(st[jt][r] - mx);
                    st[jt][r] = e;
                    sum += e;
                }
            sum += __shfl_xor(sum, 32);
            float rinv = 1.0f / sum;

            floatx16 ot = {};
            #pragma unroll
            for (int jc = 0; jc < 4; ++jc) {
                int jt = jc >> 1, rb = (jc & 1) * 8;
                uint u0 = pack2(st[jt][rb + 0], st[jt][rb + 1]);
                uint u1 = pack2(st[jt][rb + 2], st[jt][rb + 3]);
                uint u2 = pack2(st[jt][rb + 4], st[jt][rb + 5]);
                uint u3 = pack2(st[jt][rb + 6], st[jt][rb + 7]);
                uint s0 = __shfl_xor(u0, 32);
                uint s1 = __shfl_xor(u1, 32);
                uint s2 = __shfl_xor(u2, 32);
                uint s3 = __shfl_xor(u3, 32);
                union { short8 v; uint u[4]; } bf;
                bf.u[0] = hilane ? s2 : u0;
                bf.u[1] = hilane ? s3 : u1;
                bf.u[2] = hilane ? u2 : s0;
                bf.u[3] = hilane ? u3 : s1;
                short8 av = *(const short8*)(vDb + l31 * 128 + (((jc * 2 + l5) ^ (l31 & 7)) << 4));
                ot = __builtin_amdgcn_mfma_f32_32x32x16_bf16(av, bf.v, ot, 0, 0, 0);
            }
            int gy = wy * 8 + (i >> 3);
            int gx = (wxp * 2 + win) * 8 + (i & 7);
            float* Ab = A + (((size_t)(b * 256 + h * 16)) << 16) + gy * 256 + gx;
            #pragma unroll
            for (int r = 0; r < 8; ++r) {
                int d = (r & 3) + 8 * (r >> 2) + 4 * l5;
                Ab[(size_t)d << 16] = ot[r] * rinv;
            }
        }
    }
}

// ---------------------------------------------------------------------------
// K7 (tiled): L += avgpoolV(A) + avgpoolH(A). 64x64 tile + 7-halo in LDS.
// grid: B * C * 16 = 8192 blocks, 256 threads (16 outputs each)
// ---------------------------------------------------------------------------
__global__ __launch_bounds__(256) void k7_pool(const float* __restrict__ A,
        float* __restrict__ L)
{
    int blk = blockIdx.x;
    int tile = blk & 15;
    int c = (blk >> 4) & 255;
    int b = blk >> 12;
    int ty = (tile >> 2) * 64, tx = (tile & 3) * 64;
    int t = threadIdx.x;
    __shared__ float aT[71][73];
    const float* Ac = A + ((size_t)(b * 256 + c) << 16);
    for (int i = t; i < 71 * 71; i += 256) {
        int rr = i / 71, cc = i - rr * 71;
        int gy = ty + rr - 3, gx = tx + cc - 3;
        float v = 0.f;
        if (gy >= 0 && gy <= 256 && gx >= 0 && gx <= 256) {
            int ry = (gy == 256) ? 254 : gy;
            int rx = (gx == 256) ? 254 : gx;
            v = Ac[ry * 256 + rx];
        }
        aT[rr][cc] = v;
    }
    __syncthreads();
    int jj = t & 63;
    int oy0 = (t >> 6) * 16;
    float* Lc = L + ((size_t)(b * 256 + c) << 16);
    #pragma unroll 4
    for (int dy = 0; dy < 16; ++dy) {
        int oi = oy0 + dy;
        float sv = 0.f, sh = 0.f;
        #pragma unroll
        for (int u = 0; u < 8; ++u) {
            sv += aT[oi + u][jj + 3];
            sh += aT[oi + 3][jj + u];
        }
        int idx = (ty + oi) * 256 + tx + jj;
        Lc[idx] += 0.125f * (sv + sh);
    }
}

// ---------------------------------------------------------------------------
// K8 (tiled): D(bf16) = sp * dwconv8x8(pad_out(L), wdw, pad=3) + bp
// grid: B * C * 64 = 32768 blocks; 32x32 tile, 4 outputs/thread
// ---------------------------------------------------------------------------
__global__ __launch_bounds__(256) void k8_dw(const float* __restrict__ P,
        const float* __restrict__ wdw, const float* __restrict__ sp,
        const float* __restrict__ bp, ushort* __restrict__ D)
{
    int blk = blockIdx.x;
    int tile = blk & 63;
    int c = (blk >> 6) & 255;
    int b = blk >> 14;
    int ty = (tile >> 3) * 32, tx = (tile & 7) * 32;
    int t = threadIdx.x;
    __shared__ float pT[39][40];
    __shared__ float wT[64];
    const float* Pc = P + ((size_t)(b * 256 + c) << 16);
    for (int i = t; i < 39 * 40; i += 256) {
        int rr = i / 40, cc = i - rr * 40;
        int gy = ty + rr - 3, gx = tx + cc - 3;
        float v = 0.f;
        if (gy >= 0 && gy <= 256 && gx >= 0 && gx <= 256) {
            int ry = (gy == 256) ? 254 : gy;
            int rx = (gx == 256) ? 254 : gx;
            v = Pc[ry * 256 + rx];
        }
        pT[rr][cc] = v;
    }
    if (t < 64) wT[t] = wdw[c * 64 + t];
    __syncthreads();
    int jj = t & 31;
    int oy0 = (t >> 5) * 4;
    float spc = sp[c], bpc = bp[c];
    ushort* Dc = D + ((size_t)(b * 256 + c) << 16);
    #pragma unroll
    for (int dy = 0; dy < 4; ++dy) {
        int oi = oy0 + dy;
        float acc = 0.f;
        #pragma unroll
        for (int u = 0; u < 8; ++u)
            #pragma unroll
            for (int v = 0; v < 8; ++v)
                acc += wT[u * 8 + v] * pT[oi + u][jj + v];
        Dc[(ty + oi) * 256 + tx + jj] = f2bf(spc * acc + bpc);
    }
}

// ---------------------------------------------------------------------------
// K9 (MFMA): out[co][px] = sum_ci Wpw[co][ci] * D[ci][px]
// ---------------------------------------------------------------------------
__global__ __launch_bounds__(512, 2) void k9_mfma(
        const ushort* __restrict__ D, const ushort* __restrict__ Wpwb,
        float* __restrict__ out)
{
    int blk = blockIdx.x;
    int b = blk >> 9;
    int px0 = (blk & 511) << 7;
    int t = threadIdx.x;
    int lane = t & 63;
    int w = t >> 6;
    int wr = w >> 1, wc = w & 1;

    __shared__ ushort sW[256 * 64];   // [co][ci] swizzled, 32KB
    __shared__ ushort sD[128 * 64];   // [px][ci] swizzled, 16KB

    floatx4 acc[4][4];
    #pragma unroll
    for (int m = 0; m < 4; ++m)
        #pragma unroll
        for (int n = 0; n < 4; ++n)
            acc[m][n] = {0.f, 0.f, 0.f, 0.f};

    int ldsWbase = w * 64 * 16;

    for (int cb = 0; cb < 4; ++cb) {
        int ci0 = cb * 64;
        __syncthreads();
        #pragma unroll
        for (int p = 0; p < 4; ++p) {
            int m = p * 512 + t;
            int row = m >> 3, ch = m & 7;
            const ushort* g = Wpwb + row * 256 + ci0 + ((ch ^ (row & 7)) << 3);
            gload16(g, (char*)sW + p * 512 * 16 + ldsWbase);
        }
        #pragma unroll
        for (int p = 0; p < 2; ++p) {
            int m = p * 512 + t;
            int ci = m & 63, pxb = (m >> 6) * 8;
            short8 v = *(const short8*)(D + ((size_t)(b * 256 + ci0 + ci) << 16) + px0 + pxb);
            #pragma unroll
            for (int k2 = 0; k2 < 8; ++k2) {
                int px = pxb + k2;
                *(ushort*)((char*)sD + px * 128 + (((ci >> 3) ^ (px & 7)) << 4) + (ci & 7) * 2) =
                    (ushort)v[k2];
            }
        }
        __syncthreads();
        #pragma unroll
        for (int kk = 0; kk < 2; ++kk) {
            int chunkb = kk * 4 + (lane >> 4);
            short8 afr[4];
            #pragma unroll
            for (int m2 = 0; m2 < 4; ++m2) {
                int row = wr * 64 + m2 * 16 + (lane & 15);
                int ch = chunkb ^ (row & 7);
                afr[m2] = *(const short8*)((const char*)sW + row * 128 + ch * 16);
            }
            #pragma unroll
            for (int n2 = 0; n2 < 4; ++n2) {
                int row = wc * 64 + n2 * 16 + (lane & 15);
                int ch = chunkb ^ (row & 7);
                short8 bfr = *(const short8*)((const char*)sD + row * 128 + ch * 16);
                #pragma unroll
                for (int m2 = 0; m2 < 4; ++m2)
                    acc[m2][n2] = __builtin_amdgcn_mfma_f32_16x16x32_bf16(
                        afr[m2], bfr, acc[m2][n2], 0, 0, 0);
            }
        }
    }
    int pxb = px0 + wc * 64 + (lane & 15);
    #pragma unroll
    for (int m2 = 0; m2 < 4; ++m2) {
        int cobase = wr * 64 + m2 * 16 + (lane >> 4) * 4;
        #pragma unroll
        for (int r = 0; r < 4; ++r) {
            int co = cobase + r;
            float* dst = out + (((size_t)(b * 256 + co)) << 16) + pxb;
            #pragma unroll
            for (int n2 = 0; n2 < 4; ++n2)
                dst[n2 * 16] = acc[m2][n2][r];
        }
    }
}

// ---------------------------------------------------------------------------
extern "C" void kernel_launch(void* const* d_in, const int* in_sizes, int n_in,
                              void* d_out, int out_size, void* d_ws, size_t ws_size,
                              hipStream_t stream)
{
    (void)in_sizes; (void)n_in; (void)out_size; (void)ws_size;
    const float* x     = (const float*)d_in[0];
    const float* y     = (const float*)d_in[1];
    const float* gamma = (const float*)d_in[2];
    const float* la_wq = (const float*)d_in[3];
    const float* la_bq = (const float*)d_in[4];
    const float* la_wk = (const float*)d_in[5];
    const float* la_bk = (const float*)d_in[6];
    const float* la_wv = (const float*)d_in[7];
    const float* la_bv = (const float*)d_in[8];
    const float* wqkv  = (const float*)d_in[9];
    const float* wl1   = (const float*)d_in[10];
    const float* s1    = (const float*)d_in[11];
    const float* b1    = (const float*)d_in[12];
    const float* wl2   = (const float*)d_in[13];
    const float* s2    = (const float*)d_in[14];
    const float* b2    = (const float*)d_in[15];
    const float* rel   = (const float*)d_in[16];
    const float* wdw   = (const float*)d_in[17];
    const float* sp    = (const float*)d_in[18];
    const float* bp    = (const float*)d_in[19];
    const float* wpw   = (const float*)d_in[20];
    float* out = (float*)d_out;

    float* ws = (float*)d_ws;
    float* Q      = ws;                      // 4,194,304 floats (Qo)
    float* Kn     = ws + 4194304;            // 4,194,304 (W-preps alias after k2)
    float* stats  = ws + 8388608;            // 40,960 floats
    float* Ksum   = stats;                   // 64
    float* xsum   = stats + 64;              // 512
    float* KX     = stats + 576;             // 16,384
    float* matrix = stats + 16960;           // 16,384
    float* vsum   = stats + 33344;           // 512
    float* A      = ws + 8429568;            // 33,554,432 (ybf alias; attn out; Dbf)
    float* L      = A + 33554432;            // 33,554,432 (phase1 aliases; zf32; Lconv)

    // L-region phase-1 aliases (all dead before k4 writes zf32 / k5 writes L):
    float* KXp   = L;                        // 1024 x 8192 = 8,388,608
    float* xsp   = L + 8388608;              // 1024 x 256  = 262,144
    float* ksp   = L + 8650752;              // 1024 x 32   = 32,768
    ushort* xbf  = (ushort*)(L + 8683520);   // 33,554,432 ushorts (x NHWC bf16)
    ushort* Wqkb = (ushort*)(L + 25460736);  // 16,384 ushorts
    float* zf32  = L;                        // z f32 NCHW (after k2r/k1; before k5)

    ushort* Wb   = (ushort*)Kn;              // conv weights, 589,824 bf16
    ushort* Wqb  = (ushort*)Kn + 600064;     // qkv weights, 196,608 bf16
    ushort* Wpwb = (ushort*)Kn + 798720;     // pw weights, 65,536 bf16
    ushort* ybf  = (ushort*)A;               // padded NHWC y, bf16 — until k6
    ushort* Dbf  = (ushort*)A;               // bf16 dwconv out — after k8
    ushort* zbf  = (ushort*)d_out;           // z bf16 NHWC — between kprep_z and k6

    hipMemsetAsync(ybf, 0, (size_t)2 * 258 * 258 * 256 * sizeof(ushort), stream);

    kprep_y <<<16384, 256, 0, stream>>>(y, ybf);
    kprep_x <<<16384, 256, 0, stream>>>(x, xbf);
    kprep_qk<<<64,    256, 0, stream>>>(la_wq, la_wk, Wqkb);
    k1_mfma <<<1024,  512, 0, stream>>>(xbf, Wqkb, la_bq, la_bk, Q, Kn);
    k2_kx   <<<1024,  256, 0, stream>>>(x, Kn, KXp, xsp, ksp);
    kprep_w <<<2304,  256, 0, stream>>>(wl1, s1, wl2, s2, Wb);  // Kn dead after k2
    kprep_qw<<<768,   256, 0, stream>>>(wqkv, Wqb);
    kprep_pw<<<256,   256, 0, stream>>>(wpw, Wpwb);
    k2r     <<<68,    256, 0, stream>>>(KXp, xsp, ksp, KX, xsum, Ksum);
    k3_mat  <<<2,     256, 0, stream>>>(la_wv, la_bv, KX, xsum, Ksum, matrix, vsum);
    k4_z    <<<2048,  256, 0, stream>>>(x, Q, matrix, vsum, Ksum, gamma, zf32);
    kprep_x <<<16384, 256, 0, stream>>>(zf32, zbf);             // z -> bf16 NHWC in d_out
    k5_mfma <<<1024,  512, 0, stream>>>(ybf, Wb, b1, b2, L);    // overwrites zf32
    k6_mfma <<<1024,  512, 0, stream>>>(zbf, Wqb, rel, A);      // overwrites ybf
    k7_pool <<<8192,  256, 0, stream>>>(A, L);
    k8_dw   <<<32768, 256, 0, stream>>>(L, wdw, sp, bp, Dbf);
    k9_mfma <<<1024,  512, 0, stream>>>(Dbf, Wpwb, out);
}